// Round 1
// baseline (8641.328 us; speedup 1.0000x reference)
//
#include <hip/hip_runtime.h>
#include <cmath>

namespace {
constexpr int Bn = 16, Ln = 4096, Dn = 128, DSn = 16;
constexpr int Mtok = Bn * Ln; // 65536 tokens
}

// ---------------- embedding ----------------

// xc[b,p] = 0.5*(x0+x1+x2+x3) + x4
__global__ void k_combine(const float* __restrict__ x, float* __restrict__ xc) {
  int i = blockIdx.x * 256 + threadIdx.x; // B*HW = 65536
  int b = i >> 12, p = i & 4095;
  const float* xb = x + (size_t)b * 5 * Ln + p;
  xc[i] = 0.5f * (xb[0] + xb[Ln] + xb[2 * Ln] + xb[3 * Ln]) + xb[4 * Ln];
}

// emb[b,l,d] = conv3x3_1ch(xc)[d,l] + 3*(eb[d] + pos[l,d]) + (0.5*(t0..t3)+t4)[d]
__global__ void k_embed(const float* __restrict__ xc, const float* __restrict__ ew,
                        const float* __restrict__ eb, const float* __restrict__ pos,
                        const float* __restrict__ te, float* __restrict__ emb) {
  int l = blockIdx.x & 4095, b = blockIdx.x >> 12;
  int h = l >> 6, w = l & 63;
  int d = threadIdx.x;
  const float* xb = xc + b * Ln;
  float v[9];
#pragma unroll
  for (int dy = 0; dy < 3; dy++)
#pragma unroll
    for (int dx = 0; dx < 3; dx++) {
      int y = h + dy - 1, xx = w + dx - 1;
      v[dy * 3 + dx] = (y >= 0 && y < 64 && xx >= 0 && xx < 64) ? xb[y * 64 + xx] : 0.f;
    }
  float acc = 0.f;
#pragma unroll
  for (int k = 0; k < 9; k++) acc += v[k] * ew[d * 9 + k];
  float ts = 0.5f * (te[d] + te[128 + d] + te[256 + d] + te[384 + d]) + te[512 + d];
  emb[(size_t)blockIdx.x * Dn + d] = acc + 3.f * eb[d] + 3.f * pos[l * Dn + d] + ts;
}

// ---------------- layernorm (rows of 128) ----------------
__global__ __launch_bounds__(256) void k_ln(const float* __restrict__ in, float* __restrict__ out,
                                            const float* __restrict__ w, const float* __restrict__ bias) {
  int row = blockIdx.x * 4 + (threadIdx.x >> 6);
  int lane = threadIdx.x & 63;
  const float* p = in + (size_t)row * Dn;
  float2 v = *(const float2*)(p + lane * 2);
  float s = v.x + v.y, sq = v.x * v.x + v.y * v.y;
#pragma unroll
  for (int off = 32; off; off >>= 1) { s += __shfl_xor(s, off); sq += __shfl_xor(sq, off); }
  float m = s * (1.f / 128.f);
  float var = sq * (1.f / 128.f) - m * m;
  float r = rsqrtf(var + 1e-5f);
  int d = lane * 2;
  float2 o;
  o.x = (v.x - m) * r * w[d] + bias[d];
  o.y = (v.y - m) * r * w[d + 1] + bias[d + 1];
  *(float2*)(out + (size_t)row * Dn + d) = o;
}

// ---------------- causal depthwise conv1d k=4 + residual ----------------
__global__ void k_dwconv(const float* __restrict__ xn, float* __restrict__ emb,
                         const float* __restrict__ cw, const float* __restrict__ cb) {
  int i = blockIdx.x * 256 + threadIdx.x; // Mtok*128
  int d = i & 127;
  int l = (i >> 7) & 4095;
  const float* p = xn + i;
  float acc = cb[d] + cw[d * 4 + 3] * p[0];
  if (l >= 1) acc += cw[d * 4 + 2] * p[-128];
  if (l >= 2) acc += cw[d * 4 + 1] * p[-256];
  if (l >= 3) acc += cw[d * 4 + 0] * p[-384];
  emb[i] += acc;
}

// ---------------- generic GEMM: C[M,N] = A[M,K] @ W[N,K]^T (+ epilogues) ----------------
// MODE 0: bias               -> out[M,N]
// MODE 1: bias; col<128 silu -> out[M,128]; col>=128 sigmoid -> out2[M,128]
// MODE 2: bias; exact gelu   -> out[M,N]
// MODE 3: bias; accumulate   -> out[M,N] +=
template <int MODE>
__global__ __launch_bounds__(256) void k_gemm(const float* __restrict__ A, const float* __restrict__ W,
                                              const float* __restrict__ bias, float* __restrict__ out,
                                              float* __restrict__ out2, int K, int N) {
  __shared__ float As[16 * 68];
  __shared__ float Ws[16 * 68];
  const int m0 = blockIdx.x * 64, n0 = blockIdx.y * 64;
  const int t = threadIdx.x;
  const int tx = t & 15, ty = t >> 4;
  const int lr = t >> 2, kq = t & 3;
  float acc[4][4] = {};
  for (int k0 = 0; k0 < K; k0 += 16) {
    float4 av = *(const float4*)(A + (size_t)(m0 + lr) * K + k0 + kq * 4);
    float4 wv = *(const float4*)(W + (size_t)(n0 + lr) * K + k0 + kq * 4);
    __syncthreads();
    As[(kq * 4 + 0) * 68 + lr] = av.x;
    As[(kq * 4 + 1) * 68 + lr] = av.y;
    As[(kq * 4 + 2) * 68 + lr] = av.z;
    As[(kq * 4 + 3) * 68 + lr] = av.w;
    Ws[(kq * 4 + 0) * 68 + lr] = wv.x;
    Ws[(kq * 4 + 1) * 68 + lr] = wv.y;
    Ws[(kq * 4 + 2) * 68 + lr] = wv.z;
    Ws[(kq * 4 + 3) * 68 + lr] = wv.w;
    __syncthreads();
#pragma unroll
    for (int kk = 0; kk < 16; kk++) {
      float4 a4 = *(const float4*)&As[kk * 68 + ty * 4];
      float4 w4 = *(const float4*)&Ws[kk * 68 + tx * 4];
      float aa[4] = {a4.x, a4.y, a4.z, a4.w};
      float ww[4] = {w4.x, w4.y, w4.z, w4.w};
#pragma unroll
      for (int i = 0; i < 4; i++)
#pragma unroll
        for (int j = 0; j < 4; j++) acc[i][j] += aa[i] * ww[j];
    }
  }
#pragma unroll
  for (int i = 0; i < 4; i++) {
    const int row = m0 + ty * 4 + i;
    const int col = n0 + tx * 4;
    float v[4];
#pragma unroll
    for (int j = 0; j < 4; j++) v[j] = acc[i][j] + bias[col + j];
    if (MODE == 0) {
      float4 o = {v[0], v[1], v[2], v[3]};
      *(float4*)(out + (size_t)row * N + col) = o;
    } else if (MODE == 1) {
      float4 q;
      if (col < 128) {
        q.x = v[0] / (1.f + expf(-v[0]));
        q.y = v[1] / (1.f + expf(-v[1]));
        q.z = v[2] / (1.f + expf(-v[2]));
        q.w = v[3] / (1.f + expf(-v[3]));
        *(float4*)(out + (size_t)row * 128 + col) = q;
      } else {
        q.x = 1.f / (1.f + expf(-v[0]));
        q.y = 1.f / (1.f + expf(-v[1]));
        q.z = 1.f / (1.f + expf(-v[2]));
        q.w = 1.f / (1.f + expf(-v[3]));
        *(float4*)(out2 + (size_t)row * 128 + (col - 128)) = q;
      }
    } else if (MODE == 2) {
      float4 q;
      q.x = 0.5f * v[0] * (1.f + erff(v[0] * 0.7071067811865475f));
      q.y = 0.5f * v[1] * (1.f + erff(v[1] * 0.7071067811865475f));
      q.z = 0.5f * v[2] * (1.f + erff(v[2] * 0.7071067811865475f));
      q.w = 0.5f * v[3] * (1.f + erff(v[3] * 0.7071067811865475f));
      *(float4*)(out + (size_t)row * N + col) = q;
    } else {
      float4 cur = *(float4*)(out + (size_t)row * N + col);
      cur.x += v[0]; cur.y += v[1]; cur.z += v[2]; cur.w += v[3];
      *(float4*)(out + (size_t)row * N + col) = cur;
    }
  }
}

// ---------------- u = silu(xp) @ x_w^T + x_b  (N=16) ----------------
__global__ __launch_bounds__(256) void k_u(const float* __restrict__ XP, const float* __restrict__ xw,
                                           const float* __restrict__ xb, float* __restrict__ U) {
  __shared__ float xs[16 * 132];
  __shared__ float wsm[16 * 129];
  const int m0 = blockIdx.x * 16;
  const int t = threadIdx.x;
  for (int idx = t; idx < 2048; idx += 256) {
    wsm[(idx >> 7) * 129 + (idx & 127)] = xw[idx];
    xs[(idx >> 7) * 132 + (idx & 127)] = XP[(size_t)m0 * 128 + idx];
  }
  __syncthreads();
  const int ds = t & 15, ml = t >> 4;
  float acc = 0.f;
#pragma unroll 16
  for (int k = 0; k < 128; k++) acc += xs[ml * 132 + k] * wsm[ds * 129 + k];
  U[(size_t)(m0 + ml) * 16 + ds] = acc + xb[ds];
}

// ---------------- chunked parallel linear scan: h_t = a*h_{t-1} + u_t ----------------
// one block (64 lanes) per (b, ds); output transposed: HST[b][ds][L]
__global__ __launch_bounds__(64) void k_scan(const float* __restrict__ U, float* __restrict__ HST,
                                             const float* __restrict__ A_log) {
  __shared__ float lds[64 * 65]; // index t + (t>>6): conflict-free
  const int b = blockIdx.x >> 4, ds = blockIdx.x & 15;
  const int tid = threadIdx.x;
  const float a = expf(-expf(A_log[ds]));
  const float* ub = U + (size_t)b * Ln * 16 + ds;
  for (int j = 0; j < 64; j++) lds[j * 65 + tid] = ub[(size_t)(j * 64 + tid) * 16];
  __syncthreads();
  // local inclusive scan of this lane's 64-step chunk
  float h = 0.f;
  for (int j = 0; j < 64; j++) {
    h = a * h + lds[tid * 65 + j];
    lds[tid * 65 + j] = h;
  }
  // Kogge-Stone scan of affine segments (A=a^64, B=local final) across lanes
  float a64 = a;
#pragma unroll
  for (int q = 0; q < 6; q++) a64 *= a64;
  float Ac = a64, Bc = h;
#pragma unroll
  for (int off = 1; off < 64; off <<= 1) {
    float Ap = __shfl_up(Ac, off);
    float Bp = __shfl_up(Bc, off);
    if (tid >= off) { Bc = Ac * Bp + Bc; Ac = Ac * Ap; }
  }
  float carry = __shfl_up(Bc, 1); // H_{tid-1}
  if (tid == 0) carry = 0.f;
  float p = a;
  for (int j = 0; j < 64; j++) {
    lds[tid * 65 + j] += p * carry;
    p *= a;
  }
  __syncthreads();
  float* hb = HST + (size_t)(b * 16 + ds) * Ln;
  for (int j = 0; j < 64; j++) hb[j * 64 + tid] = lds[j * 65 + tid];
}

// ---------------- y = (hs @ D) * z ----------------
__global__ __launch_bounds__(256) void k_y(const float* __restrict__ HST, const float* __restrict__ Dm_,
                                           const float* __restrict__ Z, float* __restrict__ Y) {
  const int m = blockIdx.x * 2 + (threadIdx.x >> 7);
  const int d = threadIdx.x & 127;
  const int b = m >> 12, l = m & 4095;
  const float* hb = HST + (size_t)b * 16 * Ln + l;
  float acc = 0.f;
#pragma unroll
  for (int s = 0; s < 16; s++) acc += hb[(size_t)s * Ln] * Dm_[s * 128 + d];
  const size_t o = (size_t)m * 128 + d;
  Y[o] = acc * Z[o];
}

// ---------------- [B,L,D] -> sp at channels 128.. of u2cat [B,256,H,W] ----------------
__global__ void k_transpose(const float* __restrict__ emb, float* __restrict__ u2c) {
  __shared__ float tile[32][33];
  int l0 = blockIdx.x * 32, d0 = blockIdx.y * 32, b = blockIdx.z;
  int tx = threadIdx.x, ty = threadIdx.y;
#pragma unroll
  for (int i = 0; i < 4; i++) {
    int ll = ty + i * 8;
    tile[ll][tx] = emb[((size_t)b * 4096 + l0 + ll) * 128 + d0 + tx];
  }
  __syncthreads();
#pragma unroll
  for (int i = 0; i < 4; i++) {
    int dd = ty + i * 8;
    u2c[((size_t)b * 256 + 128 + d0 + dd) * 4096 + l0 + tx] = tile[tx][dd];
  }
}

// ---------------- 3x3 conv (pad 1) + relu; strides parameterized for cat-buffers ----------------
__global__ void k_conv3x3(const float* __restrict__ in, float* __restrict__ out,
                          const float* __restrict__ w, const float* __restrict__ bias,
                          int Cin, int Hi, int Wi, int Ho, int Wo, int stride,
                          long in_bstride, long out_bstride) {
  const int co = blockIdx.x * 4 + (threadIdx.x >> 6);
  const int p = blockIdx.y * 64 + (threadIdx.x & 63);
  const int b = blockIdx.z;
  const int ho = p / Wo, wo = p % Wo;
  const int y0 = ho * stride - 1, x0 = wo * stride - 1;
  const float* ib = in + (size_t)b * in_bstride;
  const float* wr = w + (size_t)co * Cin * 9;
  float acc = bias[co];
  for (int ci = 0; ci < Cin; ci++) {
    const float* ic = ib + (size_t)ci * Hi * Wi;
    const float* wc = wr + ci * 9;
#pragma unroll
    for (int dy = 0; dy < 3; dy++) {
      const int y = y0 + dy;
      if ((unsigned)y >= (unsigned)Hi) continue;
#pragma unroll
      for (int dx = 0; dx < 3; dx++) {
        const int xx = x0 + dx;
        if ((unsigned)xx >= (unsigned)Wi) continue;
        acc += ic[y * Wi + xx] * wc[dy * 3 + dx];
      }
    }
  }
  out[(size_t)b * out_bstride + (size_t)co * Ho * Wo + p] = fmaxf(acc, 0.f);
}

// ---------------- ConvTranspose2d k=4 s=2 p=1 + relu (gather form) ----------------
__global__ void k_convt(const float* __restrict__ in, float* __restrict__ out,
                        const float* __restrict__ w, const float* __restrict__ bias,
                        int Cin, int Cout, int Hi, int Wi, long in_bstride, long out_bstride) {
  const int Ho = Hi * 2, Wo = Wi * 2;
  const int co = blockIdx.x * 4 + (threadIdx.x >> 6);
  const int p = blockIdx.y * 64 + (threadIdx.x & 63);
  const int b = blockIdx.z;
  const int oy = p / Wo, ox = p % Wo;
  int iyA[2], kyA[2], ny = 0;
  int ixA[2], kxA[2], nx = 0;
#pragma unroll
  for (int q = 0; q < 2; q++) {
    int ky = ((oy + 1) & 1) + q * 2;
    int iy = (oy + 1 - ky) >> 1;
    if (iy >= 0 && iy < Hi) { iyA[ny] = iy; kyA[ny] = ky; ny++; }
    int kx = ((ox + 1) & 1) + q * 2;
    int ix = (ox + 1 - kx) >> 1;
    if (ix >= 0 && ix < Wi) { ixA[nx] = ix; kxA[nx] = kx; nx++; }
  }
  const float* ib = in + (size_t)b * in_bstride;
  float acc = bias[co];
  for (int ci = 0; ci < Cin; ci++) {
    const float* ic = ib + (size_t)ci * Hi * Wi;
    const float* wc = w + ((size_t)ci * Cout + co) * 16;
    for (int qa = 0; qa < ny; qa++)
      for (int qb = 0; qb < nx; qb++)
        acc += ic[iyA[qa] * Wi + ixA[qb]] * wc[kyA[qa] * 4 + kxA[qb]];
  }
  out[(size_t)b * out_bstride + (size_t)co * Ho * Wo + p] = fmaxf(acc, 0.f);
}

// ---------------- final 1x1 conv 256 -> 2 ----------------
__global__ void k_final(const float* __restrict__ in, const float* __restrict__ w,
                        const float* __restrict__ bias, float* __restrict__ out) {
  int i = blockIdx.x * 256 + threadIdx.x; // B*2*4096
  int p = i & 4095;
  int nc = (i >> 12) & 1;
  int b = i >> 13;
  const float* ib = in + (size_t)b * 256 * 4096 + p;
  const float* wr = w + nc * 256;
  float acc = bias[nc];
  for (int c = 0; c < 256; c++) acc += ib[(size_t)c * 4096] * wr[c];
  out[i] = acc;
}

extern "C" void kernel_launch(void* const* d_in, const int* in_sizes, int n_in,
                              void* d_out, int out_size, void* d_ws, size_t ws_size,
                              hipStream_t stream) {
  (void)in_sizes; (void)n_in; (void)out_size; (void)ws_size;
  const float* x          = (const float*)d_in[0];
  const float* emb_w      = (const float*)d_in[1];
  const float* emb_b      = (const float*)d_in[2];
  const float* pos_embed  = (const float*)d_in[3];
  const float* time_embed = (const float*)d_in[4];
  const float* blk_ln1_w  = (const float*)d_in[5];
  const float* blk_ln1_b  = (const float*)d_in[6];
  const float* blk_conv_w = (const float*)d_in[7];
  const float* blk_conv_b = (const float*)d_in[8];
  const float* blk_sln_w  = (const float*)d_in[9];
  const float* blk_sln_b  = (const float*)d_in[10];
  const float* blk_A_log  = (const float*)d_in[11];
  const float* blk_D      = (const float*)d_in[12];
  const float* blk_in_w   = (const float*)d_in[13];
  const float* blk_in_b   = (const float*)d_in[14];
  const float* blk_x_w    = (const float*)d_in[15];
  const float* blk_x_b    = (const float*)d_in[16];
  const float* blk_out_w  = (const float*)d_in[17];
  const float* blk_out_b  = (const float*)d_in[18];
  const float* blk_ln2_w  = (const float*)d_in[19];
  const float* blk_ln2_b  = (const float*)d_in[20];
  const float* blk_mlp_w1 = (const float*)d_in[21];
  const float* blk_mlp_b1 = (const float*)d_in[22];
  const float* blk_mlp_w2 = (const float*)d_in[23];
  const float* blk_mlp_b2 = (const float*)d_in[24];
  const float* down1_w    = (const float*)d_in[25];
  const float* down1_b    = (const float*)d_in[26];
  const float* down2_w    = (const float*)d_in[27];
  const float* down2_b    = (const float*)d_in[28];
  const float* bott_w     = (const float*)d_in[29];
  const float* bott_b     = (const float*)d_in[30];
  const float* up1_w      = (const float*)d_in[31];
  const float* up1_b      = (const float*)d_in[32];
  const float* up2_w      = (const float*)d_in[33];
  const float* up2_b      = (const float*)d_in[34];
  const float* final_w    = (const float*)d_in[35];
  const float* final_b    = (const float*)d_in[36];

  // workspace layout (floats). total 34 MiFloats = 136 MiB.
  float* ws = (float*)d_ws;
  constexpr size_t F = 1u << 20;
  float* EMB  = ws;            // [B,L,128]   8F
  float* T1   = ws + 8 * F;    // xn / y / m  8F   (later: u1cat [B,256,32,32] uses 4F)
  float* T2   = ws + 16 * F;   // xp          8F   (later: u2cat [B,256,64,64] spans T2..T3)
  float* T3   = ws + 24 * F;   // z           8F   (T2..T3 contiguous -> mlp hidden [M,256])
  float* Ubuf = ws + 32 * F;   // u [M,16]    1F   (also xc scratch, later x2)
  float* HST  = ws + 33 * F;   // hs^T        1F   (later x2b)

  k_combine<<<256, 256, 0, stream>>>(x, Ubuf);
  k_embed<<<Mtok, 128, 0, stream>>>(Ubuf, emb_w, emb_b, pos_embed, time_embed, EMB);

  for (int i = 0; i < 2; i++) {
    k_ln<<<Mtok / 4, 256, 0, stream>>>(EMB, T1, blk_ln1_w + i * Dn, blk_ln1_b + i * Dn);
    k_dwconv<<<(Mtok * Dn) / 256, 256, 0, stream>>>(T1, EMB, blk_conv_w + i * Dn * 4, blk_conv_b + i * Dn);
    k_ln<<<Mtok / 4, 256, 0, stream>>>(EMB, T1, blk_sln_w + i * Dn, blk_sln_b + i * Dn);
    k_gemm<1><<<dim3(Mtok / 64, 4), 256, 0, stream>>>(T1, blk_in_w + (size_t)i * 256 * Dn,
                                                      blk_in_b + i * 256, T2, T3, 128, 256);
    k_u<<<Mtok / 16, 256, 0, stream>>>(T2, blk_x_w + i * DSn * Dn, blk_x_b + i * DSn, Ubuf);
    k_scan<<<Bn * DSn, 64, 0, stream>>>(Ubuf, HST, blk_A_log + i * DSn);
    k_y<<<Mtok / 2, 256, 0, stream>>>(HST, blk_D + i * DSn * Dn, T3, T1);
    k_gemm<3><<<dim3(Mtok / 64, 2), 256, 0, stream>>>(T1, blk_out_w + (size_t)i * Dn * Dn,
                                                      blk_out_b + i * Dn, EMB, nullptr, 128, 128);
    k_ln<<<Mtok / 4, 256, 0, stream>>>(EMB, T1, blk_ln2_w + i * Dn, blk_ln2_b + i * Dn);
    k_gemm<2><<<dim3(Mtok / 64, 4), 256, 0, stream>>>(T1, blk_mlp_w1 + (size_t)i * 256 * Dn,
                                                      blk_mlp_b1 + i * 256, T2, nullptr, 128, 256);
    k_gemm<3><<<dim3(Mtok / 64, 2), 256, 0, stream>>>(T2, blk_mlp_w2 + (size_t)i * Dn * 256,
                                                      blk_mlp_b2 + i * Dn, EMB, nullptr, 256, 128);
  }

  // UNet head. u2cat = [B,256,64,64] at T2 (sp in chans 128..255), u1cat = [B,256,32,32] at T1.
  float* U2C = T2;
  float* U1C = T1;
  float* X2  = Ubuf;
  float* X2B = HST;
  k_transpose<<<dim3(128, 4, 16), dim3(32, 8), 0, stream>>>(EMB, U2C);
  k_conv3x3<<<dim3(32, 16, 16), 256, 0, stream>>>(U2C + 128 * 4096, U1C + 128 * 1024, down1_w, down1_b,
                                                  128, 64, 64, 32, 32, 2, 256L * 4096, 256L * 1024);
  k_conv3x3<<<dim3(64, 4, 16), 256, 0, stream>>>(U1C + 128 * 1024, X2, down2_w, down2_b,
                                                 128, 32, 32, 16, 16, 2, 256L * 1024, 256L * 256);
  k_conv3x3<<<dim3(64, 4, 16), 256, 0, stream>>>(X2, X2B, bott_w, bott_b,
                                                 256, 16, 16, 16, 16, 1, 256L * 256, 256L * 256);
  k_convt<<<dim3(32, 16, 16), 256, 0, stream>>>(X2B, U1C, up1_w, up1_b, 256, 128, 16, 16,
                                                256L * 256, 256L * 1024);
  k_convt<<<dim3(32, 64, 16), 256, 0, stream>>>(U1C, U2C, up2_w, up2_b, 256, 128, 32, 32,
                                                256L * 1024, 256L * 4096);
  k_final<<<512, 256, 0, stream>>>(U2C, final_w, final_b, (float*)d_out);
}

// Round 2
// 3429.514 us; speedup vs baseline: 2.5197x; 2.5197x over previous
//
#include <hip/hip_runtime.h>
#include <cmath>

namespace {
constexpr int Bn = 16, Ln = 4096, Dn = 128, DSn = 16;
constexpr int Mtok = Bn * Ln; // 65536 tokens
}

// ---------------- embedding ----------------

// xc[b,p] = 0.5*(x0+x1+x2+x3) + x4
__global__ void k_combine(const float* __restrict__ x, float* __restrict__ xc) {
  int i = blockIdx.x * 256 + threadIdx.x; // B*HW = 65536
  int b = i >> 12, p = i & 4095;
  const float* xb = x + (size_t)b * 5 * Ln + p;
  xc[i] = 0.5f * (xb[0] + xb[Ln] + xb[2 * Ln] + xb[3 * Ln]) + xb[4 * Ln];
}

// emb[b,l,d] = conv3x3_1ch(xc)[d,l] + 3*(eb[d] + pos[l,d]) + (0.5*(t0..t3)+t4)[d]
__global__ void k_embed(const float* __restrict__ xc, const float* __restrict__ ew,
                        const float* __restrict__ eb, const float* __restrict__ pos,
                        const float* __restrict__ te, float* __restrict__ emb) {
  int l = blockIdx.x & 4095, b = blockIdx.x >> 12;
  int h = l >> 6, w = l & 63;
  int d = threadIdx.x;
  const float* xb = xc + b * Ln;
  float v[9];
#pragma unroll
  for (int dy = 0; dy < 3; dy++)
#pragma unroll
    for (int dx = 0; dx < 3; dx++) {
      int y = h + dy - 1, xx = w + dx - 1;
      v[dy * 3 + dx] = (y >= 0 && y < 64 && xx >= 0 && xx < 64) ? xb[y * 64 + xx] : 0.f;
    }
  float acc = 0.f;
#pragma unroll
  for (int k = 0; k < 9; k++) acc += v[k] * ew[d * 9 + k];
  float ts = 0.5f * (te[d] + te[128 + d] + te[256 + d] + te[384 + d]) + te[512 + d];
  emb[(size_t)blockIdx.x * Dn + d] = acc + 3.f * eb[d] + 3.f * pos[l * Dn + d] + ts;
}

// ---------------- layernorm (rows of 128) ----------------
__global__ __launch_bounds__(256) void k_ln(const float* __restrict__ in, float* __restrict__ out,
                                            const float* __restrict__ w, const float* __restrict__ bias) {
  int row = blockIdx.x * 4 + (threadIdx.x >> 6);
  int lane = threadIdx.x & 63;
  const float* p = in + (size_t)row * Dn;
  float2 v = *(const float2*)(p + lane * 2);
  float s = v.x + v.y, sq = v.x * v.x + v.y * v.y;
#pragma unroll
  for (int off = 32; off; off >>= 1) { s += __shfl_xor(s, off); sq += __shfl_xor(sq, off); }
  float m = s * (1.f / 128.f);
  float var = sq * (1.f / 128.f) - m * m;
  float r = rsqrtf(var + 1e-5f);
  int d = lane * 2;
  float2 o;
  o.x = (v.x - m) * r * w[d] + bias[d];
  o.y = (v.y - m) * r * w[d + 1] + bias[d + 1];
  *(float2*)(out + (size_t)row * Dn + d) = o;
}

// ---------------- causal depthwise conv1d k=4 + residual ----------------
__global__ void k_dwconv(const float* __restrict__ xn, float* __restrict__ emb,
                         const float* __restrict__ cw, const float* __restrict__ cb) {
  int i = blockIdx.x * 256 + threadIdx.x; // Mtok*128
  int d = i & 127;
  int l = (i >> 7) & 4095;
  const float* p = xn + i;
  float acc = cb[d] + cw[d * 4 + 3] * p[0];
  if (l >= 1) acc += cw[d * 4 + 2] * p[-128];
  if (l >= 2) acc += cw[d * 4 + 1] * p[-256];
  if (l >= 3) acc += cw[d * 4 + 0] * p[-384];
  emb[i] += acc;
}

// ---------------- generic GEMM: C[M,N] = A[M,K] @ W[N,K]^T (+ epilogues) ----------------
// MODE 0: bias               -> out[M,N]
// MODE 1: bias; col<128 silu -> out[M,128]; col>=128 sigmoid -> out2[M,128]
// MODE 2: bias; exact gelu   -> out[M,N]
// MODE 3: bias; accumulate   -> out[M,N] +=
template <int MODE>
__global__ __launch_bounds__(256) void k_gemm(const float* __restrict__ A, const float* __restrict__ W,
                                              const float* __restrict__ bias, float* __restrict__ out,
                                              float* __restrict__ out2, int K, int N) {
  __shared__ float As[16 * 68];
  __shared__ float Ws[16 * 68];
  const int m0 = blockIdx.x * 64, n0 = blockIdx.y * 64;
  const int t = threadIdx.x;
  const int tx = t & 15, ty = t >> 4;
  const int lr = t >> 2, kq = t & 3;
  float acc[4][4] = {};
  for (int k0 = 0; k0 < K; k0 += 16) {
    float4 av = *(const float4*)(A + (size_t)(m0 + lr) * K + k0 + kq * 4);
    float4 wv = *(const float4*)(W + (size_t)(n0 + lr) * K + k0 + kq * 4);
    __syncthreads();
    As[(kq * 4 + 0) * 68 + lr] = av.x;
    As[(kq * 4 + 1) * 68 + lr] = av.y;
    As[(kq * 4 + 2) * 68 + lr] = av.z;
    As[(kq * 4 + 3) * 68 + lr] = av.w;
    Ws[(kq * 4 + 0) * 68 + lr] = wv.x;
    Ws[(kq * 4 + 1) * 68 + lr] = wv.y;
    Ws[(kq * 4 + 2) * 68 + lr] = wv.z;
    Ws[(kq * 4 + 3) * 68 + lr] = wv.w;
    __syncthreads();
#pragma unroll
    for (int kk = 0; kk < 16; kk++) {
      float4 a4 = *(const float4*)&As[kk * 68 + ty * 4];
      float4 w4 = *(const float4*)&Ws[kk * 68 + tx * 4];
      float aa[4] = {a4.x, a4.y, a4.z, a4.w};
      float ww[4] = {w4.x, w4.y, w4.z, w4.w};
#pragma unroll
      for (int i = 0; i < 4; i++)
#pragma unroll
        for (int j = 0; j < 4; j++) acc[i][j] += aa[i] * ww[j];
    }
  }
#pragma unroll
  for (int i = 0; i < 4; i++) {
    const int row = m0 + ty * 4 + i;
    const int col = n0 + tx * 4;
    float v[4];
#pragma unroll
    for (int j = 0; j < 4; j++) v[j] = acc[i][j] + bias[col + j];
    if (MODE == 0) {
      float4 o = {v[0], v[1], v[2], v[3]};
      *(float4*)(out + (size_t)row * N + col) = o;
    } else if (MODE == 1) {
      float4 q;
      if (col < 128) {
        q.x = v[0] / (1.f + expf(-v[0]));
        q.y = v[1] / (1.f + expf(-v[1]));
        q.z = v[2] / (1.f + expf(-v[2]));
        q.w = v[3] / (1.f + expf(-v[3]));
        *(float4*)(out + (size_t)row * 128 + col) = q;
      } else {
        q.x = 1.f / (1.f + expf(-v[0]));
        q.y = 1.f / (1.f + expf(-v[1]));
        q.z = 1.f / (1.f + expf(-v[2]));
        q.w = 1.f / (1.f + expf(-v[3]));
        *(float4*)(out2 + (size_t)row * 128 + (col - 128)) = q;
      }
    } else if (MODE == 2) {
      float4 q;
      q.x = 0.5f * v[0] * (1.f + erff(v[0] * 0.7071067811865475f));
      q.y = 0.5f * v[1] * (1.f + erff(v[1] * 0.7071067811865475f));
      q.z = 0.5f * v[2] * (1.f + erff(v[2] * 0.7071067811865475f));
      q.w = 0.5f * v[3] * (1.f + erff(v[3] * 0.7071067811865475f));
      *(float4*)(out + (size_t)row * N + col) = q;
    } else {
      float4 cur = *(float4*)(out + (size_t)row * N + col);
      cur.x += v[0]; cur.y += v[1]; cur.z += v[2]; cur.w += v[3];
      *(float4*)(out + (size_t)row * N + col) = cur;
    }
  }
}

// ---------------- u = silu(xp) @ x_w^T + x_b  (N=16) ----------------
__global__ __launch_bounds__(256) void k_u(const float* __restrict__ XP, const float* __restrict__ xw,
                                           const float* __restrict__ xb, float* __restrict__ U) {
  __shared__ float xs[16 * 132];
  __shared__ float wsm[16 * 129];
  const int m0 = blockIdx.x * 16;
  const int t = threadIdx.x;
  for (int idx = t; idx < 2048; idx += 256) {
    wsm[(idx >> 7) * 129 + (idx & 127)] = xw[idx];
    xs[(idx >> 7) * 132 + (idx & 127)] = XP[(size_t)m0 * 128 + idx];
  }
  __syncthreads();
  const int ds = t & 15, ml = t >> 4;
  float acc = 0.f;
#pragma unroll 16
  for (int k = 0; k < 128; k++) acc += xs[ml * 132 + k] * wsm[ds * 129 + k];
  U[(size_t)(m0 + ml) * 16 + ds] = acc + xb[ds];
}

// ---------------- chunked parallel linear scan: h_t = a*h_{t-1} + u_t ----------------
// one block (64 lanes) per (b, ds); output transposed: HST[b][ds][L]
__global__ __launch_bounds__(64) void k_scan(const float* __restrict__ U, float* __restrict__ HST,
                                             const float* __restrict__ A_log) {
  __shared__ float lds[64 * 65]; // index t + (t>>6): conflict-free
  const int b = blockIdx.x >> 4, ds = blockIdx.x & 15;
  const int tid = threadIdx.x;
  const float a = expf(-expf(A_log[ds]));
  const float* ub = U + (size_t)b * Ln * 16 + ds;
  for (int j = 0; j < 64; j++) lds[j * 65 + tid] = ub[(size_t)(j * 64 + tid) * 16];
  __syncthreads();
  // local inclusive scan of this lane's 64-step chunk
  float h = 0.f;
  for (int j = 0; j < 64; j++) {
    h = a * h + lds[tid * 65 + j];
    lds[tid * 65 + j] = h;
  }
  // Kogge-Stone scan of affine segments (A=a^64, B=local final) across lanes
  float a64 = a;
#pragma unroll
  for (int q = 0; q < 6; q++) a64 *= a64;
  float Ac = a64, Bc = h;
#pragma unroll
  for (int off = 1; off < 64; off <<= 1) {
    float Ap = __shfl_up(Ac, off);
    float Bp = __shfl_up(Bc, off);
    if (tid >= off) { Bc = Ac * Bp + Bc; Ac = Ac * Ap; }
  }
  float carry = __shfl_up(Bc, 1); // H_{tid-1}
  if (tid == 0) carry = 0.f;
  float p = a;
  for (int j = 0; j < 64; j++) {
    lds[tid * 65 + j] += p * carry;
    p *= a;
  }
  __syncthreads();
  float* hb = HST + (size_t)(b * 16 + ds) * Ln;
  for (int j = 0; j < 64; j++) hb[j * 64 + tid] = lds[j * 65 + tid];
}

// ---------------- y = (hs @ D) * z ----------------
__global__ __launch_bounds__(256) void k_y(const float* __restrict__ HST, const float* __restrict__ Dm_,
                                           const float* __restrict__ Z, float* __restrict__ Y) {
  const int m = blockIdx.x * 2 + (threadIdx.x >> 7);
  const int d = threadIdx.x & 127;
  const int b = m >> 12, l = m & 4095;
  const float* hb = HST + (size_t)b * 16 * Ln + l;
  float acc = 0.f;
#pragma unroll
  for (int s = 0; s < 16; s++) acc += hb[(size_t)s * Ln] * Dm_[s * 128 + d];
  const size_t o = (size_t)m * 128 + d;
  Y[o] = acc * Z[o];
}

// ---------------- [B,L,D] -> sp at channels 128.. of u2cat [B,256,H,W] ----------------
__global__ void k_transpose(const float* __restrict__ emb, float* __restrict__ u2c) {
  __shared__ float tile[32][33];
  int l0 = blockIdx.x * 32, d0 = blockIdx.y * 32, b = blockIdx.z;
  int tx = threadIdx.x, ty = threadIdx.y;
#pragma unroll
  for (int i = 0; i < 4; i++) {
    int ll = ty + i * 8;
    tile[ll][tx] = emb[((size_t)b * 4096 + l0 + ll) * 128 + d0 + tx];
  }
  __syncthreads();
#pragma unroll
  for (int i = 0; i < 4; i++) {
    int dd = ty + i * 8;
    u2c[((size_t)b * 256 + 128 + d0 + dd) * 4096 + l0 + tx] = tile[tx][dd];
  }
}

// ---------------- weight pre-transposes ----------------
// conv OIHW w[co][ci][9] -> WT[ci][tap][co]
__global__ void k_wtc(const float* __restrict__ w, float* __restrict__ WT, int Cin, int Cout) {
  int i = blockIdx.x * 256 + threadIdx.x;
  if (i >= Cout * Cin * 9) return;
  int co = i / (Cin * 9);
  int rem = i - co * Cin * 9;
  int ci = rem / 9, tap = rem - ci * 9;
  WT[((size_t)ci * 9 + tap) * Cout + co] = w[i];
}
// convT w[ci][co][16] -> WT[tap][ci][co]
__global__ void k_wtt(const float* __restrict__ w, float* __restrict__ WT, int Cin, int Cout) {
  int i = blockIdx.x * 256 + threadIdx.x;
  if (i >= Cin * Cout * 16) return;
  int ci = i / (Cout * 16);
  int rem = i - ci * Cout * 16;
  int co = rem >> 4, tap = rem & 15;
  WT[((size_t)tap * Cin + ci) * Cout + co] = w[i];
}

// ---------------- staged 3x3 conv (pad 1, stride 1 or 2) + relu ----------------
// block: 32 Cout x 16x16 output tile; WT layout [ci][tap][co]
template <int STRIDE>
__global__ __launch_bounds__(256) void k_conv3s(const float* __restrict__ in, float* __restrict__ out,
                                                const float* __restrict__ WT, const float* __restrict__ bias,
                                                int Cin, int Cout, int Hi, int Wi, int nsp, int nspx,
                                                long in_bstride, long out_bstride) {
  constexpr int WR = 15 * STRIDE + 3;            // 18 (s1) / 33 (s2)
  constexpr int WSTR = (STRIDE == 2) ? 35 : 19;  // bank-spread padding
  __shared__ float in_s[4][WR][WSTR];
  __shared__ float wl[4][9][32];
  const int b = blockIdx.z;
  const int cb = blockIdx.x / nsp;
  const int spt = blockIdx.x - cb * nsp;
  const int spy = spt / nspx, spx = spt - spy * nspx;
  const int Wo = Wi / STRIDE;
  const int t = threadIdx.x;
  const int co_id = t >> 3, sp_id = t & 7;
  const int r0 = (sp_id >> 1) * 4, c0 = (sp_id & 1) * 8;
  const float* ib = in + (size_t)b * in_bstride;
  float acc[4][8] = {};
  for (int ci0 = 0; ci0 < Cin; ci0 += 4) {
    __syncthreads();
    for (int idx = t; idx < 4 * WR * WR; idx += 256) {
      int ci = idx / (WR * WR);
      int rem = idx - ci * (WR * WR);
      int wy = rem / WR, wx = rem - wy * WR;
      int iy = spy * 16 * STRIDE - 1 + wy;
      int ix = spx * 16 * STRIDE - 1 + wx;
      float v = 0.f;
      if ((unsigned)iy < (unsigned)Hi && (unsigned)ix < (unsigned)Wi)
        v = ib[(size_t)(ci0 + ci) * Hi * Wi + iy * Wi + ix];
      in_s[ci][wy][wx] = v;
    }
    for (int idx = t; idx < 4 * 9 * 32; idx += 256) {
      int co = idx & 31;
      int q = idx >> 5;
      int ci = q / 9, tap = q - ci * 9;
      wl[ci][tap][co] = WT[((size_t)(ci0 + ci) * 9 + tap) * Cout + cb * 32 + co];
    }
    __syncthreads();
#pragma unroll
    for (int ci = 0; ci < 4; ci++) {
      float wv[9];
#pragma unroll
      for (int q = 0; q < 9; q++) wv[q] = wl[ci][q][co_id];
#pragma unroll
      for (int r = 0; r < 4; r++) {
#pragma unroll
        for (int dy = 0; dy < 3; dy++) {
          const float* rp = &in_s[ci][(r0 + r) * STRIDE + dy][c0 * STRIDE];
#pragma unroll
          for (int c = 0; c < 8; c++) {
#pragma unroll
            for (int dx = 0; dx < 3; dx++) acc[r][c] += wv[dy * 3 + dx] * rp[c * STRIDE + dx];
          }
        }
      }
    }
  }
  const int co = cb * 32 + co_id;
  const float bb = bias[co];
  float* ob = out + (size_t)b * out_bstride + (size_t)co * (size_t)(Hi / STRIDE) * Wo;
#pragma unroll
  for (int r = 0; r < 4; r++)
#pragma unroll
    for (int c = 0; c < 8; c++)
      ob[(spy * 16 + r0 + r) * Wo + spx * 16 + c0 + c] = fmaxf(acc[r][c] + bb, 0.f);
}

// ---------------- parity-decomposed ConvTranspose2d k=4 s=2 p=1 + relu ----------------
// WT layout [16 taps][Cin][Cout]; grid: x = cb*nsp + spt, y = parity(4), z = b
__global__ __launch_bounds__(256) void k_convt2(const float* __restrict__ in, float* __restrict__ out,
                                                const float* __restrict__ WT, const float* __restrict__ bias,
                                                int Cin, int Cout, int Hi, int Wi, int nsp, int nspx,
                                                long in_bstride, long out_bstride) {
  __shared__ float in_s[16][17][20];
  __shared__ float wl[2][2][16][32];
  const int b = blockIdx.z;
  const int py = blockIdx.y >> 1, px = blockIdx.y & 1;
  const int cb = blockIdx.x / nsp;
  const int spt = blockIdx.x - cb * nsp;
  const int spy = spt / nspx, spx = spt - spy * nspx;
  const int y0t = spy * 16, x0t = spx * 16;
  const int t = threadIdx.x;
  const int co_id = t >> 3, sp_id = t & 7;
  const int r0 = (sp_id >> 1) * 4, c0 = (sp_id & 1) * 8;
  const float* ib = in + (size_t)b * in_bstride;
  float acc[4][8] = {};
  for (int ci0 = 0; ci0 < Cin; ci0 += 16) {
    __syncthreads();
    for (int idx = t; idx < 16 * 17 * 17; idx += 256) {
      int ci = idx / 289;
      int rem = idx - ci * 289;
      int wy = rem / 17, wx = rem - wy * 17;
      int iy = y0t + py - 1 + wy, ix = x0t + px - 1 + wx;
      float v = 0.f;
      if ((unsigned)iy < (unsigned)Hi && (unsigned)ix < (unsigned)Wi)
        v = ib[(size_t)(ci0 + ci) * Hi * Wi + iy * Wi + ix];
      in_s[ci][wy][wx] = v;
    }
    for (int idx = t; idx < 2048; idx += 256) {
      int dd = idx >> 9;  // d*2+e
      int ci = (idx >> 5) & 15;
      int co = idx & 31;
      int d = dd >> 1, e = dd & 1;
      int tap = (3 - py - 2 * d) * 4 + (3 - px - 2 * e);
      wl[d][e][ci][co] = WT[((size_t)tap * Cin + ci0 + ci) * Cout + cb * 32 + co];
    }
    __syncthreads();
#pragma unroll
    for (int ci = 0; ci < 16; ci++) {
      float w00 = wl[0][0][ci][co_id], w01 = wl[0][1][ci][co_id];
      float w10 = wl[1][0][ci][co_id], w11 = wl[1][1][ci][co_id];
#pragma unroll
      for (int r = 0; r < 4; r++) {
#pragma unroll
        for (int c = 0; c < 8; c++) {
          float t00 = in_s[ci][r0 + r][c0 + c], t01 = in_s[ci][r0 + r][c0 + c + 1];
          float t10 = in_s[ci][r0 + r + 1][c0 + c], t11 = in_s[ci][r0 + r + 1][c0 + c + 1];
          acc[r][c] += w00 * t00 + w01 * t01 + w10 * t10 + w11 * t11;
        }
      }
    }
  }
  const int co = cb * 32 + co_id;
  const float bb = bias[co];
  const int Wo = Wi * 2;
  float* ob = out + (size_t)b * out_bstride + (size_t)co * (size_t)(Hi * 2) * Wo;
#pragma unroll
  for (int r = 0; r < 4; r++)
#pragma unroll
    for (int c = 0; c < 8; c++) {
      int oy = (y0t + r0 + r) * 2 + py;
      int ox = (x0t + c0 + c) * 2 + px;
      ob[oy * Wo + ox] = fmaxf(acc[r][c] + bb, 0.f);
    }
}

// ---------------- final 1x1 conv 256 -> 2 ----------------
__global__ void k_final(const float* __restrict__ in, const float* __restrict__ w,
                        const float* __restrict__ bias, float* __restrict__ out) {
  int i = blockIdx.x * 256 + threadIdx.x; // B*2*4096
  int p = i & 4095;
  int nc = (i >> 12) & 1;
  int b = i >> 13;
  const float* ib = in + (size_t)b * 256 * 4096 + p;
  const float* wr = w + nc * 256;
  float acc = bias[nc];
  for (int c = 0; c < 256; c++) acc += ib[(size_t)c * 4096] * wr[c];
  out[i] = acc;
}

extern "C" void kernel_launch(void* const* d_in, const int* in_sizes, int n_in,
                              void* d_out, int out_size, void* d_ws, size_t ws_size,
                              hipStream_t stream) {
  (void)in_sizes; (void)n_in; (void)out_size; (void)ws_size;
  const float* x          = (const float*)d_in[0];
  const float* emb_w      = (const float*)d_in[1];
  const float* emb_b      = (const float*)d_in[2];
  const float* pos_embed  = (const float*)d_in[3];
  const float* time_embed = (const float*)d_in[4];
  const float* blk_ln1_w  = (const float*)d_in[5];
  const float* blk_ln1_b  = (const float*)d_in[6];
  const float* blk_conv_w = (const float*)d_in[7];
  const float* blk_conv_b = (const float*)d_in[8];
  const float* blk_sln_w  = (const float*)d_in[9];
  const float* blk_sln_b  = (const float*)d_in[10];
  const float* blk_A_log  = (const float*)d_in[11];
  const float* blk_D      = (const float*)d_in[12];
  const float* blk_in_w   = (const float*)d_in[13];
  const float* blk_in_b   = (const float*)d_in[14];
  const float* blk_x_w    = (const float*)d_in[15];
  const float* blk_x_b    = (const float*)d_in[16];
  const float* blk_out_w  = (const float*)d_in[17];
  const float* blk_out_b  = (const float*)d_in[18];
  const float* blk_ln2_w  = (const float*)d_in[19];
  const float* blk_ln2_b  = (const float*)d_in[20];
  const float* blk_mlp_w1 = (const float*)d_in[21];
  const float* blk_mlp_b1 = (const float*)d_in[22];
  const float* blk_mlp_w2 = (const float*)d_in[23];
  const float* blk_mlp_b2 = (const float*)d_in[24];
  const float* down1_w    = (const float*)d_in[25];
  const float* down1_b    = (const float*)d_in[26];
  const float* down2_w    = (const float*)d_in[27];
  const float* down2_b    = (const float*)d_in[28];
  const float* bott_w     = (const float*)d_in[29];
  const float* bott_b     = (const float*)d_in[30];
  const float* up1_w      = (const float*)d_in[31];
  const float* up1_b      = (const float*)d_in[32];
  const float* up2_w      = (const float*)d_in[33];
  const float* up2_b      = (const float*)d_in[34];
  const float* final_w    = (const float*)d_in[35];
  const float* final_b    = (const float*)d_in[36];

  // workspace layout (floats). total 34 MiFloats = 136 MiB.
  float* ws = (float*)d_ws;
  constexpr size_t F = 1u << 20;
  float* EMB  = ws;            // [B,L,128]   8F   (UNet phase: weight-transpose scratch)
  float* T1   = ws + 8 * F;    // xn / y / m  8F   (later: u1cat [B,256,32,32] uses 4F)
  float* T2   = ws + 16 * F;   // xp          8F   (later: u2cat [B,256,64,64] spans T2..T3)
  float* T3   = ws + 24 * F;   // z           8F   (T2..T3 contiguous -> mlp hidden [M,256])
  float* Ubuf = ws + 32 * F;   // u [M,16]    1F   (also xc scratch, later x2)
  float* HST  = ws + 33 * F;   // hs^T        1F   (later x2b)

  k_combine<<<256, 256, 0, stream>>>(x, Ubuf);
  k_embed<<<Mtok, 128, 0, stream>>>(Ubuf, emb_w, emb_b, pos_embed, time_embed, EMB);

  for (int i = 0; i < 2; i++) {
    k_ln<<<Mtok / 4, 256, 0, stream>>>(EMB, T1, blk_ln1_w + i * Dn, blk_ln1_b + i * Dn);
    k_dwconv<<<(Mtok * Dn) / 256, 256, 0, stream>>>(T1, EMB, blk_conv_w + i * Dn * 4, blk_conv_b + i * Dn);
    k_ln<<<Mtok / 4, 256, 0, stream>>>(EMB, T1, blk_sln_w + i * Dn, blk_sln_b + i * Dn);
    k_gemm<1><<<dim3(Mtok / 64, 4), 256, 0, stream>>>(T1, blk_in_w + (size_t)i * 256 * Dn,
                                                      blk_in_b + i * 256, T2, T3, 128, 256);
    k_u<<<Mtok / 16, 256, 0, stream>>>(T2, blk_x_w + i * DSn * Dn, blk_x_b + i * DSn, Ubuf);
    k_scan<<<Bn * DSn, 64, 0, stream>>>(Ubuf, HST, blk_A_log + i * DSn);
    k_y<<<Mtok / 2, 256, 0, stream>>>(HST, blk_D + i * DSn * Dn, T3, T1);
    k_gemm<3><<<dim3(Mtok / 64, 2), 256, 0, stream>>>(T1, blk_out_w + (size_t)i * Dn * Dn,
                                                      blk_out_b + i * Dn, EMB, nullptr, 128, 128);
    k_ln<<<Mtok / 4, 256, 0, stream>>>(EMB, T1, blk_ln2_w + i * Dn, blk_ln2_b + i * Dn);
    k_gemm<2><<<dim3(Mtok / 64, 4), 256, 0, stream>>>(T1, blk_mlp_w1 + (size_t)i * 256 * Dn,
                                                      blk_mlp_b1 + i * 256, T2, nullptr, 128, 256);
    k_gemm<3><<<dim3(Mtok / 64, 2), 256, 0, stream>>>(T2, blk_mlp_w2 + (size_t)i * Dn * 256,
                                                      blk_mlp_b2 + i * Dn, EMB, nullptr, 256, 128);
  }

  // UNet head. u2cat = [B,256,64,64] at T2 (sp in chans 128..255), u1cat = [B,256,32,32] at T1.
  float* U2C = T2;
  float* U1C = T1;
  float* X2  = Ubuf;
  float* X2B = HST;
  k_transpose<<<dim3(128, 4, 16), dim3(32, 8), 0, stream>>>(EMB, U2C);

  // EMB region is now free -> weight transposes live there
  float* WTd1 = EMB;                 // 128*128*9  = 147456
  float* WTd2 = EMB + 524288;        // 256*128*9  = 294912
  float* WTb  = EMB + 1048576;       // 256*256*9  = 589824
  float* WTu1 = EMB + 2097152;       // 16*256*128 = 524288
  float* WTu2 = EMB + 3145728;       // 16*256*128 = 524288
  k_wtc<<<(128 * 128 * 9 + 255) / 256, 256, 0, stream>>>(down1_w, WTd1, 128, 128);
  k_wtc<<<(256 * 128 * 9 + 255) / 256, 256, 0, stream>>>(down2_w, WTd2, 128, 256);
  k_wtc<<<(256 * 256 * 9 + 255) / 256, 256, 0, stream>>>(bott_w, WTb, 256, 256);
  k_wtt<<<(256 * 128 * 16 + 255) / 256, 256, 0, stream>>>(up1_w, WTu1, 256, 128);
  k_wtt<<<(256 * 128 * 16 + 255) / 256, 256, 0, stream>>>(up2_w, WTu2, 256, 128);

  // down1: in U2C chans 128.. (64x64,128ch) -> U1C chans 128.. (32x32)
  k_conv3s<2><<<dim3(4 * 4, 1, 16), 256, 0, stream>>>(U2C + 128 * 4096, U1C + 128 * 1024, WTd1, down1_b,
                                                      128, 128, 64, 64, 4, 2, 256L * 4096, 256L * 1024);
  // down2: U1C chans 128.. (32x32,128ch) -> X2 (16x16,256ch)
  k_conv3s<2><<<dim3(8, 1, 16), 256, 0, stream>>>(U1C + 128 * 1024, X2, WTd2, down2_b,
                                                  128, 256, 32, 32, 1, 1, 256L * 1024, 256L * 256);
  // bott: X2 -> X2B (16x16,256ch)
  k_conv3s<1><<<dim3(8, 1, 16), 256, 0, stream>>>(X2, X2B, WTb, bott_b,
                                                  256, 256, 16, 16, 1, 1, 256L * 256, 256L * 256);
  // up1: X2B (16x16,256ch) -> U1C chans 0..127 (32x32)
  k_convt2<<<dim3(4, 4, 16), 256, 0, stream>>>(X2B, U1C, WTu1, up1_b,
                                               256, 128, 16, 16, 1, 1, 256L * 256, 256L * 1024);
  // up2: U1C (32x32,256ch) -> U2C chans 0..127 (64x64)
  k_convt2<<<dim3(4 * 4, 4, 16), 256, 0, stream>>>(U1C, U2C, WTu2, up2_b,
                                                   256, 128, 32, 32, 4, 2, 256L * 1024, 256L * 4096);
  k_final<<<512, 256, 0, stream>>>(U2C, final_w, final_b, (float*)d_out);
}

// Round 3
// 1064.863 us; speedup vs baseline: 8.1150x; 3.2206x over previous
//
#include <hip/hip_runtime.h>
#include <cmath>

namespace {
constexpr int Bn = 16, Ln = 4096, Dn = 128, DSn = 16;
constexpr int Mtok = Bn * Ln; // 65536 tokens
}

typedef short bfx8 __attribute__((ext_vector_type(8)));
typedef float f32x4 __attribute__((ext_vector_type(4)));

static __device__ __forceinline__ ushort f2bf(float f) {
  union { float f; unsigned u; } v; v.f = f;
  unsigned r = v.u + 0x7fff + ((v.u >> 16) & 1);
  return (ushort)(r >> 16);
}
static __device__ __forceinline__ float bf2f(ushort u) {
  union { unsigned u; float f; } v; v.u = ((unsigned)u) << 16;
  return v.f;
}

// ---------------- embedding ----------------

// xc[b,p] = 0.5*(x0+x1+x2+x3) + x4
__global__ void k_combine(const float* __restrict__ x, float* __restrict__ xc) {
  int i = blockIdx.x * 256 + threadIdx.x; // B*HW = 65536
  int b = i >> 12, p = i & 4095;
  const float* xb = x + (size_t)b * 5 * Ln + p;
  xc[i] = 0.5f * (xb[0] + xb[Ln] + xb[2 * Ln] + xb[3 * Ln]) + xb[4 * Ln];
}

// emb[b,l,d] = conv3x3_1ch(xc)[d,l] + 3*(eb[d] + pos[l,d]) + (0.5*(t0..t3)+t4)[d]
__global__ void k_embed(const float* __restrict__ xc, const float* __restrict__ ew,
                        const float* __restrict__ eb, const float* __restrict__ pos,
                        const float* __restrict__ te, float* __restrict__ emb) {
  int l = blockIdx.x & 4095, b = blockIdx.x >> 12;
  int h = l >> 6, w = l & 63;
  int d = threadIdx.x;
  const float* xb = xc + b * Ln;
  float v[9];
#pragma unroll
  for (int dy = 0; dy < 3; dy++)
#pragma unroll
    for (int dx = 0; dx < 3; dx++) {
      int y = h + dy - 1, xx = w + dx - 1;
      v[dy * 3 + dx] = (y >= 0 && y < 64 && xx >= 0 && xx < 64) ? xb[y * 64 + xx] : 0.f;
    }
  float acc = 0.f;
#pragma unroll
  for (int k = 0; k < 9; k++) acc += v[k] * ew[d * 9 + k];
  float ts = 0.5f * (te[d] + te[128 + d] + te[256 + d] + te[384 + d]) + te[512 + d];
  emb[(size_t)blockIdx.x * Dn + d] = acc + 3.f * eb[d] + 3.f * pos[l * Dn + d] + ts;
}

// ---------------- layernorm (rows of 128) ----------------
__global__ __launch_bounds__(256) void k_ln(const float* __restrict__ in, float* __restrict__ out,
                                            const float* __restrict__ w, const float* __restrict__ bias) {
  int row = blockIdx.x * 4 + (threadIdx.x >> 6);
  int lane = threadIdx.x & 63;
  const float* p = in + (size_t)row * Dn;
  float2 v = *(const float2*)(p + lane * 2);
  float s = v.x + v.y, sq = v.x * v.x + v.y * v.y;
#pragma unroll
  for (int off = 32; off; off >>= 1) { s += __shfl_xor(s, off); sq += __shfl_xor(sq, off); }
  float m = s * (1.f / 128.f);
  float var = sq * (1.f / 128.f) - m * m;
  float r = rsqrtf(var + 1e-5f);
  int d = lane * 2;
  float2 o;
  o.x = (v.x - m) * r * w[d] + bias[d];
  o.y = (v.y - m) * r * w[d + 1] + bias[d + 1];
  *(float2*)(out + (size_t)row * Dn + d) = o;
}

// ---------------- causal depthwise conv1d k=4 + residual ----------------
__global__ void k_dwconv(const float* __restrict__ xn, float* __restrict__ emb,
                         const float* __restrict__ cw, const float* __restrict__ cb) {
  int i = blockIdx.x * 256 + threadIdx.x; // Mtok*128
  int d = i & 127;
  int l = (i >> 7) & 4095;
  const float* p = xn + i;
  float acc = cb[d] + cw[d * 4 + 3] * p[0];
  if (l >= 1) acc += cw[d * 4 + 2] * p[-128];
  if (l >= 2) acc += cw[d * 4 + 1] * p[-256];
  if (l >= 3) acc += cw[d * 4 + 0] * p[-384];
  emb[i] += acc;
}

// ---------------- generic GEMM: C[M,N] = A[M,K] @ W[N,K]^T (+ epilogues) ----------------
// MODE 0: bias               -> out[M,N]
// MODE 1: bias; col<128 silu -> out[M,128]; col>=128 sigmoid -> out2[M,128]
// MODE 2: bias; exact gelu   -> out[M,N]
// MODE 3: bias; accumulate   -> out[M,N] +=
template <int MODE>
__global__ __launch_bounds__(256) void k_gemm(const float* __restrict__ A, const float* __restrict__ W,
                                              const float* __restrict__ bias, float* __restrict__ out,
                                              float* __restrict__ out2, int K, int N) {
  __shared__ float As[16 * 68];
  __shared__ float Ws[16 * 68];
  const int m0 = blockIdx.x * 64, n0 = blockIdx.y * 64;
  const int t = threadIdx.x;
  const int tx = t & 15, ty = t >> 4;
  const int lr = t >> 2, kq = t & 3;
  float acc[4][4] = {};
  for (int k0 = 0; k0 < K; k0 += 16) {
    float4 av = *(const float4*)(A + (size_t)(m0 + lr) * K + k0 + kq * 4);
    float4 wv = *(const float4*)(W + (size_t)(n0 + lr) * K + k0 + kq * 4);
    __syncthreads();
    As[(kq * 4 + 0) * 68 + lr] = av.x;
    As[(kq * 4 + 1) * 68 + lr] = av.y;
    As[(kq * 4 + 2) * 68 + lr] = av.z;
    As[(kq * 4 + 3) * 68 + lr] = av.w;
    Ws[(kq * 4 + 0) * 68 + lr] = wv.x;
    Ws[(kq * 4 + 1) * 68 + lr] = wv.y;
    Ws[(kq * 4 + 2) * 68 + lr] = wv.z;
    Ws[(kq * 4 + 3) * 68 + lr] = wv.w;
    __syncthreads();
#pragma unroll
    for (int kk = 0; kk < 16; kk++) {
      float4 a4 = *(const float4*)&As[kk * 68 + ty * 4];
      float4 w4 = *(const float4*)&Ws[kk * 68 + tx * 4];
      float aa[4] = {a4.x, a4.y, a4.z, a4.w};
      float ww[4] = {w4.x, w4.y, w4.z, w4.w};
#pragma unroll
      for (int i = 0; i < 4; i++)
#pragma unroll
        for (int j = 0; j < 4; j++) acc[i][j] += aa[i] * ww[j];
    }
  }
#pragma unroll
  for (int i = 0; i < 4; i++) {
    const int row = m0 + ty * 4 + i;
    const int col = n0 + tx * 4;
    float v[4];
#pragma unroll
    for (int j = 0; j < 4; j++) v[j] = acc[i][j] + bias[col + j];
    if (MODE == 0) {
      float4 o = {v[0], v[1], v[2], v[3]};
      *(float4*)(out + (size_t)row * N + col) = o;
    } else if (MODE == 1) {
      float4 q;
      if (col < 128) {
        q.x = v[0] / (1.f + expf(-v[0]));
        q.y = v[1] / (1.f + expf(-v[1]));
        q.z = v[2] / (1.f + expf(-v[2]));
        q.w = v[3] / (1.f + expf(-v[3]));
        *(float4*)(out + (size_t)row * 128 + col) = q;
      } else {
        q.x = 1.f / (1.f + expf(-v[0]));
        q.y = 1.f / (1.f + expf(-v[1]));
        q.z = 1.f / (1.f + expf(-v[2]));
        q.w = 1.f / (1.f + expf(-v[3]));
        *(float4*)(out2 + (size_t)row * 128 + (col - 128)) = q;
      }
    } else if (MODE == 2) {
      float4 q;
      q.x = 0.5f * v[0] * (1.f + erff(v[0] * 0.7071067811865475f));
      q.y = 0.5f * v[1] * (1.f + erff(v[1] * 0.7071067811865475f));
      q.z = 0.5f * v[2] * (1.f + erff(v[2] * 0.7071067811865475f));
      q.w = 0.5f * v[3] * (1.f + erff(v[3] * 0.7071067811865475f));
      *(float4*)(out + (size_t)row * N + col) = q;
    } else {
      float4 cur = *(float4*)(out + (size_t)row * N + col);
      cur.x += v[0]; cur.y += v[1]; cur.z += v[2]; cur.w += v[3];
      *(float4*)(out + (size_t)row * N + col) = cur;
    }
  }
}

// ---------------- u = silu(xp) @ x_w^T + x_b  (N=16) ----------------
__global__ __launch_bounds__(256) void k_u(const float* __restrict__ XP, const float* __restrict__ xw,
                                           const float* __restrict__ xb, float* __restrict__ U) {
  __shared__ float xs[16 * 132];
  __shared__ float wsm[16 * 129];
  const int m0 = blockIdx.x * 16;
  const int t = threadIdx.x;
  for (int idx = t; idx < 2048; idx += 256) {
    wsm[(idx >> 7) * 129 + (idx & 127)] = xw[idx];
    xs[(idx >> 7) * 132 + (idx & 127)] = XP[(size_t)m0 * 128 + idx];
  }
  __syncthreads();
  const int ds = t & 15, ml = t >> 4;
  float acc = 0.f;
#pragma unroll 16
  for (int k = 0; k < 128; k++) acc += xs[ml * 132 + k] * wsm[ds * 129 + k];
  U[(size_t)(m0 + ml) * 16 + ds] = acc + xb[ds];
}

// ---------------- chunked parallel linear scan: h_t = a*h_{t-1} + u_t ----------------
__global__ __launch_bounds__(64) void k_scan(const float* __restrict__ U, float* __restrict__ HST,
                                             const float* __restrict__ A_log) {
  __shared__ float lds[64 * 65];
  const int b = blockIdx.x >> 4, ds = blockIdx.x & 15;
  const int tid = threadIdx.x;
  const float a = expf(-expf(A_log[ds]));
  const float* ub = U + (size_t)b * Ln * 16 + ds;
  for (int j = 0; j < 64; j++) lds[j * 65 + tid] = ub[(size_t)(j * 64 + tid) * 16];
  __syncthreads();
  float h = 0.f;
  for (int j = 0; j < 64; j++) {
    h = a * h + lds[tid * 65 + j];
    lds[tid * 65 + j] = h;
  }
  float a64 = a;
#pragma unroll
  for (int q = 0; q < 6; q++) a64 *= a64;
  float Ac = a64, Bc = h;
#pragma unroll
  for (int off = 1; off < 64; off <<= 1) {
    float Ap = __shfl_up(Ac, off);
    float Bp = __shfl_up(Bc, off);
    if (tid >= off) { Bc = Ac * Bp + Bc; Ac = Ac * Ap; }
  }
  float carry = __shfl_up(Bc, 1);
  if (tid == 0) carry = 0.f;
  float p = a;
  for (int j = 0; j < 64; j++) {
    lds[tid * 65 + j] += p * carry;
    p *= a;
  }
  __syncthreads();
  float* hb = HST + (size_t)(b * 16 + ds) * Ln;
  for (int j = 0; j < 64; j++) hb[j * 64 + tid] = lds[j * 65 + tid];
}

// ---------------- y = (hs @ D) * z ----------------
__global__ __launch_bounds__(256) void k_y(const float* __restrict__ HST, const float* __restrict__ Dm_,
                                           const float* __restrict__ Z, float* __restrict__ Y) {
  const int m = blockIdx.x * 2 + (threadIdx.x >> 7);
  const int d = threadIdx.x & 127;
  const int b = m >> 12, l = m & 4095;
  const float* hb = HST + (size_t)b * 16 * Ln + l;
  float acc = 0.f;
#pragma unroll
  for (int s = 0; s < 16; s++) acc += hb[(size_t)s * Ln] * Dm_[s * 128 + d];
  const size_t o = (size_t)m * 128 + d;
  Y[o] = acc * Z[o];
}

// ---------------- fp32 [B,HW,128] -> bf16 channels-last slot [B,HW,256] at +128 ----------------
__global__ void k_tobf(const float* __restrict__ in, ushort* __restrict__ out) {
  int i = blockIdx.x * 256 + threadIdx.x; // Mtok*32
  int row = i >> 5, c4 = (i & 31) * 4;
  float4 v = *(const float4*)(in + (size_t)row * 128 + c4);
  ushort4 o;
  o.x = f2bf(v.x); o.y = f2bf(v.y); o.z = f2bf(v.z); o.w = f2bf(v.w);
  *(ushort4*)(out + (size_t)row * 256 + 128 + c4) = o;
}

// ---------------- weight converts to bf16 [tap][Cout][Cin] ----------------
// conv 3x3: w[co][ci][9]
__global__ void k_wc9(const float* __restrict__ w, ushort* __restrict__ Wb, int Cin, int Cout) {
  int i = blockIdx.x * 256 + threadIdx.x;
  if (i >= Cout * Cin * 9) return;
  int co = i / (Cin * 9);
  int r = i - co * (Cin * 9);
  int ci = r / 9, tap = r - ci * 9;
  Wb[((size_t)tap * Cout + co) * Cin + ci] = f2bf(w[i]);
}
// convT: w[ci][co][16]
__global__ void k_wc16(const float* __restrict__ w, ushort* __restrict__ Wb, int Cin, int Cout) {
  int i = blockIdx.x * 256 + threadIdx.x;
  if (i >= Cin * Cout * 16) return;
  int ci = i / (Cout * 16);
  int r = i - ci * (Cout * 16);
  int co = r >> 4, tap = r & 15;
  Wb[((size_t)tap * Cout + co) * Cin + ci] = f2bf(w[i]);
}

// ---------------- implicit-GEMM MFMA conv, channels-last bf16, no LDS ----------------
// MODE 0: 3x3 pad1 s1 | MODE 1: 3x3 pad1 s2 | MODE 2: convT k4 s2 p1 (parity = blockIdx.y)
// wave tile: 32 spatial x 32 cout. wt layout [tapw][Cout][Cin]. relu always.
template <int MODE>
__global__ __launch_bounds__(256) void k_cmfma(
    const ushort* __restrict__ in, ushort* __restrict__ out,
    const ushort* __restrict__ wt, const float* __restrict__ bias,
    int Hi, int Wi, int lw, int NT, int CP, int CO, int Cin,
    int CPo, int COo, int Cout, long ibs, long obs) {
  const int t = threadIdx.x;
  const int l = t & 63;
  const int wid = (blockIdx.x * 256 + t) >> 6;
  const int nt = wid % NT, mt = wid / NT;
  const int b = blockIdx.z;
  const int py = blockIdx.y >> 1, px = blockIdx.y & 1;
  const int l15 = l & 15, q = l >> 4;
  const int Wt = 1 << lw;
  const int m0 = mt * 32, n0 = nt * 32;
  f32x4 acc[2][2] = {};
  const ushort* ib = in + (size_t)b * ibs;
  int oy[2], ox[2];
  oy[0] = (m0 + l15) >> lw; ox[0] = (m0 + l15) & (Wt - 1);
  oy[1] = (m0 + 16 + l15) >> lw; ox[1] = (m0 + 16 + l15) & (Wt - 1);
  constexpr int NTAPS = (MODE == 2) ? 4 : 9;
  const bfx8 zf = {0, 0, 0, 0, 0, 0, 0, 0};
#pragma unroll
  for (int tap = 0; tap < NTAPS; tap++) {
    const int dy = (MODE == 2) ? (tap >> 1) : (tap / 3);
    const int dx = (MODE == 2) ? (tap & 1) : (tap - (tap / 3) * 3);
    const int tapw = (MODE == 2) ? ((3 - py - 2 * dy) * 4 + (3 - px - 2 * dx)) : tap;
    long aoff[2];
    bool av[2];
#pragma unroll
    for (int mf = 0; mf < 2; mf++) {
      int gy, gx;
      if (MODE == 0) { gy = oy[mf] + dy - 1; gx = ox[mf] + dx - 1; }
      else if (MODE == 1) { gy = oy[mf] * 2 + dy - 1; gx = ox[mf] * 2 + dx - 1; }
      else { gy = oy[mf] + py - 1 + dy; gx = ox[mf] + px - 1 + dx; }
      av[mf] = ((unsigned)gy < (unsigned)Hi) && ((unsigned)gx < (unsigned)Wi);
      aoff[mf] = (long)(gy * Wi + gx) * CP + CO + q * 8;
    }
    const ushort* wb0 = wt + ((size_t)tapw * Cout + n0 + l15) * Cin + q * 8;
    const ushort* wb1 = wb0 + (size_t)16 * Cin;
    for (int k0 = 0; k0 < Cin; k0 += 32) {
      bfx8 a0 = av[0] ? *(const bfx8*)(ib + aoff[0] + k0) : zf;
      bfx8 a1 = av[1] ? *(const bfx8*)(ib + aoff[1] + k0) : zf;
      bfx8 b0 = *(const bfx8*)(wb0 + k0);
      bfx8 b1 = *(const bfx8*)(wb1 + k0);
      acc[0][0] = __builtin_amdgcn_mfma_f32_16x16x32_bf16(a0, b0, acc[0][0], 0, 0, 0);
      acc[0][1] = __builtin_amdgcn_mfma_f32_16x16x32_bf16(a0, b1, acc[0][1], 0, 0, 0);
      acc[1][0] = __builtin_amdgcn_mfma_f32_16x16x32_bf16(a1, b0, acc[1][0], 0, 0, 0);
      acc[1][1] = __builtin_amdgcn_mfma_f32_16x16x32_bf16(a1, b1, acc[1][1], 0, 0, 0);
    }
  }
  float bv[2];
  bv[0] = bias[n0 + l15];
  bv[1] = bias[n0 + 16 + l15];
  ushort* ob = out + (size_t)b * obs + COo;
#pragma unroll
  for (int mf = 0; mf < 2; mf++)
#pragma unroll
    for (int r = 0; r < 4; r++) {
      int sp = m0 + mf * 16 + q * 4 + r;
      int yy = sp >> lw, xx = sp & (Wt - 1);
      int ooy, oox, Wo;
      if (MODE == 2) { ooy = yy * 2 + py; oox = xx * 2 + px; Wo = Wt * 2; }
      else { ooy = yy; oox = xx; Wo = Wt; }
      size_t base = ((size_t)ooy * Wo + oox) * CPo;
#pragma unroll
      for (int nf = 0; nf < 2; nf++) {
        float v = acc[mf][nf][r] + bv[nf];
        ob[base + n0 + nf * 16 + l15] = f2bf(fmaxf(v, 0.f));
      }
    }
}

// ---------------- final 1x1 conv 256 -> 2 (channels-last bf16 input) ----------------
__global__ void k_final2(const ushort* __restrict__ in, const float* __restrict__ w,
                         const float* __restrict__ bias, float* __restrict__ out) {
  int i = blockIdx.x * 256 + threadIdx.x; // B*4096
  int b = i >> 12, p = i & 4095;
  const ushort* row = in + (size_t)i * 256;
  float a0 = bias[0], a1 = bias[1];
  for (int c = 0; c < 256; c += 4) {
    ushort4 u = *(const ushort4*)(row + c);
    float4 w0 = *(const float4*)(w + c);
    float4 w1 = *(const float4*)(w + 256 + c);
    float f0 = bf2f(u.x), f1 = bf2f(u.y), f2 = bf2f(u.z), f3 = bf2f(u.w);
    a0 += f0 * w0.x + f1 * w0.y + f2 * w0.z + f3 * w0.w;
    a1 += f0 * w1.x + f1 * w1.y + f2 * w1.z + f3 * w1.w;
  }
  out[(size_t)b * 8192 + p] = a0;
  out[(size_t)b * 8192 + 4096 + p] = a1;
}

extern "C" void kernel_launch(void* const* d_in, const int* in_sizes, int n_in,
                              void* d_out, int out_size, void* d_ws, size_t ws_size,
                              hipStream_t stream) {
  (void)in_sizes; (void)n_in; (void)out_size; (void)ws_size;
  const float* x          = (const float*)d_in[0];
  const float* emb_w      = (const float*)d_in[1];
  const float* emb_b      = (const float*)d_in[2];
  const float* pos_embed  = (const float*)d_in[3];
  const float* time_embed = (const float*)d_in[4];
  const float* blk_ln1_w  = (const float*)d_in[5];
  const float* blk_ln1_b  = (const float*)d_in[6];
  const float* blk_conv_w = (const float*)d_in[7];
  const float* blk_conv_b = (const float*)d_in[8];
  const float* blk_sln_w  = (const float*)d_in[9];
  const float* blk_sln_b  = (const float*)d_in[10];
  const float* blk_A_log  = (const float*)d_in[11];
  const float* blk_D      = (const float*)d_in[12];
  const float* blk_in_w   = (const float*)d_in[13];
  const float* blk_in_b   = (const float*)d_in[14];
  const float* blk_x_w    = (const float*)d_in[15];
  const float* blk_x_b    = (const float*)d_in[16];
  const float* blk_out_w  = (const float*)d_in[17];
  const float* blk_out_b  = (const float*)d_in[18];
  const float* blk_ln2_w  = (const float*)d_in[19];
  const float* blk_ln2_b  = (const float*)d_in[20];
  const float* blk_mlp_w1 = (const float*)d_in[21];
  const float* blk_mlp_b1 = (const float*)d_in[22];
  const float* blk_mlp_w2 = (const float*)d_in[23];
  const float* blk_mlp_b2 = (const float*)d_in[24];
  const float* down1_w    = (const float*)d_in[25];
  const float* down1_b    = (const float*)d_in[26];
  const float* down2_w    = (const float*)d_in[27];
  const float* down2_b    = (const float*)d_in[28];
  const float* bott_w     = (const float*)d_in[29];
  const float* bott_b     = (const float*)d_in[30];
  const float* up1_w      = (const float*)d_in[31];
  const float* up1_b      = (const float*)d_in[32];
  const float* up2_w      = (const float*)d_in[33];
  const float* up2_b      = (const float*)d_in[34];
  const float* final_w    = (const float*)d_in[35];
  const float* final_b    = (const float*)d_in[36];

  // workspace layout (floats). total 34 MiFloats = 136 MiB.
  float* ws = (float*)d_ws;
  constexpr size_t F = 1u << 20;
  float* EMB  = ws;            // [B,L,128]   8F
  float* T1   = ws + 8 * F;    // xn / y / m  8F   (UNet: U1cat/X2b/X3b/weights, bf16)
  float* T2   = ws + 16 * F;   // xp          8F   (UNet: U2cat bf16 [B,4096,256] = 32 MiB)
  float* T3   = ws + 24 * F;   // z           8F   (T2..T3 contiguous -> mlp hidden [M,256])
  float* Ubuf = ws + 32 * F;   // u [M,16]    1F   (also xc scratch)
  float* HST  = ws + 33 * F;   // hs^T        1F

  k_combine<<<256, 256, 0, stream>>>(x, Ubuf);
  k_embed<<<Mtok, 128, 0, stream>>>(Ubuf, emb_w, emb_b, pos_embed, time_embed, EMB);

  for (int i = 0; i < 2; i++) {
    k_ln<<<Mtok / 4, 256, 0, stream>>>(EMB, T1, blk_ln1_w + i * Dn, blk_ln1_b + i * Dn);
    k_dwconv<<<(Mtok * Dn) / 256, 256, 0, stream>>>(T1, EMB, blk_conv_w + i * Dn * 4, blk_conv_b + i * Dn);
    k_ln<<<Mtok / 4, 256, 0, stream>>>(EMB, T1, blk_sln_w + i * Dn, blk_sln_b + i * Dn);
    k_gemm<1><<<dim3(Mtok / 64, 4), 256, 0, stream>>>(T1, blk_in_w + (size_t)i * 256 * Dn,
                                                      blk_in_b + i * 256, T2, T3, 128, 256);
    k_u<<<Mtok / 16, 256, 0, stream>>>(T2, blk_x_w + i * DSn * Dn, blk_x_b + i * DSn, Ubuf);
    k_scan<<<Bn * DSn, 64, 0, stream>>>(Ubuf, HST, blk_A_log + i * DSn);
    k_y<<<Mtok / 2, 256, 0, stream>>>(HST, blk_D + i * DSn * Dn, T3, T1);
    k_gemm<3><<<dim3(Mtok / 64, 2), 256, 0, stream>>>(T1, blk_out_w + (size_t)i * Dn * Dn,
                                                      blk_out_b + i * Dn, EMB, nullptr, 128, 128);
    k_ln<<<Mtok / 4, 256, 0, stream>>>(EMB, T1, blk_ln2_w + i * Dn, blk_ln2_b + i * Dn);
    k_gemm<2><<<dim3(Mtok / 64, 4), 256, 0, stream>>>(T1, blk_mlp_w1 + (size_t)i * 256 * Dn,
                                                      blk_mlp_b1 + i * 256, T2, nullptr, 128, 256);
    k_gemm<3><<<dim3(Mtok / 64, 2), 256, 0, stream>>>(T2, blk_mlp_w2 + (size_t)i * Dn * 256,
                                                      blk_mlp_b2 + i * Dn, EMB, nullptr, 256, 128);
  }

  // ---- UNet head, channels-last bf16 ----
  ushort* U2C = (ushort*)T2;              // [B,64,64,256]: up2 out at ci 0..127, sp at 128..255
  ushort* U1C = (ushort*)T1;              // [B,32,32,256]: up1 out at 0..127, down1 out at 128..255
  ushort* X2b = U1C + 4194304;            // [B,16,16,256]
  ushort* X3b = X2b + 1048576;            // [B,16,16,256]
  ushort* Wd1 = X3b + 1048576;            // 9*128*128
  ushort* Wd2 = Wd1 + 147456;             // 9*256*128
  ushort* Wb9 = Wd2 + 294912;             // 9*256*256
  ushort* Wu1 = Wb9 + 589824;             // 16*128*256
  ushort* Wu2 = Wu1 + 524288;             // 16*128*256

  k_tobf<<<8192, 256, 0, stream>>>(EMB, U2C);
  k_wc9<<<(147456 + 255) / 256, 256, 0, stream>>>(down1_w, Wd1, 128, 128);
  k_wc9<<<(294912 + 255) / 256, 256, 0, stream>>>(down2_w, Wd2, 128, 256);
  k_wc9<<<(589824 + 255) / 256, 256, 0, stream>>>(bott_w, Wb9, 256, 256);
  k_wc16<<<(524288 + 255) / 256, 256, 0, stream>>>(up1_w, Wu1, 256, 128);
  k_wc16<<<(524288 + 255) / 256, 256, 0, stream>>>(up2_w, Wu2, 256, 128);

  // down1: [B,64,64,(256|+128)] -> [B,32,32,(256|+128)]
  k_cmfma<1><<<dim3(32, 1, 16), 256, 0, stream>>>(U2C, U1C, Wd1, down1_b,
      64, 64, 5, 4, 256, 128, 128, 256, 128, 128, 64L * 64 * 256, 32L * 32 * 256);
  // down2: [B,32,32,(256|+128)] -> X2b [B,16,16,256]
  k_cmfma<1><<<dim3(16, 1, 16), 256, 0, stream>>>(U1C, X2b, Wd2, down2_b,
      32, 32, 4, 8, 256, 128, 128, 256, 0, 256, 32L * 32 * 256, 16L * 16 * 256);
  // bott: X2b -> X3b
  k_cmfma<0><<<dim3(16, 1, 16), 256, 0, stream>>>(X2b, X3b, Wb9, bott_b,
      16, 16, 4, 8, 256, 0, 256, 256, 0, 256, 16L * 16 * 256, 16L * 16 * 256);
  // up1 (convT): X3b -> U1C ci 0..127
  k_cmfma<2><<<dim3(8, 4, 16), 256, 0, stream>>>(X3b, U1C, Wu1, up1_b,
      16, 16, 4, 4, 256, 0, 256, 256, 0, 128, 16L * 16 * 256, 32L * 32 * 256);
  // up2 (convT): U1C -> U2C ci 0..127
  k_cmfma<2><<<dim3(32, 4, 16), 256, 0, stream>>>(U1C, U2C, Wu2, up2_b,
      32, 32, 5, 4, 256, 0, 256, 256, 0, 128, 32L * 32 * 256, 64L * 64 * 256);

  k_final2<<<256, 256, 0, stream>>>(U2C, final_w, final_b, (float*)d_out);
}

// Round 4
// 804.422 us; speedup vs baseline: 10.7423x; 1.3238x over previous
//
#include <hip/hip_runtime.h>
#include <cmath>

namespace {
constexpr int Bn = 16, Ln = 4096, Dn = 128, DSn = 16;
constexpr int Mtok = Bn * Ln; // 65536 tokens
}

typedef short bfx8 __attribute__((ext_vector_type(8)));
typedef float f32x4 __attribute__((ext_vector_type(4)));

static __device__ __forceinline__ ushort f2bf(float f) {
  union { float f; unsigned u; } v; v.f = f;
  unsigned r = v.u + 0x7fff + ((v.u >> 16) & 1);
  return (ushort)(r >> 16);
}
static __device__ __forceinline__ float bf2f(ushort u) {
  union { unsigned u; float f; } v; v.u = ((unsigned)u) << 16;
  return v.f;
}

// ---------------- embedding ----------------

__global__ void k_combine(const float* __restrict__ x, float* __restrict__ xc) {
  int i = blockIdx.x * 256 + threadIdx.x; // B*HW = 65536
  int b = i >> 12, p = i & 4095;
  const float* xb = x + (size_t)b * 5 * Ln + p;
  xc[i] = 0.5f * (xb[0] + xb[Ln] + xb[2 * Ln] + xb[3 * Ln]) + xb[4 * Ln];
}

__global__ void k_embed(const float* __restrict__ xc, const float* __restrict__ ew,
                        const float* __restrict__ eb, const float* __restrict__ pos,
                        const float* __restrict__ te, float* __restrict__ emb) {
  int l = blockIdx.x & 4095, b = blockIdx.x >> 12;
  int h = l >> 6, w = l & 63;
  int d = threadIdx.x;
  const float* xb = xc + b * Ln;
  float v[9];
#pragma unroll
  for (int dy = 0; dy < 3; dy++)
#pragma unroll
    for (int dx = 0; dx < 3; dx++) {
      int y = h + dy - 1, xx = w + dx - 1;
      v[dy * 3 + dx] = (y >= 0 && y < 64 && xx >= 0 && xx < 64) ? xb[y * 64 + xx] : 0.f;
    }
  float acc = 0.f;
#pragma unroll
  for (int k = 0; k < 9; k++) acc += v[k] * ew[d * 9 + k];
  float ts = 0.5f * (te[d] + te[128 + d] + te[256 + d] + te[384 + d]) + te[512 + d];
  emb[(size_t)blockIdx.x * Dn + d] = acc + 3.f * eb[d] + 3.f * pos[l * Dn + d] + ts;
}

// ---------------- layernorm (rows of 128), fp32 in -> bf16 out ----------------
__global__ __launch_bounds__(256) void k_lnb(const float* __restrict__ in, ushort* __restrict__ out,
                                             const float* __restrict__ w, const float* __restrict__ bias) {
  int row = blockIdx.x * 4 + (threadIdx.x >> 6);
  int lane = threadIdx.x & 63;
  const float* p = in + (size_t)row * Dn;
  float2 v = *(const float2*)(p + lane * 2);
  float s = v.x + v.y, sq = v.x * v.x + v.y * v.y;
#pragma unroll
  for (int off = 32; off; off >>= 1) { s += __shfl_xor(s, off); sq += __shfl_xor(sq, off); }
  float m = s * (1.f / 128.f);
  float var = sq * (1.f / 128.f) - m * m;
  float r = rsqrtf(var + 1e-5f);
  int d = lane * 2;
  ushort2 o;
  o.x = f2bf((v.x - m) * r * w[d] + bias[d]);
  o.y = f2bf((v.y - m) * r * w[d + 1] + bias[d + 1]);
  *(ushort2*)(out + (size_t)row * Dn + d) = o;
}

// ---------------- causal depthwise conv1d k=4 + residual (bf16 in, fp32 accum) --------
__global__ void k_dwconvb(const ushort* __restrict__ xn, float* __restrict__ emb,
                          const float* __restrict__ cw, const float* __restrict__ cb) {
  int i = blockIdx.x * 256 + threadIdx.x; // Mtok*128
  int d = i & 127;
  int l = (i >> 7) & 4095;
  const ushort* p = xn + i;
  float acc = cb[d] + cw[d * 4 + 3] * bf2f(p[0]);
  if (l >= 1) acc += cw[d * 4 + 2] * bf2f(p[-128]);
  if (l >= 2) acc += cw[d * 4 + 1] * bf2f(p[-256]);
  if (l >= 3) acc += cw[d * 4 + 0] * bf2f(p[-384]);
  emb[i] += acc;
}

// ---------------- fp32 -> bf16 convert ----------------
__global__ void k_cvt(const float* __restrict__ src, ushort* __restrict__ dst, int n) {
  int i = blockIdx.x * 256 + threadIdx.x;
  if (i < n) dst[i] = f2bf(src[i]);
}

// ---------------- MFMA GEMM: C[M,N] = A[M,K](bf16) @ W[N,K]^T(bf16) + epilogue ----
// block: 128x128 tile, 4 waves of 64x64; no LDS, operands direct from L2/L3.
// MODE 1: col<128 silu -> XP bf16 [M,128]; col>=128 sigmoid -> Z bf16 [M,128]
// MODE 2: gelu -> out bf16 [M,256]
// MODE 3: accumulate fp32 -> out[M,128] +=
template <int MODE>
__global__ __launch_bounds__(256) void k_mgemm(const ushort* __restrict__ A, const ushort* __restrict__ W,
                                               const float* __restrict__ bias, void* __restrict__ outv,
                                               void* __restrict__ out2v, int K) {
  const int t = threadIdx.x;
  const int l = t & 63, wv = t >> 6;
  const int l15 = l & 15, q = l >> 4;
  const int wm = wv >> 1, wn = wv & 1;
  const int m0 = blockIdx.x * 128 + wm * 64;
  const int n0 = blockIdx.y * 128 + wn * 64;
  f32x4 acc[4][4] = {};
  const ushort* Ab = A + (size_t)(m0 + l15) * K + q * 8;
  const ushort* Wb = W + (size_t)(n0 + l15) * K + q * 8;
  for (int k0 = 0; k0 < K; k0 += 32) {
    bfx8 a[4], b[4];
#pragma unroll
    for (int mf = 0; mf < 4; mf++) a[mf] = *(const bfx8*)(Ab + (size_t)mf * 16 * K + k0);
#pragma unroll
    for (int nf = 0; nf < 4; nf++) b[nf] = *(const bfx8*)(Wb + (size_t)nf * 16 * K + k0);
#pragma unroll
    for (int mf = 0; mf < 4; mf++)
#pragma unroll
      for (int nf = 0; nf < 4; nf++)
        acc[mf][nf] = __builtin_amdgcn_mfma_f32_16x16x32_bf16(a[mf], b[nf], acc[mf][nf], 0, 0, 0);
  }
#pragma unroll
  for (int mf = 0; mf < 4; mf++) {
#pragma unroll
    for (int nf = 0; nf < 4; nf++) {
      const int col = n0 + nf * 16 + l15;
      const float bb = bias[col];
#pragma unroll
      for (int r = 0; r < 4; r++) {
        const int row = m0 + mf * 16 + q * 4 + r;
        float v = acc[mf][nf][r] + bb;
        if (MODE == 1) {
          if (col < 128) {
            ((ushort*)outv)[(size_t)row * 128 + col] = f2bf(v / (1.f + expf(-v)));
          } else {
            ((ushort*)out2v)[(size_t)row * 128 + col - 128] = f2bf(1.f / (1.f + expf(-v)));
          }
        } else if (MODE == 2) {
          ((ushort*)outv)[(size_t)row * 256 + col] = f2bf(0.5f * v * (1.f + erff(v * 0.7071067811865475f)));
        } else {
          ((float*)outv)[(size_t)row * 128 + col] += v;
        }
      }
    }
  }
}

// ---------------- u = silu(xp) @ x_w^T + x_b  (N=16, bf16 inputs) ----------------
__global__ __launch_bounds__(256) void k_ub(const ushort* __restrict__ XP, const ushort* __restrict__ xw,
                                            const float* __restrict__ xb, float* __restrict__ U) {
  __shared__ float xs[16 * 132];
  __shared__ float wsm[16 * 129];
  const int m0 = blockIdx.x * 16;
  const int t = threadIdx.x;
  for (int idx = t; idx < 2048; idx += 256) {
    wsm[(idx >> 7) * 129 + (idx & 127)] = bf2f(xw[idx]);
    xs[(idx >> 7) * 132 + (idx & 127)] = bf2f(XP[(size_t)m0 * 128 + idx]);
  }
  __syncthreads();
  const int ds = t & 15, ml = t >> 4;
  float acc = 0.f;
#pragma unroll 16
  for (int k = 0; k < 128; k++) acc += xs[ml * 132 + k] * wsm[ds * 129 + k];
  U[(size_t)(m0 + ml) * 16 + ds] = acc + xb[ds];
}

// ---------------- chunked parallel linear scan ----------------
__global__ __launch_bounds__(64) void k_scan(const float* __restrict__ U, float* __restrict__ HST,
                                             const float* __restrict__ A_log) {
  __shared__ float lds[64 * 65];
  const int b = blockIdx.x >> 4, ds = blockIdx.x & 15;
  const int tid = threadIdx.x;
  const float a = expf(-expf(A_log[ds]));
  const float* ub = U + (size_t)b * Ln * 16 + ds;
  for (int j = 0; j < 64; j++) lds[j * 65 + tid] = ub[(size_t)(j * 64 + tid) * 16];
  __syncthreads();
  float h = 0.f;
  for (int j = 0; j < 64; j++) {
    h = a * h + lds[tid * 65 + j];
    lds[tid * 65 + j] = h;
  }
  float a64 = a;
#pragma unroll
  for (int q = 0; q < 6; q++) a64 *= a64;
  float Ac = a64, Bc = h;
#pragma unroll
  for (int off = 1; off < 64; off <<= 1) {
    float Ap = __shfl_up(Ac, off);
    float Bp = __shfl_up(Bc, off);
    if (tid >= off) { Bc = Ac * Bp + Bc; Ac = Ac * Ap; }
  }
  float carry = __shfl_up(Bc, 1);
  if (tid == 0) carry = 0.f;
  float p = a;
  for (int j = 0; j < 64; j++) {
    lds[tid * 65 + j] += p * carry;
    p *= a;
  }
  __syncthreads();
  float* hb = HST + (size_t)(b * 16 + ds) * Ln;
  for (int j = 0; j < 64; j++) hb[j * 64 + tid] = lds[j * 65 + tid];
}

// ---------------- y = (hs @ D) * z  (z bf16, y bf16 out) ----------------
__global__ __launch_bounds__(256) void k_yb(const float* __restrict__ HST, const float* __restrict__ Dm_,
                                            const ushort* __restrict__ Z, ushort* __restrict__ Y) {
  const int m = blockIdx.x * 2 + (threadIdx.x >> 7);
  const int d = threadIdx.x & 127;
  const int b = m >> 12, l = m & 4095;
  const float* hb = HST + (size_t)b * 16 * Ln + l;
  float acc = 0.f;
#pragma unroll
  for (int s = 0; s < 16; s++) acc += hb[(size_t)s * Ln] * Dm_[s * 128 + d];
  const size_t o = (size_t)m * 128 + d;
  Y[o] = f2bf(acc * bf2f(Z[o]));
}

// ---------------- fp32 [B,HW,128] -> bf16 channels-last slot [B,HW,256] at +128 ----------------
__global__ void k_tobf(const float* __restrict__ in, ushort* __restrict__ out) {
  int i = blockIdx.x * 256 + threadIdx.x; // Mtok*32
  int row = i >> 5, c4 = (i & 31) * 4;
  float4 v = *(const float4*)(in + (size_t)row * 128 + c4);
  ushort4 o;
  o.x = f2bf(v.x); o.y = f2bf(v.y); o.z = f2bf(v.z); o.w = f2bf(v.w);
  *(ushort4*)(out + (size_t)row * 256 + 128 + c4) = o;
}

// ---------------- conv weight converts to bf16 [tap][Cout][Cin] ----------------
__global__ void k_wc9(const float* __restrict__ w, ushort* __restrict__ Wb, int Cin, int Cout) {
  int i = blockIdx.x * 256 + threadIdx.x;
  if (i >= Cout * Cin * 9) return;
  int co = i / (Cin * 9);
  int r = i - co * (Cin * 9);
  int ci = r / 9, tap = r - ci * 9;
  Wb[((size_t)tap * Cout + co) * Cin + ci] = f2bf(w[i]);
}
__global__ void k_wc16(const float* __restrict__ w, ushort* __restrict__ Wb, int Cin, int Cout) {
  int i = blockIdx.x * 256 + threadIdx.x;
  if (i >= Cin * Cout * 16) return;
  int ci = i / (Cout * 16);
  int r = i - ci * (Cout * 16);
  int co = r >> 4, tap = r & 15;
  Wb[((size_t)tap * Cout + co) * Cin + ci] = f2bf(w[i]);
}

// ---------------- implicit-GEMM MFMA conv (unchanged from round 3) ----------------
template <int MODE>
__global__ __launch_bounds__(256) void k_cmfma(
    const ushort* __restrict__ in, ushort* __restrict__ out,
    const ushort* __restrict__ wt, const float* __restrict__ bias,
    int Hi, int Wi, int lw, int NT, int CP, int CO, int Cin,
    int CPo, int COo, int Cout, long ibs, long obs) {
  const int t = threadIdx.x;
  const int l = t & 63;
  const int wid = (blockIdx.x * 256 + t) >> 6;
  const int nt = wid % NT, mt = wid / NT;
  const int b = blockIdx.z;
  const int py = blockIdx.y >> 1, px = blockIdx.y & 1;
  const int l15 = l & 15, q = l >> 4;
  const int Wt = 1 << lw;
  const int m0 = mt * 32, n0 = nt * 32;
  f32x4 acc[2][2] = {};
  const ushort* ib = in + (size_t)b * ibs;
  int oy[2], ox[2];
  oy[0] = (m0 + l15) >> lw; ox[0] = (m0 + l15) & (Wt - 1);
  oy[1] = (m0 + 16 + l15) >> lw; ox[1] = (m0 + 16 + l15) & (Wt - 1);
  constexpr int NTAPS = (MODE == 2) ? 4 : 9;
  const bfx8 zf = {0, 0, 0, 0, 0, 0, 0, 0};
#pragma unroll
  for (int tap = 0; tap < NTAPS; tap++) {
    const int dy = (MODE == 2) ? (tap >> 1) : (tap / 3);
    const int dx = (MODE == 2) ? (tap & 1) : (tap - (tap / 3) * 3);
    const int tapw = (MODE == 2) ? ((3 - py - 2 * dy) * 4 + (3 - px - 2 * dx)) : tap;
    long aoff[2];
    bool av[2];
#pragma unroll
    for (int mf = 0; mf < 2; mf++) {
      int gy, gx;
      if (MODE == 0) { gy = oy[mf] + dy - 1; gx = ox[mf] + dx - 1; }
      else if (MODE == 1) { gy = oy[mf] * 2 + dy - 1; gx = ox[mf] * 2 + dx - 1; }
      else { gy = oy[mf] + py - 1 + dy; gx = ox[mf] + px - 1 + dx; }
      av[mf] = ((unsigned)gy < (unsigned)Hi) && ((unsigned)gx < (unsigned)Wi);
      aoff[mf] = (long)(gy * Wi + gx) * CP + CO + q * 8;
    }
    const ushort* wb0 = wt + ((size_t)tapw * Cout + n0 + l15) * Cin + q * 8;
    const ushort* wb1 = wb0 + (size_t)16 * Cin;
    for (int k0 = 0; k0 < Cin; k0 += 32) {
      bfx8 a0 = av[0] ? *(const bfx8*)(ib + aoff[0] + k0) : zf;
      bfx8 a1 = av[1] ? *(const bfx8*)(ib + aoff[1] + k0) : zf;
      bfx8 b0 = *(const bfx8*)(wb0 + k0);
      bfx8 b1 = *(const bfx8*)(wb1 + k0);
      acc[0][0] = __builtin_amdgcn_mfma_f32_16x16x32_bf16(a0, b0, acc[0][0], 0, 0, 0);
      acc[0][1] = __builtin_amdgcn_mfma_f32_16x16x32_bf16(a0, b1, acc[0][1], 0, 0, 0);
      acc[1][0] = __builtin_amdgcn_mfma_f32_16x16x32_bf16(a1, b0, acc[1][0], 0, 0, 0);
      acc[1][1] = __builtin_amdgcn_mfma_f32_16x16x32_bf16(a1, b1, acc[1][1], 0, 0, 0);
    }
  }
  float bv[2];
  bv[0] = bias[n0 + l15];
  bv[1] = bias[n0 + 16 + l15];
  ushort* ob = out + (size_t)b * obs + COo;
#pragma unroll
  for (int mf = 0; mf < 2; mf++)
#pragma unroll
    for (int r = 0; r < 4; r++) {
      int sp = m0 + mf * 16 + q * 4 + r;
      int yy = sp >> lw, xx = sp & (Wt - 1);
      int ooy, oox, Wo;
      if (MODE == 2) { ooy = yy * 2 + py; oox = xx * 2 + px; Wo = Wt * 2; }
      else { ooy = yy; oox = xx; Wo = Wt; }
      size_t base = ((size_t)ooy * Wo + oox) * CPo;
#pragma unroll
      for (int nf = 0; nf < 2; nf++) {
        float v = acc[mf][nf][r] + bv[nf];
        ob[base + n0 + nf * 16 + l15] = f2bf(fmaxf(v, 0.f));
      }
    }
}

// ---------------- final 1x1 conv 256 -> 2 (channels-last bf16 input) ----------------
__global__ void k_final2(const ushort* __restrict__ in, const float* __restrict__ w,
                         const float* __restrict__ bias, float* __restrict__ out) {
  int i = blockIdx.x * 256 + threadIdx.x; // B*4096
  int b = i >> 12, p = i & 4095;
  const ushort* row = in + (size_t)i * 256;
  float a0 = bias[0], a1 = bias[1];
  for (int c = 0; c < 256; c += 4) {
    ushort4 u = *(const ushort4*)(row + c);
    float4 w0 = *(const float4*)(w + c);
    float4 w1 = *(const float4*)(w + 256 + c);
    float f0 = bf2f(u.x), f1 = bf2f(u.y), f2 = bf2f(u.z), f3 = bf2f(u.w);
    a0 += f0 * w0.x + f1 * w0.y + f2 * w0.z + f3 * w0.w;
    a1 += f0 * w1.x + f1 * w1.y + f2 * w1.z + f3 * w1.w;
  }
  out[(size_t)b * 8192 + p] = a0;
  out[(size_t)b * 8192 + 4096 + p] = a1;
}

extern "C" void kernel_launch(void* const* d_in, const int* in_sizes, int n_in,
                              void* d_out, int out_size, void* d_ws, size_t ws_size,
                              hipStream_t stream) {
  (void)in_sizes; (void)n_in; (void)out_size; (void)ws_size;
  const float* x          = (const float*)d_in[0];
  const float* emb_w      = (const float*)d_in[1];
  const float* emb_b      = (const float*)d_in[2];
  const float* pos_embed  = (const float*)d_in[3];
  const float* time_embed = (const float*)d_in[4];
  const float* blk_ln1_w  = (const float*)d_in[5];
  const float* blk_ln1_b  = (const float*)d_in[6];
  const float* blk_conv_w = (const float*)d_in[7];
  const float* blk_conv_b = (const float*)d_in[8];
  const float* blk_sln_w  = (const float*)d_in[9];
  const float* blk_sln_b  = (const float*)d_in[10];
  const float* blk_A_log  = (const float*)d_in[11];
  const float* blk_D      = (const float*)d_in[12];
  const float* blk_in_w   = (const float*)d_in[13];
  const float* blk_in_b   = (const float*)d_in[14];
  const float* blk_x_w    = (const float*)d_in[15];
  const float* blk_x_b    = (const float*)d_in[16];
  const float* blk_out_w  = (const float*)d_in[17];
  const float* blk_out_b  = (const float*)d_in[18];
  const float* blk_ln2_w  = (const float*)d_in[19];
  const float* blk_ln2_b  = (const float*)d_in[20];
  const float* blk_mlp_w1 = (const float*)d_in[21];
  const float* blk_mlp_b1 = (const float*)d_in[22];
  const float* blk_mlp_w2 = (const float*)d_in[23];
  const float* blk_mlp_b2 = (const float*)d_in[24];
  const float* down1_w    = (const float*)d_in[25];
  const float* down1_b    = (const float*)d_in[26];
  const float* down2_w    = (const float*)d_in[27];
  const float* down2_b    = (const float*)d_in[28];
  const float* bott_w     = (const float*)d_in[29];
  const float* bott_b     = (const float*)d_in[30];
  const float* up1_w      = (const float*)d_in[31];
  const float* up1_b      = (const float*)d_in[32];
  const float* up2_w      = (const float*)d_in[33];
  const float* up2_b      = (const float*)d_in[34];
  const float* final_w    = (const float*)d_in[35];
  const float* final_b    = (const float*)d_in[36];

  // workspace layout (floats). total 34 MiFloats = 136 MiB.
  float* ws = (float*)d_ws;
  constexpr size_t F = 1u << 20;
  float* EMB  = ws;            // fp32 residual [M,128], 8F
  float* T1   = ws + 8 * F;    // bf16 xn/y/m-A 8F  (UNet: U1cat/X2b/X3b/conv weights)
  float* T2   = ws + 16 * F;   // bf16 xp|z / mlp hidden 8F (UNet: U2cat)
  float* T3   = ws + 24 * F;   // bf16 trunk weights 8F
  float* Ubuf = ws + 32 * F;   // u [M,16] fp32 1F (also xc scratch)
  float* HST  = ws + 33 * F;   // hs^T fp32 1F

  ushort* XN   = (ushort*)T1;                 // [M,128] bf16
  ushort* XPu  = (ushort*)T2;                 // [M,128] bf16
  ushort* Zu   = XPu + (size_t)Mtok * 128;    // [M,128] bf16
  ushort* MH   = (ushort*)T2;                 // [M,256] bf16 (after xp/z dead)
  ushort* Wi   = (ushort*)T3;                 // 2*256*128
  ushort* Wo   = Wi + 65536;                  // 2*128*128
  ushort* Wm1  = Wo + 32768;                  // 2*256*128
  ushort* Wm2  = Wm1 + 65536;                 // 2*128*256
  ushort* Wx   = Wm2 + 65536;                 // 2*16*128

  // trunk weight converts (tiny)
  k_cvt<<<256, 256, 0, stream>>>(blk_in_w, Wi, 65536);
  k_cvt<<<128, 256, 0, stream>>>(blk_out_w, Wo, 32768);
  k_cvt<<<256, 256, 0, stream>>>(blk_mlp_w1, Wm1, 65536);
  k_cvt<<<256, 256, 0, stream>>>(blk_mlp_w2, Wm2, 65536);
  k_cvt<<<16, 256, 0, stream>>>(blk_x_w, Wx, 4096);

  k_combine<<<256, 256, 0, stream>>>(x, Ubuf);
  k_embed<<<Mtok, 128, 0, stream>>>(Ubuf, emb_w, emb_b, pos_embed, time_embed, EMB);

  for (int i = 0; i < 2; i++) {
    k_lnb<<<Mtok / 4, 256, 0, stream>>>(EMB, XN, blk_ln1_w + i * Dn, blk_ln1_b + i * Dn);
    k_dwconvb<<<(Mtok * Dn) / 256, 256, 0, stream>>>(XN, EMB, blk_conv_w + i * Dn * 4, blk_conv_b + i * Dn);
    k_lnb<<<Mtok / 4, 256, 0, stream>>>(EMB, XN, blk_sln_w + i * Dn, blk_sln_b + i * Dn);
    k_mgemm<1><<<dim3(Mtok / 128, 2), 256, 0, stream>>>(XN, Wi + i * 32768, blk_in_b + i * 256,
                                                        XPu, Zu, 128);
    k_ub<<<Mtok / 16, 256, 0, stream>>>(XPu, Wx + i * 2048, blk_x_b + i * DSn, Ubuf);
    k_scan<<<Bn * DSn, 64, 0, stream>>>(Ubuf, HST, blk_A_log + i * DSn);
    k_yb<<<Mtok / 2, 256, 0, stream>>>(HST, blk_D + i * DSn * Dn, Zu, XN);
    k_mgemm<3><<<dim3(Mtok / 128, 1), 256, 0, stream>>>(XN, Wo + i * 16384, blk_out_b + i * Dn,
                                                        EMB, nullptr, 128);
    k_lnb<<<Mtok / 4, 256, 0, stream>>>(EMB, XN, blk_ln2_w + i * Dn, blk_ln2_b + i * Dn);
    k_mgemm<2><<<dim3(Mtok / 128, 2), 256, 0, stream>>>(XN, Wm1 + i * 32768, blk_mlp_b1 + i * 256,
                                                        MH, nullptr, 128);
    k_mgemm<3><<<dim3(Mtok / 128, 1), 256, 0, stream>>>(MH, Wm2 + i * 32768, blk_mlp_b2 + i * Dn,
                                                        EMB, nullptr, 256);
  }

  // ---- UNet head, channels-last bf16 (unchanged from round 3) ----
  ushort* U2C = (ushort*)T2;              // [B,64,64,256]
  ushort* U1C = (ushort*)T1;              // [B,32,32,256]
  ushort* X2b = U1C + 4194304;            // [B,16,16,256]
  ushort* X3b = X2b + 1048576;            // [B,16,16,256]
  ushort* Wd1 = X3b + 1048576;            // 9*128*128
  ushort* Wd2 = Wd1 + 147456;             // 9*256*128
  ushort* Wb9 = Wd2 + 294912;             // 9*256*256
  ushort* Wu1 = Wb9 + 589824;             // 16*128*256
  ushort* Wu2 = Wu1 + 524288;             // 16*128*256

  k_tobf<<<8192, 256, 0, stream>>>(EMB, U2C);
  k_wc9<<<(147456 + 255) / 256, 256, 0, stream>>>(down1_w, Wd1, 128, 128);
  k_wc9<<<(294912 + 255) / 256, 256, 0, stream>>>(down2_w, Wd2, 128, 256);
  k_wc9<<<(589824 + 255) / 256, 256, 0, stream>>>(bott_w, Wb9, 256, 256);
  k_wc16<<<(524288 + 255) / 256, 256, 0, stream>>>(up1_w, Wu1, 256, 128);
  k_wc16<<<(524288 + 255) / 256, 256, 0, stream>>>(up2_w, Wu2, 256, 128);

  k_cmfma<1><<<dim3(32, 1, 16), 256, 0, stream>>>(U2C, U1C, Wd1, down1_b,
      64, 64, 5, 4, 256, 128, 128, 256, 128, 128, 64L * 64 * 256, 32L * 32 * 256);
  k_cmfma<1><<<dim3(16, 1, 16), 256, 0, stream>>>(U1C, X2b, Wd2, down2_b,
      32, 32, 4, 8, 256, 128, 128, 256, 0, 256, 32L * 32 * 256, 16L * 16 * 256);
  k_cmfma<0><<<dim3(16, 1, 16), 256, 0, stream>>>(X2b, X3b, Wb9, bott_b,
      16, 16, 4, 8, 256, 0, 256, 256, 0, 256, 16L * 16 * 256, 16L * 16 * 256);
  k_cmfma<2><<<dim3(8, 4, 16), 256, 0, stream>>>(X3b, U1C, Wu1, up1_b,
      16, 16, 4, 4, 256, 0, 256, 256, 0, 128, 16L * 16 * 256, 32L * 32 * 256);
  k_cmfma<2><<<dim3(32, 4, 16), 256, 0, stream>>>(U1C, U2C, Wu2, up2_b,
      32, 32, 5, 4, 256, 0, 256, 256, 0, 128, 32L * 32 * 256, 64L * 64 * 256);

  k_final2<<<256, 256, 0, stream>>>(U2C, final_w, final_b, (float*)d_out);
}

// Round 5
// 651.671 us; speedup vs baseline: 13.2603x; 1.2344x over previous
//
#include <hip/hip_runtime.h>
#include <cmath>

namespace {
constexpr int Bn = 16, Ln = 4096, Dn = 128, DSn = 16;
constexpr int Mtok = Bn * Ln; // 65536 tokens
}

typedef short bfx8 __attribute__((ext_vector_type(8)));
typedef float f32x4 __attribute__((ext_vector_type(4)));

static __device__ __forceinline__ ushort f2bf(float f) {
  union { float f; unsigned u; } v; v.f = f;
  unsigned r = v.u + 0x7fff + ((v.u >> 16) & 1);
  return (ushort)(r >> 16);
}
static __device__ __forceinline__ float bf2f(ushort u) {
  union { unsigned u; float f; } v; v.u = ((unsigned)u) << 16;
  return v.f;
}

// ---------------- embedding ----------------

__global__ void k_combine(const float* __restrict__ x, float* __restrict__ xc) {
  int i = blockIdx.x * 256 + threadIdx.x; // B*HW = 65536
  int b = i >> 12, p = i & 4095;
  const float* xb = x + (size_t)b * 5 * Ln + p;
  xc[i] = 0.5f * (xb[0] + xb[Ln] + xb[2 * Ln] + xb[3 * Ln]) + xb[4 * Ln];
}

__global__ void k_embed(const float* __restrict__ xc, const float* __restrict__ ew,
                        const float* __restrict__ eb, const float* __restrict__ pos,
                        const float* __restrict__ te, float* __restrict__ emb) {
  int l = blockIdx.x & 4095, b = blockIdx.x >> 12;
  int h = l >> 6, w = l & 63;
  int d = threadIdx.x;
  const float* xb = xc + b * Ln;
  float v[9];
#pragma unroll
  for (int dy = 0; dy < 3; dy++)
#pragma unroll
    for (int dx = 0; dx < 3; dx++) {
      int y = h + dy - 1, xx = w + dx - 1;
      v[dy * 3 + dx] = (y >= 0 && y < 64 && xx >= 0 && xx < 64) ? xb[y * 64 + xx] : 0.f;
    }
  float acc = 0.f;
#pragma unroll
  for (int k = 0; k < 9; k++) acc += v[k] * ew[d * 9 + k];
  float ts = 0.5f * (te[d] + te[128 + d] + te[256 + d] + te[384 + d]) + te[512 + d];
  emb[(size_t)blockIdx.x * Dn + d] = acc + 3.f * eb[d] + 3.f * pos[l * Dn + d] + ts;
}

// ---------------- layernorm (rows of 128), fp32 in -> bf16 out, float4 loads --------
__global__ __launch_bounds__(256) void k_lnb(const float* __restrict__ in, ushort* __restrict__ out,
                                             const float* __restrict__ w, const float* __restrict__ bias) {
  int row = blockIdx.x * 8 + (threadIdx.x >> 5);
  int ln = threadIdx.x & 31;
  const float* p = in + (size_t)row * Dn;
  float4 v = *(const float4*)(p + ln * 4);
  float s = v.x + v.y + v.z + v.w;
  float sq = v.x * v.x + v.y * v.y + v.z * v.z + v.w * v.w;
#pragma unroll
  for (int off = 16; off; off >>= 1) { s += __shfl_xor(s, off); sq += __shfl_xor(sq, off); }
  float m = s * (1.f / 128.f);
  float var = sq * (1.f / 128.f) - m * m;
  float r = rsqrtf(var + 1e-5f);
  float4 wv = *(const float4*)(w + ln * 4);
  float4 bv = *(const float4*)(bias + ln * 4);
  ushort4 o;
  o.x = f2bf((v.x - m) * r * wv.x + bv.x);
  o.y = f2bf((v.y - m) * r * wv.y + bv.y);
  o.z = f2bf((v.z - m) * r * wv.z + bv.z);
  o.w = f2bf((v.w - m) * r * wv.w + bv.w);
  *(ushort4*)(out + (size_t)row * Dn + ln * 4) = o;
}

// ---------------- cw transpose: cw[blk][d][4] -> cwT[blk][k][128] ----------------
__global__ void k_cwt(const float* __restrict__ cw, float* __restrict__ cwT) {
  int i = blockIdx.x * 256 + threadIdx.x; // 1024
  if (i >= 1024) return;
  int blk = i >> 9, r = i & 511;
  int d = r >> 2, k = r & 3;
  cwT[blk * 512 + k * 128 + d] = cw[i];
}

// ---------------- causal depthwise conv1d k=4 + residual (vectorized) ----------------
__global__ void k_dwconvb8(const ushort* __restrict__ xn, float* __restrict__ emb,
                           const float* __restrict__ cwT, const float* __restrict__ cb) {
  int i = blockIdx.x * 256 + threadIdx.x; // Mtok*16
  int g = i & 15, tok = i >> 4;
  int d0 = g * 8;
  int l = tok & 4095;
  const ushort* p = xn + (size_t)tok * 128 + d0;
  const bfx8 zf = {0, 0, 0, 0, 0, 0, 0, 0};
  bfx8 v0 = *(const bfx8*)p;
  bfx8 v1 = (l >= 1) ? *(const bfx8*)(p - 128) : zf;
  bfx8 v2 = (l >= 2) ? *(const bfx8*)(p - 256) : zf;
  bfx8 v3 = (l >= 3) ? *(const bfx8*)(p - 384) : zf;
  float acc[8];
#pragma unroll
  for (int half = 0; half < 2; half++) {
    float4 c0 = *(const float4*)(cwT + 0 * 128 + d0 + half * 4);
    float4 c1 = *(const float4*)(cwT + 1 * 128 + d0 + half * 4);
    float4 c2 = *(const float4*)(cwT + 2 * 128 + d0 + half * 4);
    float4 c3 = *(const float4*)(cwT + 3 * 128 + d0 + half * 4);
    float4 bb = *(const float4*)(cb + d0 + half * 4);
    const float* c0p = &c0.x; const float* c1p = &c1.x;
    const float* c2p = &c2.x; const float* c3p = &c3.x;
    const float* bbp = &bb.x;
#pragma unroll
    for (int j = 0; j < 4; j++) {
      int e = half * 4 + j;
      acc[e] = bbp[j] + c3p[j] * bf2f((ushort)v0[e]) + c2p[j] * bf2f((ushort)v1[e]) +
               c1p[j] * bf2f((ushort)v2[e]) + c0p[j] * bf2f((ushort)v3[e]);
    }
  }
  float* ep = emb + (size_t)tok * 128 + d0;
  float4 e0 = *(const float4*)ep;
  float4 e1 = *(const float4*)(ep + 4);
  e0.x += acc[0]; e0.y += acc[1]; e0.z += acc[2]; e0.w += acc[3];
  e1.x += acc[4]; e1.y += acc[5]; e1.z += acc[6]; e1.w += acc[7];
  *(float4*)ep = e0;
  *(float4*)(ep + 4) = e1;
}

// ---------------- fp32 -> bf16 convert ----------------
__global__ void k_cvt(const float* __restrict__ src, ushort* __restrict__ dst, int n) {
  int i = blockIdx.x * 256 + threadIdx.x;
  if (i < n) dst[i] = f2bf(src[i]);
}

// ---------------- MFMA GEMM: C[M,N] = A[M,K](bf16) @ W[N,K]^T(bf16) + epilogue ----
// MODE 1: col<128 silu -> XP bf16; col>=128 sigmoid -> Z bf16
// MODE 2: gelu -> out bf16 [M,256]
// MODE 3: accumulate fp32 -> out[M,128] +=
template <int MODE, int K>
__global__ __launch_bounds__(256) void k_mgemm(const ushort* __restrict__ A, const ushort* __restrict__ W,
                                               const float* __restrict__ bias, void* __restrict__ outv,
                                               void* __restrict__ out2v) {
  const int t = threadIdx.x;
  const int l = t & 63, wv = t >> 6;
  const int l15 = l & 15, q = l >> 4;
  const int wm = wv >> 1, wn = wv & 1;
  const int m0 = blockIdx.x * 128 + wm * 64;
  const int n0 = blockIdx.y * 128 + wn * 64;
  f32x4 acc[4][4] = {};
  const ushort* Ab = A + (size_t)(m0 + l15) * K + q * 8;
  const ushort* Wb = W + (size_t)(n0 + l15) * K + q * 8;
#pragma unroll
  for (int k0 = 0; k0 < K; k0 += 32) {
    bfx8 a[4], b[4];
#pragma unroll
    for (int mf = 0; mf < 4; mf++) a[mf] = *(const bfx8*)(Ab + (size_t)mf * 16 * K + k0);
#pragma unroll
    for (int nf = 0; nf < 4; nf++) b[nf] = *(const bfx8*)(Wb + (size_t)nf * 16 * K + k0);
#pragma unroll
    for (int mf = 0; mf < 4; mf++)
#pragma unroll
      for (int nf = 0; nf < 4; nf++)
        acc[mf][nf] = __builtin_amdgcn_mfma_f32_16x16x32_bf16(a[mf], b[nf], acc[mf][nf], 0, 0, 0);
  }
#pragma unroll
  for (int mf = 0; mf < 4; mf++) {
#pragma unroll
    for (int nf = 0; nf < 4; nf++) {
      const int col = n0 + nf * 16 + l15;
      const float bb = bias[col];
#pragma unroll
      for (int r = 0; r < 4; r++) {
        const int row = m0 + mf * 16 + q * 4 + r;
        float v = acc[mf][nf][r] + bb;
        if (MODE == 1) {
          if (col < 128) {
            ((ushort*)outv)[(size_t)row * 128 + col] = f2bf(v / (1.f + expf(-v)));
          } else {
            ((ushort*)out2v)[(size_t)row * 128 + col - 128] = f2bf(1.f / (1.f + expf(-v)));
          }
        } else if (MODE == 2) {
          ((ushort*)outv)[(size_t)row * 256 + col] = f2bf(0.5f * v * (1.f + erff(v * 0.7071067811865475f)));
        } else {
          ((float*)outv)[(size_t)row * 128 + col] += v;
        }
      }
    }
  }
}

// ---------------- u = silu(xp) @ x_w^T + x_b  (N=16, bf16 inputs) ----------------
__global__ __launch_bounds__(256) void k_ub(const ushort* __restrict__ XP, const ushort* __restrict__ xw,
                                            const float* __restrict__ xb, float* __restrict__ U) {
  __shared__ float xs[16 * 132];
  __shared__ float wsm[16 * 129];
  const int m0 = blockIdx.x * 16;
  const int t = threadIdx.x;
  for (int idx = t; idx < 2048; idx += 256) {
    wsm[(idx >> 7) * 129 + (idx & 127)] = bf2f(xw[idx]);
    xs[(idx >> 7) * 132 + (idx & 127)] = bf2f(XP[(size_t)m0 * 128 + idx]);
  }
  __syncthreads();
  const int ds = t & 15, ml = t >> 4;
  float acc = 0.f;
#pragma unroll 16
  for (int k = 0; k < 128; k++) acc += xs[ml * 132 + k] * wsm[ds * 129 + k];
  U[(size_t)(m0 + ml) * 16 + ds] = acc + xb[ds];
}

// ---------------- chunked parallel linear scan ----------------
__global__ __launch_bounds__(64) void k_scan(const float* __restrict__ U, float* __restrict__ HST,
                                             const float* __restrict__ A_log) {
  __shared__ float lds[64 * 65];
  const int b = blockIdx.x >> 4, ds = blockIdx.x & 15;
  const int tid = threadIdx.x;
  const float a = expf(-expf(A_log[ds]));
  const float* ub = U + (size_t)b * Ln * 16 + ds;
  for (int j = 0; j < 64; j++) lds[j * 65 + tid] = ub[(size_t)(j * 64 + tid) * 16];
  __syncthreads();
  float h = 0.f;
  for (int j = 0; j < 64; j++) {
    h = a * h + lds[tid * 65 + j];
    lds[tid * 65 + j] = h;
  }
  float a64 = a;
#pragma unroll
  for (int q = 0; q < 6; q++) a64 *= a64;
  float Ac = a64, Bc = h;
#pragma unroll
  for (int off = 1; off < 64; off <<= 1) {
    float Ap = __shfl_up(Ac, off);
    float Bp = __shfl_up(Bc, off);
    if (tid >= off) { Bc = Ac * Bp + Bc; Ac = Ac * Ap; }
  }
  float carry = __shfl_up(Bc, 1);
  if (tid == 0) carry = 0.f;
  float p = a;
  for (int j = 0; j < 64; j++) {
    lds[tid * 65 + j] += p * carry;
    p *= a;
  }
  __syncthreads();
  float* hb = HST + (size_t)(b * 16 + ds) * Ln;
  for (int j = 0; j < 64; j++) hb[j * 64 + tid] = lds[j * 65 + tid];
}

// ---------------- y = (hs @ D) * z  (z bf16, y bf16 out) ----------------
__global__ __launch_bounds__(256) void k_yb(const float* __restrict__ HST, const float* __restrict__ Dm_,
                                            const ushort* __restrict__ Z, ushort* __restrict__ Y) {
  const int m = blockIdx.x * 2 + (threadIdx.x >> 7);
  const int d = threadIdx.x & 127;
  const int b = m >> 12, l = m & 4095;
  const float* hb = HST + (size_t)b * 16 * Ln + l;
  float acc = 0.f;
#pragma unroll
  for (int s = 0; s < 16; s++) acc += hb[(size_t)s * Ln] * Dm_[s * 128 + d];
  const size_t o = (size_t)m * 128 + d;
  Y[o] = f2bf(acc * bf2f(Z[o]));
}

// ---------------- fp32 [B,HW,128] -> bf16 channels-last slot [B,HW,256] at +128 ----------------
__global__ void k_tobf(const float* __restrict__ in, ushort* __restrict__ out) {
  int i = blockIdx.x * 256 + threadIdx.x; // Mtok*32
  int row = i >> 5, c4 = (i & 31) * 4;
  float4 v = *(const float4*)(in + (size_t)row * 128 + c4);
  ushort4 o;
  o.x = f2bf(v.x); o.y = f2bf(v.y); o.z = f2bf(v.z); o.w = f2bf(v.w);
  *(ushort4*)(out + (size_t)row * 256 + 128 + c4) = o;
}

// ---------------- conv weight converts to bf16 [tap][Cout][Cin] ----------------
__global__ void k_wc9(const float* __restrict__ w, ushort* __restrict__ Wb, int Cin, int Cout) {
  int i = blockIdx.x * 256 + threadIdx.x;
  if (i >= Cout * Cin * 9) return;
  int co = i / (Cin * 9);
  int r = i - co * (Cin * 9);
  int ci = r / 9, tap = r - ci * 9;
  Wb[((size_t)tap * Cout + co) * Cin + ci] = f2bf(w[i]);
}
__global__ void k_wc16(const float* __restrict__ w, ushort* __restrict__ Wb, int Cin, int Cout) {
  int i = blockIdx.x * 256 + threadIdx.x;
  if (i >= Cin * Cout * 16) return;
  int ci = i / (Cout * 16);
  int r = i - ci * (Cout * 16);
  int co = r >> 4, tap = r & 15;
  Wb[((size_t)tap * Cout + co) * Cin + ci] = f2bf(w[i]);
}

// ---------------- LDS-staged implicit-GEMM conv ----------------
// MODE 0: 3x3 pad1 s1 | MODE 1: 3x3 pad1 s2 | MODE 2: convT k4 s2 p1 (parity=blockIdx.y)
// Block: 4 waves; output tile OTH x OTW spatial (input coords for MODE2), 64 couts (16/wave).
// A staged in LDS per 32-ch chunk (80B/pixel stride: 2-way bank aliasing = free).
// wt layout [tapw][Cout][Cin].
template <int MODE, int OTH, int OTW, int CIN>
__global__ __launch_bounds__(256) void k_cv(
    const ushort* __restrict__ in, ushort* __restrict__ out,
    const ushort* __restrict__ wt, const float* __restrict__ bias,
    int Hi, int Wi, int CP, int CO, int CPo, int COo, int Cout,
    int nsp, int nspx, long ibs, long obs) {
  constexpr int ITH = (MODE == 1) ? (2 * OTH + 1) : (OTH + 2);
  constexpr int ITW = (MODE == 1) ? (2 * OTW + 1) : (OTW + 2);
  constexpr int NPIX = ITH * ITW;
  constexpr int SPF = OTH * OTW / 16;
  constexpr int NTAPS = (MODE == 2) ? 4 : 9;
  constexpr int NCH = CIN / 32;
  __shared__ __attribute__((aligned(16))) ushort lds[NPIX * 40];
  const int t = threadIdx.x;
  const int w = t >> 6, l = t & 63;
  const int l15 = l & 15, q = l >> 4;
  const int b = blockIdx.z;
  const int py = (MODE == 2) ? ((int)blockIdx.y >> 1) : 0;
  const int px = (MODE == 2) ? ((int)blockIdx.y & 1) : 0;
  const int cb = blockIdx.x / nsp;
  const int spt = blockIdx.x - cb * nsp;
  const int spy = spt / nspx, spx = spt - spy * nspx;
  const int n0 = cb * 64 + w * 16;
  const int y0 = spy * OTH, x0 = spx * OTW;
  const int gy0 = (MODE == 1) ? (2 * y0 - 1) : (y0 - 1);
  const int gx0 = (MODE == 1) ? (2 * x0 - 1) : (x0 - 1);
  const ushort* ib = in + (size_t)b * ibs;
  f32x4 acc[SPF] = {};
  int abase[SPF];
#pragma unroll
  for (int af = 0; af < SPF; af++) {
    int p = af * 16 + l15;
    int ty = p / OTW, tx = p % OTW;
    int sy = (MODE == 1) ? (2 * ty) : ty;
    int sx = (MODE == 1) ? (2 * tx) : tx;
    abase[af] = (sy * ITW + sx) * 40 + q * 8;
  }
  for (int c = 0; c < NCH; c++) {
    const int k0 = c * 32;
    __syncthreads();
    for (int idx = t; idx < NPIX * 4; idx += 256) {
      int pix = idx >> 2, qq = idx & 3;
      int sy = pix / ITW, sx = pix - sy * ITW;
      int gy = gy0 + sy, gx = gx0 + sx;
      bfx8 v = {0, 0, 0, 0, 0, 0, 0, 0};
      if ((unsigned)gy < (unsigned)Hi && (unsigned)gx < (unsigned)Wi)
        v = *(const bfx8*)(ib + (size_t)(gy * Wi + gx) * CP + CO + k0 + qq * 8);
      *(bfx8*)&lds[pix * 40 + qq * 8] = v;
    }
    __syncthreads();
#pragma unroll
    for (int tap = 0; tap < NTAPS; tap++) {
      const int dy = (MODE == 2) ? (tap >> 1) : (tap / 3);
      const int dx = (MODE == 2) ? (tap & 1) : (tap - (tap / 3) * 3);
      const int tapw = (MODE == 2) ? ((3 - py - 2 * dy) * 4 + (3 - px - 2 * dx)) : tap;
      const int toff = (MODE == 2) ? (((py + dy) * ITW + (px + dx)) * 40)
                                   : ((dy * ITW + dx) * 40);
      bfx8 bv = *(const bfx8*)(wt + ((size_t)tapw * Cout + n0 + l15) * CIN + k0 + q * 8);
#pragma unroll
      for (int af = 0; af < SPF; af++) {
        bfx8 av = *(const bfx8*)&lds[abase[af] + toff];
        acc[af] = __builtin_amdgcn_mfma_f32_16x16x32_bf16(av, bv, acc[af], 0, 0, 0);
      }
    }
  }
  const float bb = bias[n0 + l15];
  ushort* ob = out + (size_t)b * obs + COo + n0 + l15;
#pragma unroll
  for (int af = 0; af < SPF; af++) {
#pragma unroll
    for (int r = 0; r < 4; r++) {
      int p = af * 16 + q * 4 + r;
      int ty = p / OTW, tx = p % OTW;
      int oy, ox, Wo;
      if (MODE == 2) { oy = (y0 + ty) * 2 + py; ox = (x0 + tx) * 2 + px; Wo = Wi * 2; }
      else if (MODE == 1) { oy = y0 + ty; ox = x0 + tx; Wo = Wi / 2; }
      else { oy = y0 + ty; ox = x0 + tx; Wo = Wi; }
      ob[(size_t)(oy * Wo + ox) * CPo] = f2bf(fmaxf(acc[af][r] + bb, 0.f));
    }
  }
}

// ---------------- final 1x1 conv 256 -> 2 (channels-last bf16 input) ----------------
__global__ void k_final2(const ushort* __restrict__ in, const float* __restrict__ w,
                         const float* __restrict__ bias, float* __restrict__ out) {
  int i = blockIdx.x * 256 + threadIdx.x; // B*4096
  int b = i >> 12, p = i & 4095;
  const ushort* row = in + (size_t)i * 256;
  float a0 = bias[0], a1 = bias[1];
  for (int c = 0; c < 256; c += 4) {
    ushort4 u = *(const ushort4*)(row + c);
    float4 w0 = *(const float4*)(w + c);
    float4 w1 = *(const float4*)(w + 256 + c);
    float f0 = bf2f(u.x), f1 = bf2f(u.y), f2 = bf2f(u.z), f3 = bf2f(u.w);
    a0 += f0 * w0.x + f1 * w0.y + f2 * w0.z + f3 * w0.w;
    a1 += f0 * w1.x + f1 * w1.y + f2 * w1.z + f3 * w1.w;
  }
  out[(size_t)b * 8192 + p] = a0;
  out[(size_t)b * 8192 + 4096 + p] = a1;
}

extern "C" void kernel_launch(void* const* d_in, const int* in_sizes, int n_in,
                              void* d_out, int out_size, void* d_ws, size_t ws_size,
                              hipStream_t stream) {
  (void)in_sizes; (void)n_in; (void)out_size; (void)ws_size;
  const float* x          = (const float*)d_in[0];
  const float* emb_w      = (const float*)d_in[1];
  const float* emb_b      = (const float*)d_in[2];
  const float* pos_embed  = (const float*)d_in[3];
  const float* time_embed = (const float*)d_in[4];
  const float* blk_ln1_w  = (const float*)d_in[5];
  const float* blk_ln1_b  = (const float*)d_in[6];
  const float* blk_conv_w = (const float*)d_in[7];
  const float* blk_conv_b = (const float*)d_in[8];
  const float* blk_sln_w  = (const float*)d_in[9];
  const float* blk_sln_b  = (const float*)d_in[10];
  const float* blk_A_log  = (const float*)d_in[11];
  const float* blk_D      = (const float*)d_in[12];
  const float* blk_in_w   = (const float*)d_in[13];
  const float* blk_in_b   = (const float*)d_in[14];
  const float* blk_x_w    = (const float*)d_in[15];
  const float* blk_x_b    = (const float*)d_in[16];
  const float* blk_out_w  = (const float*)d_in[17];
  const float* blk_out_b  = (const float*)d_in[18];
  const float* blk_ln2_w  = (const float*)d_in[19];
  const float* blk_ln2_b  = (const float*)d_in[20];
  const float* blk_mlp_w1 = (const float*)d_in[21];
  const float* blk_mlp_b1 = (const float*)d_in[22];
  const float* blk_mlp_w2 = (const float*)d_in[23];
  const float* blk_mlp_b2 = (const float*)d_in[24];
  const float* down1_w    = (const float*)d_in[25];
  const float* down1_b    = (const float*)d_in[26];
  const float* down2_w    = (const float*)d_in[27];
  const float* down2_b    = (const float*)d_in[28];
  const float* bott_w     = (const float*)d_in[29];
  const float* bott_b     = (const float*)d_in[30];
  const float* up1_w      = (const float*)d_in[31];
  const float* up1_b      = (const float*)d_in[32];
  const float* up2_w      = (const float*)d_in[33];
  const float* up2_b      = (const float*)d_in[34];
  const float* final_w    = (const float*)d_in[35];
  const float* final_b    = (const float*)d_in[36];

  // workspace layout (floats). total 34 MiFloats = 136 MiB.
  float* ws = (float*)d_ws;
  constexpr size_t F = 1u << 20;
  float* EMB  = ws;            // fp32 residual [M,128], 8F
  float* T1   = ws + 8 * F;    // bf16 xn/y/m-A 8F  (UNet: U1cat/X2b/X3b/conv weights)
  float* T2   = ws + 16 * F;   // bf16 xp|z / mlp hidden 8F (UNet: U2cat)
  float* T3   = ws + 24 * F;   // bf16 trunk weights + cwT 8F
  float* Ubuf = ws + 32 * F;   // u [M,16] fp32 1F (also xc scratch)
  float* HST  = ws + 33 * F;   // hs^T fp32 1F

  ushort* XN   = (ushort*)T1;                 // [M,128] bf16
  ushort* XPu  = (ushort*)T2;                 // [M,128] bf16
  ushort* Zu   = XPu + (size_t)Mtok * 128;    // [M,128] bf16
  ushort* MH   = (ushort*)T2;                 // [M,256] bf16 (after xp/z dead)
  ushort* Wi   = (ushort*)T3;                 // 2*256*128
  ushort* Wo   = Wi + 65536;                  // 2*128*128
  ushort* Wm1  = Wo + 32768;                  // 2*256*128
  ushort* Wm2  = Wm1 + 65536;                 // 2*128*256
  ushort* Wx   = Wm2 + 65536;                 // 2*16*128
  float*  CWT  = (float*)(Wx + 4096);         // 2*4*128 fp32

  // trunk weight converts (tiny)
  k_cvt<<<256, 256, 0, stream>>>(blk_in_w, Wi, 65536);
  k_cvt<<<128, 256, 0, stream>>>(blk_out_w, Wo, 32768);
  k_cvt<<<256, 256, 0, stream>>>(blk_mlp_w1, Wm1, 65536);
  k_cvt<<<256, 256, 0, stream>>>(blk_mlp_w2, Wm2, 65536);
  k_cvt<<<16, 256, 0, stream>>>(blk_x_w, Wx, 4096);
  k_cwt<<<4, 256, 0, stream>>>(blk_conv_w, CWT);

  k_combine<<<256, 256, 0, stream>>>(x, Ubuf);
  k_embed<<<Mtok, 128, 0, stream>>>(Ubuf, emb_w, emb_b, pos_embed, time_embed, EMB);

  for (int i = 0; i < 2; i++) {
    k_lnb<<<Mtok / 8, 256, 0, stream>>>(EMB, XN, blk_ln1_w + i * Dn, blk_ln1_b + i * Dn);
    k_dwconvb8<<<(Mtok * 16) / 256, 256, 0, stream>>>(XN, EMB, CWT + i * 512, blk_conv_b + i * Dn);
    k_lnb<<<Mtok / 8, 256, 0, stream>>>(EMB, XN, blk_sln_w + i * Dn, blk_sln_b + i * Dn);
    k_mgemm<1, 128><<<dim3(Mtok / 128, 2), 256, 0, stream>>>(XN, Wi + i * 32768, blk_in_b + i * 256,
                                                             XPu, Zu);
    k_ub<<<Mtok / 16, 256, 0, stream>>>(XPu, Wx + i * 2048, blk_x_b + i * DSn, Ubuf);
    k_scan<<<Bn * DSn, 64, 0, stream>>>(Ubuf, HST, blk_A_log + i * DSn);
    k_yb<<<Mtok / 2, 256, 0, stream>>>(HST, blk_D + i * DSn * Dn, Zu, XN);
    k_mgemm<3, 128><<<dim3(Mtok / 128, 1), 256, 0, stream>>>(XN, Wo + i * 16384, blk_out_b + i * Dn,
                                                             EMB, nullptr);
    k_lnb<<<Mtok / 8, 256, 0, stream>>>(EMB, XN, blk_ln2_w + i * Dn, blk_ln2_b + i * Dn);
    k_mgemm<2, 128><<<dim3(Mtok / 128, 2), 256, 0, stream>>>(XN, Wm1 + i * 32768, blk_mlp_b1 + i * 256,
                                                             MH, nullptr);
    k_mgemm<3, 256><<<dim3(Mtok / 128, 1), 256, 0, stream>>>(MH, Wm2 + i * 32768, blk_mlp_b2 + i * Dn,
                                                             EMB, nullptr);
  }

  // ---- UNet head, channels-last bf16 ----
  ushort* U2C = (ushort*)T2;              // [B,64,64,256]
  ushort* U1C = (ushort*)T1;              // [B,32,32,256]
  ushort* X2b = U1C + 4194304;            // [B,16,16,256]
  ushort* X3b = X2b + 1048576;            // [B,16,16,256]
  ushort* Wd1 = X3b + 1048576;            // 9*128*128
  ushort* Wd2 = Wd1 + 147456;             // 9*256*128
  ushort* Wb9 = Wd2 + 294912;             // 9*256*256
  ushort* Wu1 = Wb9 + 589824;             // 16*128*256
  ushort* Wu2 = Wu1 + 524288;             // 16*128*256

  k_tobf<<<8192, 256, 0, stream>>>(EMB, U2C);
  k_wc9<<<(147456 + 255) / 256, 256, 0, stream>>>(down1_w, Wd1, 128, 128);
  k_wc9<<<(294912 + 255) / 256, 256, 0, stream>>>(down2_w, Wd2, 128, 256);
  k_wc9<<<(589824 + 255) / 256, 256, 0, stream>>>(bott_w, Wb9, 256, 256);
  k_wc16<<<(524288 + 255) / 256, 256, 0, stream>>>(up1_w, Wu1, 256, 128);
  k_wc16<<<(524288 + 255) / 256, 256, 0, stream>>>(up2_w, Wu2, 256, 128);

  // down1: U2C chans 128.. (64x64,128ch) -> U1C chans 128.. (32x32,128co)
  k_cv<1, 8, 8, 128><<<dim3(2 * 16, 1, 16), 256, 0, stream>>>(
      U2C, U1C, Wd1, down1_b, 64, 64, 256, 128, 256, 128, 128,
      16, 4, 64L * 64 * 256, 32L * 32 * 256);
  // down2: U1C chans 128.. (32x32,128ch) -> X2b (16x16,256co)
  k_cv<1, 8, 8, 128><<<dim3(4 * 4, 1, 16), 256, 0, stream>>>(
      U1C, X2b, Wd2, down2_b, 32, 32, 256, 128, 256, 0, 256,
      4, 2, 32L * 32 * 256, 16L * 16 * 256);
  // bott: X2b -> X3b (16x16,256ch->256co)
  k_cv<0, 8, 8, 256><<<dim3(4 * 4, 1, 16), 256, 0, stream>>>(
      X2b, X3b, Wb9, bott_b, 16, 16, 256, 0, 256, 0, 256,
      4, 2, 16L * 16 * 256, 16L * 16 * 256);
  // up1 (convT): X3b (16x16,256ch) -> U1C chans 0..127 (32x32,128co)
  k_cv<2, 8, 16, 256><<<dim3(2 * 2, 4, 16), 256, 0, stream>>>(
      X3b, U1C, Wu1, up1_b, 16, 16, 256, 0, 256, 0, 128,
      2, 1, 16L * 16 * 256, 32L * 32 * 256);
  // up2 (convT): U1C (32x32,256ch) -> U2C chans 0..127 (64x64,128co)
  k_cv<2, 16, 16, 256><<<dim3(2 * 4, 4, 16), 256, 0, stream>>>(
      U1C, U2C, Wu2, up2_b, 32, 32, 256, 0, 256, 0, 128,
      4, 2, 32L * 32 * 256, 64L * 64 * 256);

  k_final2<<<256, 256, 0, stream>>>(U2C, final_w, final_b, (float*)d_out);
}

// Round 6
// 554.541 us; speedup vs baseline: 15.5829x; 1.1752x over previous
//
#include <hip/hip_runtime.h>
#include <cmath>

namespace {
constexpr int Bn = 16, Ln = 4096, Dn = 128, DSn = 16;
constexpr int Mtok = Bn * Ln; // 65536 tokens
}

typedef short bfx8 __attribute__((ext_vector_type(8)));
typedef float f32x4 __attribute__((ext_vector_type(4)));

static __device__ __forceinline__ ushort f2bf(float f) {
  union { float f; unsigned u; } v; v.f = f;
  unsigned r = v.u + 0x7fff + ((v.u >> 16) & 1);
  return (ushort)(r >> 16);
}
static __device__ __forceinline__ float bf2f(ushort u) {
  union { unsigned u; float f; } v; v.u = ((unsigned)u) << 16;
  return v.f;
}

// ---------------- all weight preprocessing in one kernel ----------------
// segments (cumulative ends):
//  in_w cvt 65536 | out_w 98304 | mlp_w1 163840 | mlp_w2 229376 | x_w 233472
//  | cwT 234496 | d1 wc9(128,128) 381952 | d2 wc9(128,256) 676864
//  | bott wc9(256,256) 1266688 | up1 wc16(256,128) 1790976 | up2 2315264
__global__ void k_prep(const float* __restrict__ inw, const float* __restrict__ outw,
                       const float* __restrict__ m1, const float* __restrict__ m2,
                       const float* __restrict__ xw, const float* __restrict__ cw,
                       const float* __restrict__ d1, const float* __restrict__ d2,
                       const float* __restrict__ bo, const float* __restrict__ u1,
                       const float* __restrict__ u2, ushort* __restrict__ W3,
                       float* __restrict__ CWT) {
  int i = blockIdx.x * 256 + threadIdx.x;
  if (i < 65536) { W3[i] = f2bf(inw[i]); return; }
  if (i < 98304) { W3[i] = f2bf(outw[i - 65536]); return; }
  if (i < 163840) { W3[i] = f2bf(m1[i - 98304]); return; }
  if (i < 229376) { W3[i] = f2bf(m2[i - 163840]); return; }
  if (i < 233472) { W3[i] = f2bf(xw[i - 229376]); return; }
  if (i < 234496) {
    int j = i - 233472; int blk = j >> 9, r = j & 511, d = r >> 2, k = r & 3;
    CWT[blk * 512 + k * 128 + d] = cw[j]; return;
  }
  if (i < 381952) { // down1: w[co][ci][9], 128->128
    int j = i - 234496; int co = j / (128 * 9); int r = j - co * (128 * 9);
    int ci = r / 9, tap = r - ci * 9;
    W3[233472 + ((size_t)tap * 128 + co) * 128 + ci] = f2bf(d1[j]); return;
  }
  if (i < 676864) { // down2: 128->256
    int j = i - 381952; int co = j / (128 * 9); int r = j - co * (128 * 9);
    int ci = r / 9, tap = r - ci * 9;
    W3[380928 + ((size_t)tap * 256 + co) * 128 + ci] = f2bf(d2[j]); return;
  }
  if (i < 1266688) { // bott: 256->256
    int j = i - 676864; int co = j / (256 * 9); int r = j - co * (256 * 9);
    int ci = r / 9, tap = r - ci * 9;
    W3[675840 + ((size_t)tap * 256 + co) * 256 + ci] = f2bf(bo[j]); return;
  }
  if (i < 1790976) { // up1: w[ci][co][16], 256->128
    int j = i - 1266688; int ci = j / (128 * 16); int r = j - ci * (128 * 16);
    int co = r >> 4, tap = r & 15;
    W3[1265664 + ((size_t)tap * 128 + co) * 256 + ci] = f2bf(u1[j]); return;
  }
  if (i < 2315264) { // up2
    int j = i - 1790976; int ci = j / (128 * 16); int r = j - ci * (128 * 16);
    int co = r >> 4, tap = r & 15;
    W3[1789952 + ((size_t)tap * 128 + co) * 256 + ci] = f2bf(u2[j]); return;
  }
}

// ---------------- embedding ----------------
__global__ void k_combine(const float* __restrict__ x, float* __restrict__ xc) {
  int i = blockIdx.x * 256 + threadIdx.x; // B*HW = 65536
  int b = i >> 12, p = i & 4095;
  const float* xb = x + (size_t)b * 5 * Ln + p;
  xc[i] = 0.5f * (xb[0] + xb[Ln] + xb[2 * Ln] + xb[3 * Ln]) + xb[4 * Ln];
}

// embed + ln1 fused: writes EMB fp32 and XN1 = ln1(EMB) bf16
__global__ __launch_bounds__(256) void k_embedln(
    const float* __restrict__ xc, const float* __restrict__ ew, const float* __restrict__ eb,
    const float* __restrict__ pos, const float* __restrict__ te,
    const float* __restrict__ lw, const float* __restrict__ lb,
    float* __restrict__ emb, ushort* __restrict__ xn) {
  int tok = blockIdx.x * 8 + (threadIdx.x >> 5);
  int ln = threadIdx.x & 31;
  int b = tok >> 12, l = tok & 4095;
  int h = l >> 6, w = l & 63;
  const float* xb = xc + b * 4096;
  float v[9];
#pragma unroll
  for (int dy = 0; dy < 3; dy++)
#pragma unroll
    for (int dx = 0; dx < 3; dx++) {
      int y = h + dy - 1, xx = w + dx - 1;
      v[dy * 3 + dx] = (y >= 0 && y < 64 && xx >= 0 && xx < 64) ? xb[y * 64 + xx] : 0.f;
    }
  int d0 = ln * 4;
  float o[4]; float s = 0.f, sq = 0.f;
#pragma unroll
  for (int e = 0; e < 4; e++) {
    int d = d0 + e;
    float a = 0.f;
#pragma unroll
    for (int k = 0; k < 9; k++) a += v[k] * ew[d * 9 + k];
    float ts = 0.5f * (te[d] + te[128 + d] + te[256 + d] + te[384 + d]) + te[512 + d];
    float r = a + 3.f * eb[d] + 3.f * pos[l * 128 + d] + ts;
    o[e] = r; s += r; sq += r * r;
  }
  float4 f4; f4.x = o[0]; f4.y = o[1]; f4.z = o[2]; f4.w = o[3];
  *(float4*)(emb + (size_t)tok * 128 + d0) = f4;
#pragma unroll
  for (int off = 16; off; off >>= 1) { s += __shfl_xor(s, off); sq += __shfl_xor(sq, off); }
  float m = s * (1.f / 128.f);
  float var = sq * (1.f / 128.f) - m * m;
  float rs = rsqrtf(var + 1e-5f);
  ushort4 u;
  u.x = f2bf((o[0] - m) * rs * lw[d0 + 0] + lb[d0 + 0]);
  u.y = f2bf((o[1] - m) * rs * lw[d0 + 1] + lb[d0 + 1]);
  u.z = f2bf((o[2] - m) * rs * lw[d0 + 2] + lb[d0 + 2]);
  u.w = f2bf((o[3] - m) * rs * lw[d0 + 3] + lb[d0 + 3]);
  *(ushort4*)(xn + (size_t)tok * 128 + d0) = u;
}

// ---------------- fused dwconv + residual + sln ----------------
// xn1 = ln1(emb) precomputed (bf16); emb RMW fp32; xn2 = sln(emb') bf16
__global__ __launch_bounds__(256) void k_fuse1(
    const ushort* __restrict__ xn1, float* __restrict__ emb, ushort* __restrict__ xn2,
    const float* __restrict__ cwT, const float* __restrict__ cb,
    const float* __restrict__ sw, const float* __restrict__ sb) {
  int i = blockIdx.x * 256 + threadIdx.x; // Mtok*16
  int g = i & 15, tok = i >> 4, d0 = g * 8, l = tok & 4095;
  const ushort* p = xn1 + (size_t)tok * 128 + d0;
  const bfx8 zf = {0, 0, 0, 0, 0, 0, 0, 0};
  bfx8 v0 = *(const bfx8*)p;
  bfx8 v1 = (l >= 1) ? *(const bfx8*)(p - 128) : zf;
  bfx8 v2 = (l >= 2) ? *(const bfx8*)(p - 256) : zf;
  bfx8 v3 = (l >= 3) ? *(const bfx8*)(p - 384) : zf;
  float* ep = emb + (size_t)tok * 128 + d0;
  float4 e0 = *(const float4*)ep;
  float4 e1 = *(const float4*)(ep + 4);
  float ev[8] = {e0.x, e0.y, e0.z, e0.w, e1.x, e1.y, e1.z, e1.w};
  float nv[8]; float s = 0.f, sq = 0.f;
#pragma unroll
  for (int e = 0; e < 8; e++) {
    int d = d0 + e;
    float c = cb[d] + cwT[3 * 128 + d] * bf2f((ushort)v0[e]) + cwT[2 * 128 + d] * bf2f((ushort)v1[e]) +
              cwT[1 * 128 + d] * bf2f((ushort)v2[e]) + cwT[0 * 128 + d] * bf2f((ushort)v3[e]);
    nv[e] = ev[e] + c;
    s += nv[e]; sq += nv[e] * nv[e];
  }
  float4 w0; w0.x = nv[0]; w0.y = nv[1]; w0.z = nv[2]; w0.w = nv[3];
  float4 w1; w1.x = nv[4]; w1.y = nv[5]; w1.z = nv[6]; w1.w = nv[7];
  *(float4*)ep = w0;
  *(float4*)(ep + 4) = w1;
#pragma unroll
  for (int off = 8; off; off >>= 1) { s += __shfl_xor(s, off); sq += __shfl_xor(sq, off); }
  float m = s * (1.f / 128.f);
  float var = sq * (1.f / 128.f) - m * m;
  float rs = rsqrtf(var + 1e-5f);
  bfx8 r8;
#pragma unroll
  for (int e = 0; e < 8; e++) {
    int d = d0 + e;
    r8[e] = (short)f2bf((nv[e] - m) * rs * sw[d] + sb[d]);
  }
  *(bfx8*)(xn2 + (size_t)tok * 128 + d0) = r8;
}

// ---------------- MFMA GEMM: C[M,N] = A[M,K](bf16) @ W[N,K]^T(bf16) + epilogue ----
// MODE 1: col<128 silu -> outv bf16 [M,128]; col>=128 sigmoid -> out2v bf16 [M,128]
// MODE 2: gelu -> outv bf16 [M,256]
// MODE 5: emb += v (fp32); LN(emb') with lw/lb -> out2v bf16 [M,128]   (grid.y==1)
// MODE 4: emb += v (fp32); bf16 convert -> out2v channels-last [M,256] at +128 (grid.y==1)
template <int MODE, int K>
__global__ __launch_bounds__(256) void k_mgemm(const ushort* __restrict__ A, const ushort* __restrict__ W,
                                               const float* __restrict__ bias, void* __restrict__ outv,
                                               void* __restrict__ out2v, float* __restrict__ emb,
                                               const float* __restrict__ lw, const float* __restrict__ lb) {
  __shared__ float red[2][128][2];
  const int t = threadIdx.x;
  const int l = t & 63, wv = t >> 6;
  const int l15 = l & 15, q = l >> 4;
  const int wm = wv >> 1, wn = wv & 1;
  const int m0 = blockIdx.x * 128 + wm * 64;
  const int n0 = blockIdx.y * 128 + wn * 64;
  f32x4 acc[4][4] = {};
  const ushort* Ab = A + (size_t)(m0 + l15) * K + q * 8;
  const ushort* Wb = W + (size_t)(n0 + l15) * K + q * 8;
#pragma unroll
  for (int k0 = 0; k0 < K; k0 += 32) {
    bfx8 a[4], b[4];
#pragma unroll
    for (int mf = 0; mf < 4; mf++) a[mf] = *(const bfx8*)(Ab + (size_t)mf * 16 * K + k0);
#pragma unroll
    for (int nf = 0; nf < 4; nf++) b[nf] = *(const bfx8*)(Wb + (size_t)nf * 16 * K + k0);
#pragma unroll
    for (int mf = 0; mf < 4; mf++)
#pragma unroll
      for (int nf = 0; nf < 4; nf++)
        acc[mf][nf] = __builtin_amdgcn_mfma_f32_16x16x32_bf16(a[mf], b[nf], acc[mf][nf], 0, 0, 0);
  }
  if constexpr (MODE == 1 || MODE == 2) {
#pragma unroll
    for (int mf = 0; mf < 4; mf++) {
#pragma unroll
      for (int nf = 0; nf < 4; nf++) {
        const int col = n0 + nf * 16 + l15;
        const float bb = bias[col];
#pragma unroll
        for (int r = 0; r < 4; r++) {
          const int row = m0 + mf * 16 + q * 4 + r;
          float v = acc[mf][nf][r] + bb;
          if (MODE == 1) {
            if (col < 128) {
              ((ushort*)outv)[(size_t)row * 128 + col] = f2bf(v / (1.f + expf(-v)));
            } else {
              ((ushort*)out2v)[(size_t)row * 128 + col - 128] = f2bf(1.f / (1.f + expf(-v)));
            }
          } else {
            ((ushort*)outv)[(size_t)row * 256 + col] = f2bf(0.5f * v * (1.f + erff(v * 0.7071067811865475f)));
          }
        }
      }
    }
  } else {
    // MODE 4/5: accumulate into fp32 residual, then LN or bf16-convert epilogue
    float sv[4][4], qv[4][4];
#pragma unroll
    for (int mf = 0; mf < 4; mf++)
#pragma unroll
      for (int r = 0; r < 4; r++) { sv[mf][r] = 0.f; qv[mf][r] = 0.f; }
#pragma unroll
    for (int mf = 0; mf < 4; mf++) {
#pragma unroll
      for (int nf = 0; nf < 4; nf++) {
        const int col = n0 + nf * 16 + l15;
        const float bb = bias[col];
#pragma unroll
        for (int r = 0; r < 4; r++) {
          const int row = m0 + mf * 16 + q * 4 + r;
          float v = acc[mf][nf][r] + bb + emb[(size_t)row * 128 + col];
          acc[mf][nf][r] = v;
          sv[mf][r] += v; qv[mf][r] += v * v;
        }
      }
    }
    if constexpr (MODE == 5) {
#pragma unroll
      for (int mf = 0; mf < 4; mf++)
#pragma unroll
        for (int r = 0; r < 4; r++) {
#pragma unroll
          for (int off = 1; off < 16; off <<= 1) {
            sv[mf][r] += __shfl_xor(sv[mf][r], off);
            qv[mf][r] += __shfl_xor(qv[mf][r], off);
          }
          if (l15 == 0) {
            int rowl = wm * 64 + mf * 16 + q * 4 + r;
            red[0][rowl][wn] = sv[mf][r];
            red[1][rowl][wn] = qv[mf][r];
          }
        }
      __syncthreads();
    }
#pragma unroll
    for (int mf = 0; mf < 4; mf++)
#pragma unroll
      for (int r = 0; r < 4; r++) {
        const int rowl = wm * 64 + mf * 16 + q * 4 + r;
        const int row = blockIdx.x * 128 + rowl;
        float mm = 0.f, rs = 0.f;
        if constexpr (MODE == 5) {
          float ts = red[0][rowl][0] + red[0][rowl][1];
          float tq = red[1][rowl][0] + red[1][rowl][1];
          mm = ts * (1.f / 128.f);
          float var = tq * (1.f / 128.f) - mm * mm;
          rs = rsqrtf(var + 1e-5f);
        }
#pragma unroll
        for (int nf = 0; nf < 4; nf++) {
          const int col = n0 + nf * 16 + l15;
          float v = acc[mf][nf][r];
          emb[(size_t)row * 128 + col] = v;
          if constexpr (MODE == 5)
            ((ushort*)out2v)[(size_t)row * 128 + col] = f2bf((v - mm) * rs * lw[col] + lb[col]);
          else
            ((ushort*)out2v)[(size_t)row * 256 + 128 + col] = f2bf(v);
        }
      }
  }
}

// ---------------- u = silu(xp) @ x_w^T + x_b, written TRANSPOSED [b][ds][L] ----------------
__global__ __launch_bounds__(256) void k_ub(const ushort* __restrict__ XP, const ushort* __restrict__ xw,
                                            const float* __restrict__ xb, float* __restrict__ UT) {
  __shared__ float xs[16 * 132];
  __shared__ float wsm[16 * 129];
  const int m0 = blockIdx.x * 16;
  const int t = threadIdx.x;
  for (int idx = t; idx < 2048; idx += 256) {
    wsm[(idx >> 7) * 129 + (idx & 127)] = bf2f(xw[idx]);
    xs[(idx >> 7) * 132 + (idx & 127)] = bf2f(XP[(size_t)m0 * 128 + idx]);
  }
  __syncthreads();
  const int ds = t & 15, ml = t >> 4;
  float acc = 0.f;
#pragma unroll 16
  for (int k = 0; k < 128; k++) acc += xs[ml * 132 + k] * wsm[ds * 129 + k];
  const int b = m0 >> 12, l0 = m0 & 4095;
  UT[((size_t)(b * 16 + ds)) * 4096 + l0 + ml] = acc + xb[ds];
}

// ---------------- register chunked scan: h_t = a*h_{t-1} + u_t ----------------
// UT and HST both [b][ds][L]; one wave per (b,ds); lane tid owns chunk [tid*64, tid*64+64)
__global__ __launch_bounds__(64) void k_scan(const float* __restrict__ UT, float* __restrict__ HST,
                                             const float* __restrict__ A_log) {
  const int b = blockIdx.x >> 4, ds = blockIdx.x & 15;
  const int tid = threadIdx.x;
  const float a = expf(-expf(A_log[ds]));
  const float4* ut4 = (const float4*)(UT + ((size_t)(b * 16 + ds)) * 4096 + tid * 64);
  float r[64];
#pragma unroll
  for (int j4 = 0; j4 < 16; j4++) {
    float4 v = ut4[j4];
    r[j4 * 4 + 0] = v.x; r[j4 * 4 + 1] = v.y; r[j4 * 4 + 2] = v.z; r[j4 * 4 + 3] = v.w;
  }
  float h = 0.f;
#pragma unroll
  for (int j = 0; j < 64; j++) { h = a * h + r[j]; r[j] = h; }
  float a64 = a;
#pragma unroll
  for (int qq = 0; qq < 6; qq++) a64 *= a64;
  float Ac = a64, Bc = h;
#pragma unroll
  for (int off = 1; off < 64; off <<= 1) {
    float Ap = __shfl_up(Ac, off);
    float Bp = __shfl_up(Bc, off);
    if (tid >= off) { Bc = Ac * Bp + Bc; Ac = Ac * Ap; }
  }
  float carry = __shfl_up(Bc, 1);
  if (tid == 0) carry = 0.f;
  float p = a;
#pragma unroll
  for (int j = 0; j < 64; j++) { r[j] += p * carry; p *= a; }
  float4* hb4 = (float4*)(HST + ((size_t)(b * 16 + ds)) * 4096 + tid * 64);
#pragma unroll
  for (int j4 = 0; j4 < 16; j4++) {
    float4 v; v.x = r[j4 * 4 + 0]; v.y = r[j4 * 4 + 1]; v.z = r[j4 * 4 + 2]; v.w = r[j4 * 4 + 3];
    hb4[j4] = v;
  }
}

// ---------------- y = (hs @ D) * z  (z bf16, y bf16 out) ----------------
__global__ __launch_bounds__(256) void k_yb(const float* __restrict__ HST, const float* __restrict__ Dm_,
                                            const ushort* __restrict__ Z, ushort* __restrict__ Y) {
  const int m = blockIdx.x * 2 + (threadIdx.x >> 7);
  const int d = threadIdx.x & 127;
  const int b = m >> 12, l = m & 4095;
  const float* hb = HST + (size_t)b * 16 * Ln + l;
  float acc = 0.f;
#pragma unroll
  for (int s = 0; s < 16; s++) acc += hb[(size_t)s * Ln] * Dm_[s * 128 + d];
  const size_t o = (size_t)m * 128 + d;
  Y[o] = f2bf(acc * bf2f(Z[o]));
}

// ---------------- LDS-staged implicit-GEMM conv (unchanged from round 5) ----------------
template <int MODE, int OTH, int OTW, int CIN>
__global__ __launch_bounds__(256) void k_cv(
    const ushort* __restrict__ in, ushort* __restrict__ out,
    const ushort* __restrict__ wt, const float* __restrict__ bias,
    int Hi, int Wi, int CP, int CO, int CPo, int COo, int Cout,
    int nsp, int nspx, long ibs, long obs) {
  constexpr int ITH = (MODE == 1) ? (2 * OTH + 1) : (OTH + 2);
  constexpr int ITW = (MODE == 1) ? (2 * OTW + 1) : (OTW + 2);
  constexpr int NPIX = ITH * ITW;
  constexpr int SPF = OTH * OTW / 16;
  constexpr int NTAPS = (MODE == 2) ? 4 : 9;
  constexpr int NCH = CIN / 32;
  __shared__ __attribute__((aligned(16))) ushort lds[NPIX * 40];
  const int t = threadIdx.x;
  const int w = t >> 6, l = t & 63;
  const int l15 = l & 15, q = l >> 4;
  const int b = blockIdx.z;
  const int py = (MODE == 2) ? ((int)blockIdx.y >> 1) : 0;
  const int px = (MODE == 2) ? ((int)blockIdx.y & 1) : 0;
  const int cb = blockIdx.x / nsp;
  const int spt = blockIdx.x - cb * nsp;
  const int spy = spt / nspx, spx = spt - spy * nspx;
  const int n0 = cb * 64 + w * 16;
  const int y0 = spy * OTH, x0 = spx * OTW;
  const int gy0 = (MODE == 1) ? (2 * y0 - 1) : (y0 - 1);
  const int gx0 = (MODE == 1) ? (2 * x0 - 1) : (x0 - 1);
  const ushort* ib = in + (size_t)b * ibs;
  f32x4 acc[SPF] = {};
  int abase[SPF];
#pragma unroll
  for (int af = 0; af < SPF; af++) {
    int p = af * 16 + l15;
    int ty = p / OTW, tx = p % OTW;
    int sy = (MODE == 1) ? (2 * ty) : ty;
    int sx = (MODE == 1) ? (2 * tx) : tx;
    abase[af] = (sy * ITW + sx) * 40 + q * 8;
  }
  for (int c = 0; c < NCH; c++) {
    const int k0 = c * 32;
    __syncthreads();
    for (int idx = t; idx < NPIX * 4; idx += 256) {
      int pix = idx >> 2, qq = idx & 3;
      int sy = pix / ITW, sx = pix - sy * ITW;
      int gy = gy0 + sy, gx = gx0 + sx;
      bfx8 v = {0, 0, 0, 0, 0, 0, 0, 0};
      if ((unsigned)gy < (unsigned)Hi && (unsigned)gx < (unsigned)Wi)
        v = *(const bfx8*)(ib + (size_t)(gy * Wi + gx) * CP + CO + k0 + qq * 8);
      *(bfx8*)&lds[pix * 40 + qq * 8] = v;
    }
    __syncthreads();
#pragma unroll
    for (int tap = 0; tap < NTAPS; tap++) {
      const int dy = (MODE == 2) ? (tap >> 1) : (tap / 3);
      const int dx = (MODE == 2) ? (tap & 1) : (tap - (tap / 3) * 3);
      const int tapw = (MODE == 2) ? ((3 - py - 2 * dy) * 4 + (3 - px - 2 * dx)) : tap;
      const int toff = (MODE == 2) ? (((py + dy) * ITW + (px + dx)) * 40)
                                   : ((dy * ITW + dx) * 40);
      bfx8 bv = *(const bfx8*)(wt + ((size_t)tapw * Cout + n0 + l15) * CIN + k0 + q * 8);
#pragma unroll
      for (int af = 0; af < SPF; af++) {
        bfx8 av = *(const bfx8*)&lds[abase[af] + toff];
        acc[af] = __builtin_amdgcn_mfma_f32_16x16x32_bf16(av, bv, acc[af], 0, 0, 0);
      }
    }
  }
  const float bb = bias[n0 + l15];
  ushort* ob = out + (size_t)b * obs + COo + n0 + l15;
#pragma unroll
  for (int af = 0; af < SPF; af++) {
#pragma unroll
    for (int r = 0; r < 4; r++) {
      int p = af * 16 + q * 4 + r;
      int ty = p / OTW, tx = p % OTW;
      int oy, ox, Wo;
      if (MODE == 2) { oy = (y0 + ty) * 2 + py; ox = (x0 + tx) * 2 + px; Wo = Wi * 2; }
      else if (MODE == 1) { oy = y0 + ty; ox = x0 + tx; Wo = Wi / 2; }
      else { oy = y0 + ty; ox = x0 + tx; Wo = Wi; }
      ob[(size_t)(oy * Wo + ox) * CPo] = f2bf(fmaxf(acc[af][r] + bb, 0.f));
    }
  }
}

// ---------------- final 1x1 conv 256 -> 2 (channels-last bf16 input) ----------------
__global__ void k_final2(const ushort* __restrict__ in, const float* __restrict__ w,
                         const float* __restrict__ bias, float* __restrict__ out) {
  int i = blockIdx.x * 256 + threadIdx.x; // B*4096
  int b = i >> 12, p = i & 4095;
  const ushort* row = in + (size_t)i * 256;
  float a0 = bias[0], a1 = bias[1];
  for (int c = 0; c < 256; c += 4) {
    ushort4 u = *(const ushort4*)(row + c);
    float4 w0 = *(const float4*)(w + c);
    float4 w1 = *(const float4*)(w + 256 + c);
    float f0 = bf2f(u.x), f1 = bf2f(u.y), f2 = bf2f(u.z), f3 = bf2f(u.w);
    a0 += f0 * w0.x + f1 * w0.y + f2 * w0.z + f3 * w0.w;
    a1 += f0 * w1.x + f1 * w1.y + f2 * w1.z + f3 * w1.w;
  }
  out[(size_t)b * 8192 + p] = a0;
  out[(size_t)b * 8192 + 4096 + p] = a1;
}

extern "C" void kernel_launch(void* const* d_in, const int* in_sizes, int n_in,
                              void* d_out, int out_size, void* d_ws, size_t ws_size,
                              hipStream_t stream) {
  (void)in_sizes; (void)n_in; (void)out_size; (void)ws_size;
  const float* x          = (const float*)d_in[0];
  const float* emb_w      = (const float*)d_in[1];
  const float* emb_b      = (const float*)d_in[2];
  const float* pos_embed  = (const float*)d_in[3];
  const float* time_embed = (const float*)d_in[4];
  const float* blk_ln1_w  = (const float*)d_in[5];
  const float* blk_ln1_b  = (const float*)d_in[6];
  const float* blk_conv_w = (const float*)d_in[7];
  const float* blk_conv_b = (const float*)d_in[8];
  const float* blk_sln_w  = (const float*)d_in[9];
  const float* blk_sln_b  = (const float*)d_in[10];
  const float* blk_A_log  = (const float*)d_in[11];
  const float* blk_D      = (const float*)d_in[12];
  const float* blk_in_w   = (const float*)d_in[13];
  const float* blk_in_b   = (const float*)d_in[14];
  const float* blk_x_w    = (const float*)d_in[15];
  const float* blk_x_b    = (const float*)d_in[16];
  const float* blk_out_w  = (const float*)d_in[17];
  const float* blk_out_b  = (const float*)d_in[18];
  const float* blk_ln2_w  = (const float*)d_in[19];
  const float* blk_ln2_b  = (const float*)d_in[20];
  const float* blk_mlp_w1 = (const float*)d_in[21];
  const float* blk_mlp_b1 = (const float*)d_in[22];
  const float* blk_mlp_w2 = (const float*)d_in[23];
  const float* blk_mlp_b2 = (const float*)d_in[24];
  const float* down1_w    = (const float*)d_in[25];
  const float* down1_b    = (const float*)d_in[26];
  const float* down2_w    = (const float*)d_in[27];
  const float* down2_b    = (const float*)d_in[28];
  const float* bott_w     = (const float*)d_in[29];
  const float* bott_b     = (const float*)d_in[30];
  const float* up1_w      = (const float*)d_in[31];
  const float* up1_b      = (const float*)d_in[32];
  const float* up2_w      = (const float*)d_in[33];
  const float* up2_b      = (const float*)d_in[34];
  const float* final_w    = (const float*)d_in[35];
  const float* final_b    = (const float*)d_in[36];

  // workspace layout (floats). total 34 MiFloats = 136 MiB.
  float* ws = (float*)d_ws;
  constexpr size_t F = 1u << 20;
  float* EMB = ws;                            // fp32 residual [M,128], 8F
  ushort* XN1 = (ushort*)(ws + 8 * F);        // ln-out bf16 [M,128] (T1 lower half)
  ushort* XN2 = XN1 + 8 * F;                  // sln-out / y bf16 [M,128] (T1 upper half)
  ushort* XPu = (ushort*)(ws + 16 * F);       // [M,128] bf16 (T2)
  ushort* Zu  = XPu + 8 * F;                  // [M,128] bf16
  ushort* MH  = XPu;                          // [M,256] bf16 (after xp/z dead)
  ushort* W3  = (ushort*)(ws + 24 * F);       // all preprocessed weights (T3)
  float* Ubuf = ws + 32 * F;                  // xc scratch, then U_T [B*16, 4096] fp32
  float* HST  = ws + 33 * F;                  // hs^T fp32

  // W3 offsets (ushorts)
  ushort* Wi  = W3;                 // 2*256*128
  ushort* Wo  = W3 + 65536;         // 2*128*128
  ushort* Wm1 = W3 + 98304;         // 2*256*128
  ushort* Wm2 = W3 + 163840;        // 2*128*256
  ushort* Wx  = W3 + 229376;        // 2*16*128
  ushort* Wd1 = W3 + 233472;        // 9*128*128
  ushort* Wd2 = W3 + 380928;        // 9*256*128
  ushort* Wb9 = W3 + 675840;        // 9*256*256
  ushort* Wu1 = W3 + 1265664;       // 16*128*256
  ushort* Wu2 = W3 + 1789952;       // 16*128*256
  float*  CWT = (float*)(W3 + 2314240); // 2*4*128 fp32

  k_prep<<<9044, 256, 0, stream>>>(blk_in_w, blk_out_w, blk_mlp_w1, blk_mlp_w2, blk_x_w,
                                   blk_conv_w, down1_w, down2_w, bott_w, up1_w, up2_w, W3, CWT);
  k_combine<<<256, 256, 0, stream>>>(x, Ubuf);
  k_embedln<<<8192, 256, 0, stream>>>(Ubuf, emb_w, emb_b, pos_embed, time_embed,
                                      blk_ln1_w, blk_ln1_b, EMB, XN1);

  ushort* U2C = XPu; // [B,64,64,256] channels-last (written by mlp2 MODE4 + up2)
  for (int i = 0; i < 2; i++) {
    k_fuse1<<<4096, 256, 0, stream>>>(XN1, EMB, XN2, CWT + i * 512, blk_conv_b + i * Dn,
                                      blk_sln_w + i * Dn, blk_sln_b + i * Dn);
    k_mgemm<1, 128><<<dim3(512, 2), 256, 0, stream>>>(XN2, Wi + i * 32768, blk_in_b + i * 256,
                                                      XPu, Zu, nullptr, nullptr, nullptr);
    k_ub<<<4096, 256, 0, stream>>>(XPu, Wx + i * 2048, blk_x_b + i * DSn, Ubuf);
    k_scan<<<256, 64, 0, stream>>>(Ubuf, HST, blk_A_log + i * DSn);
    k_yb<<<32768, 256, 0, stream>>>(HST, blk_D + i * DSn * Dn, Zu, XN2);
    k_mgemm<5, 128><<<dim3(512, 1), 256, 0, stream>>>(XN2, Wo + i * 16384, blk_out_b + i * Dn,
                                                      nullptr, XN1, EMB,
                                                      blk_ln2_w + i * Dn, blk_ln2_b + i * Dn);
    k_mgemm<2, 128><<<dim3(512, 2), 256, 0, stream>>>(XN1, Wm1 + i * 32768, blk_mlp_b1 + i * 256,
                                                      MH, nullptr, nullptr, nullptr, nullptr);
    if (i == 0)
      k_mgemm<5, 256><<<dim3(512, 1), 256, 0, stream>>>(MH, Wm2 + i * 32768, blk_mlp_b2 + i * Dn,
                                                        nullptr, XN1, EMB,
                                                        blk_ln1_w + Dn, blk_ln1_b + Dn);
    else
      k_mgemm<4, 256><<<dim3(512, 1), 256, 0, stream>>>(MH, Wm2 + i * 32768, blk_mlp_b2 + i * Dn,
                                                        nullptr, U2C, EMB, nullptr, nullptr);
  }

  // ---- UNet head, channels-last bf16 ----
  ushort* U1C = XN1;              // [B,32,32,256] (T1)
  ushort* X2b = XN1 + 8388608;    // [B,16,16,256]
  ushort* X3b = X2b + 1048576;    // [B,16,16,256]

  k_cv<1, 8, 8, 128><<<dim3(2 * 16, 1, 16), 256, 0, stream>>>(
      U2C, U1C, Wd1, down1_b, 64, 64, 256, 128, 256, 128, 128,
      16, 4, 64L * 64 * 256, 32L * 32 * 256);
  k_cv<1, 8, 8, 128><<<dim3(4 * 4, 1, 16), 256, 0, stream>>>(
      U1C, X2b, Wd2, down2_b, 32, 32, 256, 128, 256, 0, 256,
      4, 2, 32L * 32 * 256, 16L * 16 * 256);
  k_cv<0, 8, 8, 256><<<dim3(4 * 4, 1, 16), 256, 0, stream>>>(
      X2b, X3b, Wb9, bott_b, 16, 16, 256, 0, 256, 0, 256,
      4, 2, 16L * 16 * 256, 16L * 16 * 256);
  k_cv<2, 8, 16, 256><<<dim3(2 * 2, 4, 16), 256, 0, stream>>>(
      X3b, U1C, Wu1, up1_b, 16, 16, 256, 0, 256, 0, 128,
      2, 1, 16L * 16 * 256, 32L * 32 * 256);
  k_cv<2, 16, 16, 256><<<dim3(2 * 4, 4, 16), 256, 0, stream>>>(
      U1C, U2C, Wu2, up2_b, 32, 32, 256, 0, 256, 0, 128,
      4, 2, 32L * 32 * 256, 64L * 64 * 256);

  k_final2<<<256, 256, 0, stream>>>(U2C, final_w, final_b, (float*)d_out);
}

// Round 8
// 503.550 us; speedup vs baseline: 17.1608x; 1.1013x over previous
//
#include <hip/hip_runtime.h>
#include <cmath>

namespace {
constexpr int Bn = 16, Ln = 4096, Dn = 128, DSn = 16;
constexpr int Mtok = Bn * Ln; // 65536 tokens
constexpr int SLS = 138;      // LDS row stride (ushorts) for 128-col bf16 tiles
}

typedef short bfx8 __attribute__((ext_vector_type(8)));
typedef float f32x4 __attribute__((ext_vector_type(4)));

static __device__ __forceinline__ ushort f2bf(float f) {
  union { float f; unsigned u; } v; v.f = f;
  unsigned r = v.u + 0x7fff + ((v.u >> 16) & 1);
  return (ushort)(r >> 16);
}
static __device__ __forceinline__ float bf2f(ushort u) {
  union { unsigned u; float f; } v; v.u = ((unsigned)u) << 16;
  return v.f;
}

// ---------------- all weight preprocessing in one kernel ----------------
__global__ void k_prep(const float* __restrict__ inw, const float* __restrict__ outw,
                       const float* __restrict__ m1, const float* __restrict__ m2,
                       const float* __restrict__ xw, const float* __restrict__ cw,
                       const float* __restrict__ d1, const float* __restrict__ d2,
                       const float* __restrict__ bo, const float* __restrict__ u1,
                       const float* __restrict__ u2, ushort* __restrict__ W3,
                       float* __restrict__ CWT) {
  int i = blockIdx.x * 256 + threadIdx.x;
  if (i < 65536) { W3[i] = f2bf(inw[i]); return; }
  if (i < 98304) { W3[i] = f2bf(outw[i - 65536]); return; }
  if (i < 163840) { W3[i] = f2bf(m1[i - 98304]); return; }
  if (i < 229376) { W3[i] = f2bf(m2[i - 163840]); return; }
  if (i < 233472) { W3[i] = f2bf(xw[i - 229376]); return; }
  if (i < 234496) {
    int j = i - 233472; int blk = j >> 9, r = j & 511, d = r >> 2, k = r & 3;
    CWT[blk * 512 + k * 128 + d] = cw[j]; return;
  }
  if (i < 381952) { // down1: w[co][ci][9], 128->128
    int j = i - 234496; int co = j / (128 * 9); int r = j - co * (128 * 9);
    int ci = r / 9, tap = r - ci * 9;
    W3[233472 + ((size_t)tap * 128 + co) * 128 + ci] = f2bf(d1[j]); return;
  }
  if (i < 676864) { // down2: 128->256
    int j = i - 381952; int co = j / (128 * 9); int r = j - co * (128 * 9);
    int ci = r / 9, tap = r - ci * 9;
    W3[380928 + ((size_t)tap * 256 + co) * 128 + ci] = f2bf(d2[j]); return;
  }
  if (i < 1266688) { // bott: 256->256
    int j = i - 676864; int co = j / (256 * 9); int r = j - co * (256 * 9);
    int ci = r / 9, tap = r - ci * 9;
    W3[675840 + ((size_t)tap * 256 + co) * 256 + ci] = f2bf(bo[j]); return;
  }
  if (i < 1790976) { // up1: w[ci][co][16], 256->128
    int j = i - 1266688; int ci = j / (128 * 16); int r = j - ci * (128 * 16);
    int co = r >> 4, tap = r & 15;
    W3[1265664 + ((size_t)tap * 128 + co) * 256 + ci] = f2bf(u1[j]); return;
  }
  if (i < 2315264) { // up2
    int j = i - 1790976; int ci = j / (128 * 16); int r = j - ci * (128 * 16);
    int co = r >> 4, tap = r & 15;
    W3[1789952 + ((size_t)tap * 128 + co) * 256 + ci] = f2bf(u2[j]); return;
  }
}

// ---------------- embedding ----------------
__global__ void k_combine(const float* __restrict__ x, float* __restrict__ xc) {
  int i = blockIdx.x * 256 + threadIdx.x; // B*HW = 65536
  int b = i >> 12, p = i & 4095;
  const float* xb = x + (size_t)b * 5 * Ln + p;
  xc[i] = 0.5f * (xb[0] + xb[Ln] + xb[2 * Ln] + xb[3 * Ln]) + xb[4 * Ln];
}

// embed + ln1 fused: writes EMB fp32 and XN1 = ln1(EMB) bf16
__global__ __launch_bounds__(256) void k_embedln(
    const float* __restrict__ xc, const float* __restrict__ ew, const float* __restrict__ eb,
    const float* __restrict__ pos, const float* __restrict__ te,
    const float* __restrict__ lw, const float* __restrict__ lb,
    float* __restrict__ emb, ushort* __restrict__ xn) {
  int tok = blockIdx.x * 8 + (threadIdx.x >> 5);
  int ln = threadIdx.x & 31;
  int b = tok >> 12, l = tok & 4095;
  int h = l >> 6, w = l & 63;
  const float* xb = xc + b * 4096;
  float v[9];
#pragma unroll
  for (int dy = 0; dy < 3; dy++)
#pragma unroll
    for (int dx = 0; dx < 3; dx++) {
      int y = h + dy - 1, xx = w + dx - 1;
      v[dy * 3 + dx] = (y >= 0 && y < 64 && xx >= 0 && xx < 64) ? xb[y * 64 + xx] : 0.f;
    }
  int d0 = ln * 4;
  float o[4]; float s = 0.f, sq = 0.f;
#pragma unroll
  for (int e = 0; e < 4; e++) {
    int d = d0 + e;
    float a = 0.f;
#pragma unroll
    for (int k = 0; k < 9; k++) a += v[k] * ew[d * 9 + k];
    float ts = 0.5f * (te[d] + te[128 + d] + te[256 + d] + te[384 + d]) + te[512 + d];
    float r = a + 3.f * eb[d] + 3.f * pos[l * 128 + d] + ts;
    o[e] = r; s += r; sq += r * r;
  }
  float4 f4; f4.x = o[0]; f4.y = o[1]; f4.z = o[2]; f4.w = o[3];
  *(float4*)(emb + (size_t)tok * 128 + d0) = f4;
#pragma unroll
  for (int off = 16; off; off >>= 1) { s += __shfl_xor(s, off); sq += __shfl_xor(sq, off); }
  float m = s * (1.f / 128.f);
  float var = sq * (1.f / 128.f) - m * m;
  float rs = rsqrtf(var + 1e-5f);
  ushort4 u;
  u.x = f2bf((o[0] - m) * rs * lw[d0 + 0] + lb[d0 + 0]);
  u.y = f2bf((o[1] - m) * rs * lw[d0 + 1] + lb[d0 + 1]);
  u.z = f2bf((o[2] - m) * rs * lw[d0 + 2] + lb[d0 + 2]);
  u.w = f2bf((o[3] - m) * rs * lw[d0 + 3] + lb[d0 + 3]);
  *(ushort4*)(xn + (size_t)tok * 128 + d0) = u;
}

// ---------------- fused dwconv + residual + sln ----------------
__global__ __launch_bounds__(256) void k_fuse1(
    const ushort* __restrict__ xn1, float* __restrict__ emb, ushort* __restrict__ xn2,
    const float* __restrict__ cwT, const float* __restrict__ cb,
    const float* __restrict__ sw, const float* __restrict__ sb) {
  int i = blockIdx.x * 256 + threadIdx.x; // Mtok*16
  int g = i & 15, tok = i >> 4, d0 = g * 8, l = tok & 4095;
  const ushort* p = xn1 + (size_t)tok * 128 + d0;
  const bfx8 zf = {0, 0, 0, 0, 0, 0, 0, 0};
  bfx8 v0 = *(const bfx8*)p;
  bfx8 v1 = (l >= 1) ? *(const bfx8*)(p - 128) : zf;
  bfx8 v2 = (l >= 2) ? *(const bfx8*)(p - 256) : zf;
  bfx8 v3 = (l >= 3) ? *(const bfx8*)(p - 384) : zf;
  float* ep = emb + (size_t)tok * 128 + d0;
  float4 e0 = *(const float4*)ep;
  float4 e1 = *(const float4*)(ep + 4);
  float ev[8] = {e0.x, e0.y, e0.z, e0.w, e1.x, e1.y, e1.z, e1.w};
  float nv[8]; float s = 0.f, sq = 0.f;
#pragma unroll
  for (int e = 0; e < 8; e++) {
    int d = d0 + e;
    float c = cb[d] + cwT[3 * 128 + d] * bf2f((ushort)v0[e]) + cwT[2 * 128 + d] * bf2f((ushort)v1[e]) +
              cwT[1 * 128 + d] * bf2f((ushort)v2[e]) + cwT[0 * 128 + d] * bf2f((ushort)v3[e]);
    nv[e] = ev[e] + c;
    s += nv[e]; sq += nv[e] * nv[e];
  }
  float4 w0; w0.x = nv[0]; w0.y = nv[1]; w0.z = nv[2]; w0.w = nv[3];
  float4 w1; w1.x = nv[4]; w1.y = nv[5]; w1.z = nv[6]; w1.w = nv[7];
  *(float4*)ep = w0;
  *(float4*)(ep + 4) = w1;
#pragma unroll
  for (int off = 8; off; off >>= 1) { s += __shfl_xor(s, off); sq += __shfl_xor(sq, off); }
  float m = s * (1.f / 128.f);
  float var = sq * (1.f / 128.f) - m * m;
  float rs = rsqrtf(var + 1e-5f);
  bfx8 r8;
#pragma unroll
  for (int e = 0; e < 8; e++) {
    int d = d0 + e;
    r8[e] = (short)f2bf((nv[e] - m) * rs * sw[d] + sb[d]);
  }
  *(bfx8*)(xn2 + (size_t)tok * 128 + d0) = r8;
}

// ---------------- in-proj GEMM + fused u: grid (M/128, 2) ----------------
// y==0: silu half -> LDS -> u = silu(xp)@xw^T + xb -> UT[b][ds][L]  (no global xp!)
// y==1: sigmoid half -> Zu bf16 [M,128]
__global__ __launch_bounds__(256) void k_gemm_xz(
    const ushort* __restrict__ A, const ushort* __restrict__ W, const float* __restrict__ bias,
    ushort* __restrict__ Zu, const ushort* __restrict__ xw, const float* __restrict__ xb,
    float* __restrict__ UT) {
  __shared__ ushort sl[128 * SLS];
  const int t = threadIdx.x;
  const int l = t & 63, wv = t >> 6;
  const int l15 = l & 15, q = l >> 4;
  const int wm = wv >> 1, wn = wv & 1;
  const int m0 = blockIdx.x * 128 + wm * 64;
  const int n0 = blockIdx.y * 128 + wn * 64;
  f32x4 acc[4][4] = {};
  const ushort* Ab = A + (size_t)(m0 + l15) * 128 + q * 8;
  const ushort* Wb = W + (size_t)(n0 + l15) * 128 + q * 8;
#pragma unroll
  for (int k0 = 0; k0 < 128; k0 += 32) {
    bfx8 a[4], b[4];
#pragma unroll
    for (int mf = 0; mf < 4; mf++) a[mf] = *(const bfx8*)(Ab + (size_t)mf * 16 * 128 + k0);
#pragma unroll
    for (int nf = 0; nf < 4; nf++) b[nf] = *(const bfx8*)(Wb + (size_t)nf * 16 * 128 + k0);
#pragma unroll
    for (int mf = 0; mf < 4; mf++)
#pragma unroll
      for (int nf = 0; nf < 4; nf++)
        acc[mf][nf] = __builtin_amdgcn_mfma_f32_16x16x32_bf16(a[mf], b[nf], acc[mf][nf], 0, 0, 0);
  }
  if (blockIdx.y == 1) {
#pragma unroll
    for (int mf = 0; mf < 4; mf++)
#pragma unroll
      for (int nf = 0; nf < 4; nf++) {
        const int col = n0 + nf * 16 + l15;
        const float bb = bias[col];
#pragma unroll
        for (int r = 0; r < 4; r++) {
          const int row = m0 + mf * 16 + q * 4 + r;
          float v = acc[mf][nf][r] + bb;
          Zu[(size_t)row * 128 + col - 128] = f2bf(1.f / (1.f + expf(-v)));
        }
      }
    return;
  }
  // y==0: silu -> LDS tile (rows 0..127 local, cols 0..127)
#pragma unroll
  for (int mf = 0; mf < 4; mf++)
#pragma unroll
    for (int nf = 0; nf < 4; nf++) {
      const int col = wn * 64 + nf * 16 + l15;
      const float bb = bias[col];
#pragma unroll
      for (int r = 0; r < 4; r++) {
        const int rowl = wm * 64 + mf * 16 + q * 4 + r;
        float v = acc[mf][nf][r] + bb;
        sl[rowl * SLS + col] = f2bf(v / (1.f + expf(-v)));
      }
    }
  __syncthreads();
  // u-GEMM: M=128 (2 m-frags/wave), N=16 (ds), K=128
  f32x4 pu[2] = {};
#pragma unroll
  for (int k0 = 0; k0 < 128; k0 += 32) {
    bfx8 bx_ = *(const bfx8*)(xw + l15 * 128 + k0 + q * 8);
#pragma unroll
    for (int mi = 0; mi < 2; mi++) {
      bfx8 a2 = *(const bfx8*)&sl[(wv * 32 + mi * 16 + l15) * SLS + k0 + q * 8];
      pu[mi] = __builtin_amdgcn_mfma_f32_16x16x32_bf16(a2, bx_, pu[mi], 0, 0, 0);
    }
  }
  const float ub = xb[l15];
#pragma unroll
  for (int mi = 0; mi < 2; mi++)
#pragma unroll
    for (int r = 0; r < 4; r++) {
      int token = blockIdx.x * 128 + wv * 32 + mi * 16 + q * 4 + r;
      int b = token >> 12, ll = token & 4095;
      UT[((size_t)(b * 16 + l15)) * 4096 + ll] = pu[mi][r] + ub;
    }
}

// ---------------- out-proj + residual + ln2 + mlp1(gelu): grid (M/128, 1) ----------------
__global__ __launch_bounds__(256) void k_gemm_om(
    const ushort* __restrict__ A, const ushort* __restrict__ W1, const float* __restrict__ b1,
    float* __restrict__ emb, const float* __restrict__ lw, const float* __restrict__ lb,
    const ushort* __restrict__ W2, const float* __restrict__ b2, ushort* __restrict__ MH) {
  __shared__ ushort sl[128 * SLS];
  __shared__ float red[2][128][2];
  const int t = threadIdx.x;
  const int l = t & 63, wv = t >> 6;
  const int l15 = l & 15, q = l >> 4;
  const int wm = wv >> 1, wn = wv & 1;
  const int m0 = blockIdx.x * 128 + wm * 64;
  const int n0 = wn * 64;
  {
    f32x4 acc[4][4] = {};
    const ushort* Ab = A + (size_t)(m0 + l15) * 128 + q * 8;
    const ushort* Wb = W1 + (size_t)(n0 + l15) * 128 + q * 8;
#pragma unroll
    for (int k0 = 0; k0 < 128; k0 += 32) {
      bfx8 a[4], b[4];
#pragma unroll
      for (int mf = 0; mf < 4; mf++) a[mf] = *(const bfx8*)(Ab + (size_t)mf * 16 * 128 + k0);
#pragma unroll
      for (int nf = 0; nf < 4; nf++) b[nf] = *(const bfx8*)(Wb + (size_t)nf * 16 * 128 + k0);
#pragma unroll
      for (int mf = 0; mf < 4; mf++)
#pragma unroll
        for (int nf = 0; nf < 4; nf++)
          acc[mf][nf] = __builtin_amdgcn_mfma_f32_16x16x32_bf16(a[mf], b[nf], acc[mf][nf], 0, 0, 0);
    }
    float sv[4][4], qv[4][4];
#pragma unroll
    for (int mf = 0; mf < 4; mf++)
#pragma unroll
      for (int r = 0; r < 4; r++) { sv[mf][r] = 0.f; qv[mf][r] = 0.f; }
#pragma unroll
    for (int mf = 0; mf < 4; mf++)
#pragma unroll
      for (int nf = 0; nf < 4; nf++) {
        const int col = n0 + nf * 16 + l15;
        const float bb = b1[col];
#pragma unroll
        for (int r = 0; r < 4; r++) {
          const int row = m0 + mf * 16 + q * 4 + r;
          float v = acc[mf][nf][r] + bb + emb[(size_t)row * 128 + col];
          acc[mf][nf][r] = v;
          sv[mf][r] += v; qv[mf][r] += v * v;
        }
      }
#pragma unroll
    for (int mf = 0; mf < 4; mf++)
#pragma unroll
      for (int r = 0; r < 4; r++) {
#pragma unroll
        for (int off = 1; off < 16; off <<= 1) {
          sv[mf][r] += __shfl_xor(sv[mf][r], off);
          qv[mf][r] += __shfl_xor(qv[mf][r], off);
        }
        if (l15 == 0) {
          int rowl = wm * 64 + mf * 16 + q * 4 + r;
          red[0][rowl][wn] = sv[mf][r];
          red[1][rowl][wn] = qv[mf][r];
        }
      }
    __syncthreads();
#pragma unroll
    for (int mf = 0; mf < 4; mf++)
#pragma unroll
      for (int r = 0; r < 4; r++) {
        const int rowl = wm * 64 + mf * 16 + q * 4 + r;
        const int row = blockIdx.x * 128 + rowl;
        float ts = red[0][rowl][0] + red[0][rowl][1];
        float tq = red[1][rowl][0] + red[1][rowl][1];
        float mm = ts * (1.f / 128.f);
        float var = tq * (1.f / 128.f) - mm * mm;
        float rs = rsqrtf(var + 1e-5f);
#pragma unroll
        for (int nf = 0; nf < 4; nf++) {
          const int col = n0 + nf * 16 + l15;
          float v = acc[mf][nf][r];
          emb[(size_t)row * 128 + col] = v;
          sl[rowl * SLS + col] = f2bf((v - mm) * rs * lw[col] + lb[col]);
        }
      }
  }
  __syncthreads();
  // phase 2: MH[row][0..255] = gelu(ln2 @ W2^T + b2); wave wv owns rows wv*32..+32
#pragma unroll
  for (int p = 0; p < 2; p++) {
    f32x4 acc2[2][8] = {};
#pragma unroll
    for (int k0 = 0; k0 < 128; k0 += 32) {
      bfx8 a2[2];
#pragma unroll
      for (int mi = 0; mi < 2; mi++)
        a2[mi] = *(const bfx8*)&sl[(wv * 32 + mi * 16 + l15) * SLS + k0 + q * 8];
#pragma unroll
      for (int nf = 0; nf < 8; nf++) {
        bfx8 b2v = *(const bfx8*)(W2 + (size_t)(p * 128 + nf * 16 + l15) * 128 + k0 + q * 8);
#pragma unroll
        for (int mi = 0; mi < 2; mi++)
          acc2[mi][nf] = __builtin_amdgcn_mfma_f32_16x16x32_bf16(a2[mi], b2v, acc2[mi][nf], 0, 0, 0);
      }
    }
#pragma unroll
    for (int mi = 0; mi < 2; mi++)
#pragma unroll
      for (int nf = 0; nf < 8; nf++) {
        const int col = p * 128 + nf * 16 + l15;
        const float bb = b2[col];
#pragma unroll
        for (int r = 0; r < 4; r++) {
          const int row = blockIdx.x * 128 + wv * 32 + mi * 16 + q * 4 + r;
          float v = acc2[mi][nf][r] + bb;
          MH[(size_t)row * 256 + col] = f2bf(0.5f * v * (1.f + erff(v * 0.7071067811865475f)));
        }
      }
  }
}

// ---------------- MFMA GEMM (mlp2): MODE 5: emb+=v, LN -> out2v bf16 [M,128]
//                                   MODE 4: emb+=v, bf16 -> out2v channels-last at +128
template <int MODE, int K>
__global__ __launch_bounds__(256) void k_mgemm(const ushort* __restrict__ A, const ushort* __restrict__ W,
                                               const float* __restrict__ bias, void* __restrict__ out2v,
                                               float* __restrict__ emb,
                                               const float* __restrict__ lw, const float* __restrict__ lb) {
  __shared__ float red[2][128][2];
  const int t = threadIdx.x;
  const int l = t & 63, wv = t >> 6;
  const int l15 = l & 15, q = l >> 4;
  const int wm = wv >> 1, wn = wv & 1;
  const int m0 = blockIdx.x * 128 + wm * 64;
  const int n0 = wn * 64;
  f32x4 acc[4][4] = {};
  const ushort* Ab = A + (size_t)(m0 + l15) * K + q * 8;
  const ushort* Wb = W + (size_t)(n0 + l15) * K + q * 8;
#pragma unroll
  for (int k0 = 0; k0 < K; k0 += 32) {
    bfx8 a[4], b[4];
#pragma unroll
    for (int mf = 0; mf < 4; mf++) a[mf] = *(const bfx8*)(Ab + (size_t)mf * 16 * K + k0);
#pragma unroll
    for (int nf = 0; nf < 4; nf++) b[nf] = *(const bfx8*)(Wb + (size_t)nf * 16 * K + k0);
#pragma unroll
    for (int mf = 0; mf < 4; mf++)
#pragma unroll
      for (int nf = 0; nf < 4; nf++)
        acc[mf][nf] = __builtin_amdgcn_mfma_f32_16x16x32_bf16(a[mf], b[nf], acc[mf][nf], 0, 0, 0);
  }
  float sv[4][4], qv[4][4];
#pragma unroll
  for (int mf = 0; mf < 4; mf++)
#pragma unroll
    for (int r = 0; r < 4; r++) { sv[mf][r] = 0.f; qv[mf][r] = 0.f; }
#pragma unroll
  for (int mf = 0; mf < 4; mf++)
#pragma unroll
    for (int nf = 0; nf < 4; nf++) {
      const int col = n0 + nf * 16 + l15;
      const float bb = bias[col];
#pragma unroll
      for (int r = 0; r < 4; r++) {
        const int row = m0 + mf * 16 + q * 4 + r;
        float v = acc[mf][nf][r] + bb + emb[(size_t)row * 128 + col];
        acc[mf][nf][r] = v;
        sv[mf][r] += v; qv[mf][r] += v * v;
      }
    }
  if constexpr (MODE == 5) {
#pragma unroll
    for (int mf = 0; mf < 4; mf++)
#pragma unroll
      for (int r = 0; r < 4; r++) {
#pragma unroll
        for (int off = 1; off < 16; off <<= 1) {
          sv[mf][r] += __shfl_xor(sv[mf][r], off);
          qv[mf][r] += __shfl_xor(qv[mf][r], off);
        }
        if (l15 == 0) {
          int rowl = wm * 64 + mf * 16 + q * 4 + r;
          red[0][rowl][wn] = sv[mf][r];
          red[1][rowl][wn] = qv[mf][r];
        }
      }
    __syncthreads();
  }
#pragma unroll
  for (int mf = 0; mf < 4; mf++)
#pragma unroll
    for (int r = 0; r < 4; r++) {
      const int rowl = wm * 64 + mf * 16 + q * 4 + r;
      const int row = blockIdx.x * 128 + rowl;
      float mm = 0.f, rs = 0.f;
      if constexpr (MODE == 5) {
        float ts = red[0][rowl][0] + red[0][rowl][1];
        float tq = red[1][rowl][0] + red[1][rowl][1];
        mm = ts * (1.f / 128.f);
        float var = tq * (1.f / 128.f) - mm * mm;
        rs = rsqrtf(var + 1e-5f);
      }
#pragma unroll
      for (int nf = 0; nf < 4; nf++) {
        const int col = n0 + nf * 16 + l15;
        float v = acc[mf][nf][r];
        emb[(size_t)row * 128 + col] = v;
        if constexpr (MODE == 5)
          ((ushort*)out2v)[(size_t)row * 128 + col] = f2bf((v - mm) * rs * lw[col] + lb[col]);
        else
          ((ushort*)out2v)[(size_t)row * 256 + 128 + col] = f2bf(v);
      }
    }
}

// ---------------- register chunked scan ----------------
__global__ __launch_bounds__(64) void k_scan(const float* __restrict__ UT, float* __restrict__ HST,
                                             const float* __restrict__ A_log) {
  const int b = blockIdx.x >> 4, ds = blockIdx.x & 15;
  const int tid = threadIdx.x;
  const float a = expf(-expf(A_log[ds]));
  const float4* ut4 = (const float4*)(UT + ((size_t)(b * 16 + ds)) * 4096 + tid * 64);
  float r[64];
#pragma unroll
  for (int j4 = 0; j4 < 16; j4++) {
    float4 v = ut4[j4];
    r[j4 * 4 + 0] = v.x; r[j4 * 4 + 1] = v.y; r[j4 * 4 + 2] = v.z; r[j4 * 4 + 3] = v.w;
  }
  float h = 0.f;
#pragma unroll
  for (int j = 0; j < 64; j++) { h = a * h + r[j]; r[j] = h; }
  float a64 = a;
#pragma unroll
  for (int qq = 0; qq < 6; qq++) a64 *= a64;
  float Ac = a64, Bc = h;
#pragma unroll
  for (int off = 1; off < 64; off <<= 1) {
    float Ap = __shfl_up(Ac, off);
    float Bp = __shfl_up(Bc, off);
    if (tid >= off) { Bc = Ac * Bp + Bc; Ac = Ac * Ap; }
  }
  float carry = __shfl_up(Bc, 1);
  if (tid == 0) carry = 0.f;
  float p = a;
#pragma unroll
  for (int j = 0; j < 64; j++) { r[j] += p * carry; p *= a; }
  float4* hb4 = (float4*)(HST + ((size_t)(b * 16 + ds)) * 4096 + tid * 64);
#pragma unroll
  for (int j4 = 0; j4 < 16; j4++) {
    float4 v; v.x = r[j4 * 4 + 0]; v.y = r[j4 * 4 + 1]; v.z = r[j4 * 4 + 2]; v.w = r[j4 * 4 + 3];
    hb4[j4] = v;
  }
}

// ---------------- y = (hs @ D) * z ----------------
__global__ __launch_bounds__(256) void k_yb(const float* __restrict__ HST, const float* __restrict__ Dm_,
                                            const ushort* __restrict__ Z, ushort* __restrict__ Y) {
  const int m = blockIdx.x * 2 + (threadIdx.x >> 7);
  const int d = threadIdx.x & 127;
  const int b = m >> 12, l = m & 4095;
  const float* hb = HST + (size_t)b * 16 * Ln + l;
  float acc = 0.f;
#pragma unroll
  for (int s = 0; s < 16; s++) acc += hb[(size_t)s * Ln] * Dm_[s * 128 + d];
  const size_t o = (size_t)m * 128 + d;
  Y[o] = f2bf(acc * bf2f(Z[o]));
}

// ---------------- LDS-staged implicit-GEMM conv (WPB waves/block) ----------------
template <int MODE, int OTH, int OTW, int CIN, int WPB>
__global__ __launch_bounds__(WPB * 64) void k_cv(
    const ushort* __restrict__ in, ushort* __restrict__ out,
    const ushort* __restrict__ wt, const float* __restrict__ bias,
    int Hi, int Wi, int CP, int CO, int CPo, int COo, int Cout,
    int nsp, int nspx, long ibs, long obs) {
  constexpr int ITH = (MODE == 1) ? (2 * OTH + 1) : (OTH + 2);
  constexpr int ITW = (MODE == 1) ? (2 * OTW + 1) : (OTW + 2);
  constexpr int NPIX = ITH * ITW;
  constexpr int SPF = OTH * OTW / 16;
  constexpr int NTAPS = (MODE == 2) ? 4 : 9;
  constexpr int NCH = CIN / 32;
  __shared__ __attribute__((aligned(16))) ushort lds[NPIX * 40];
  const int t = threadIdx.x;
  const int w = t >> 6, l = t & 63;
  const int l15 = l & 15, q = l >> 4;
  const int b = blockIdx.z;
  const int py = (MODE == 2) ? ((int)blockIdx.y >> 1) : 0;
  const int px = (MODE == 2) ? ((int)blockIdx.y & 1) : 0;
  const int cb = blockIdx.x / nsp;
  const int spt = blockIdx.x - cb * nsp;
  const int spy = spt / nspx, spx = spt - spy * nspx;
  const int n0 = cb * (16 * WPB) + w * 16;
  const int y0 = spy * OTH, x0 = spx * OTW;
  const int gy0 = (MODE == 1) ? (2 * y0 - 1) : (y0 - 1);
  const int gx0 = (MODE == 1) ? (2 * x0 - 1) : (x0 - 1);
  const ushort* ib = in + (size_t)b * ibs;
  f32x4 acc[SPF] = {};
  int abase[SPF];
#pragma unroll
  for (int af = 0; af < SPF; af++) {
    int p = af * 16 + l15;
    int ty = p / OTW, tx = p % OTW;
    int sy = (MODE == 1) ? (2 * ty) : ty;
    int sx = (MODE == 1) ? (2 * tx) : tx;
    abase[af] = (sy * ITW + sx) * 40 + q * 8;
  }
  for (int c = 0; c < NCH; c++) {
    const int k0 = c * 32;
    __syncthreads();
    for (int idx = t; idx < NPIX * 4; idx += WPB * 64) {
      int pix = idx >> 2, qq = idx & 3;
      int sy = pix / ITW, sx = pix - sy * ITW;
      int gy = gy0 + sy, gx = gx0 + sx;
      bfx8 v = {0, 0, 0, 0, 0, 0, 0, 0};
      if ((unsigned)gy < (unsigned)Hi && (unsigned)gx < (unsigned)Wi)
        v = *(const bfx8*)(ib + (size_t)(gy * Wi + gx) * CP + CO + k0 + qq * 8);
      *(bfx8*)&lds[pix * 40 + qq * 8] = v;
    }
    __syncthreads();
#pragma unroll
    for (int tap = 0; tap < NTAPS; tap++) {
      const int dy = (MODE == 2) ? (tap >> 1) : (tap / 3);
      const int dx = (MODE == 2) ? (tap & 1) : (tap - (tap / 3) * 3);
      const int tapw = (MODE == 2) ? ((3 - py - 2 * dy) * 4 + (3 - px - 2 * dx)) : tap;
      const int toff = (MODE == 2) ? (((py + dy) * ITW + (px + dx)) * 40)
                                   : ((dy * ITW + dx) * 40);
      bfx8 bv = *(const bfx8*)(wt + ((size_t)tapw * Cout + n0 + l15) * CIN + k0 + q * 8);
#pragma unroll
      for (int af = 0; af < SPF; af++) {
        bfx8 av = *(const bfx8*)&lds[abase[af] + toff];
        acc[af] = __builtin_amdgcn_mfma_f32_16x16x32_bf16(av, bv, acc[af], 0, 0, 0);
      }
    }
  }
  const float bb = bias[n0 + l15];
  ushort* ob = out + (size_t)b * obs + COo + n0 + l15;
#pragma unroll
  for (int af = 0; af < SPF; af++) {
#pragma unroll
    for (int r = 0; r < 4; r++) {
      int p = af * 16 + q * 4 + r;
      int ty = p / OTW, tx = p % OTW;
      int oy, ox, Wo;
      if (MODE == 2) { oy = (y0 + ty) * 2 + py; ox = (x0 + tx) * 2 + px; Wo = Wi * 2; }
      else if (MODE == 1) { oy = y0 + ty; ox = x0 + tx; Wo = Wi / 2; }
      else { oy = y0 + ty; ox = x0 + tx; Wo = Wi; }
      ob[(size_t)(oy * Wo + ox) * CPo] = f2bf(fmaxf(acc[af][r] + bb, 0.f));
    }
  }
}

// ---------------- final 1x1 conv 256 -> 2 ----------------
__global__ void k_final2(const ushort* __restrict__ in, const float* __restrict__ w,
                         const float* __restrict__ bias, float* __restrict__ out) {
  int i = blockIdx.x * 256 + threadIdx.x; // B*4096
  int b = i >> 12, p = i & 4095;
  const ushort* row = in + (size_t)i * 256;
  float a0 = bias[0], a1 = bias[1];
  for (int c = 0; c < 256; c += 4) {
    ushort4 u = *(const ushort4*)(row + c);
    float4 w0 = *(const float4*)(w + c);
    float4 w1 = *(const float4*)(w + 256 + c);
    float f0 = bf2f(u.x), f1 = bf2f(u.y), f2 = bf2f(u.z), f3 = bf2f(u.w);
    a0 += f0 * w0.x + f1 * w0.y + f2 * w0.z + f3 * w0.w;
    a1 += f0 * w1.x + f1 * w1.y + f2 * w1.z + f3 * w1.w;
  }
  out[(size_t)b * 8192 + p] = a0;
  out[(size_t)b * 8192 + 4096 + p] = a1;
}

extern "C" void kernel_launch(void* const* d_in, const int* in_sizes, int n_in,
                              void* d_out, int out_size, void* d_ws, size_t ws_size,
                              hipStream_t stream) {
  (void)in_sizes; (void)n_in; (void)out_size; (void)ws_size;
  const float* x          = (const float*)d_in[0];
  const float* emb_w      = (const float*)d_in[1];
  const float* emb_b      = (const float*)d_in[2];
  const float* pos_embed  = (const float*)d_in[3];
  const float* time_embed = (const float*)d_in[4];
  const float* blk_ln1_w  = (const float*)d_in[5];
  const float* blk_ln1_b  = (const float*)d_in[6];
  const float* blk_conv_w = (const float*)d_in[7];
  const float* blk_conv_b = (const float*)d_in[8];
  const float* blk_sln_w  = (const float*)d_in[9];
  const float* blk_sln_b  = (const float*)d_in[10];
  const float* blk_A_log  = (const float*)d_in[11];
  const float* blk_D      = (const float*)d_in[12];
  const float* blk_in_w   = (const float*)d_in[13];
  const float* blk_in_b   = (const float*)d_in[14];
  const float* blk_x_w    = (const float*)d_in[15];
  const float* blk_x_b    = (const float*)d_in[16];
  const float* blk_out_w  = (const float*)d_in[17];
  const float* blk_out_b  = (const float*)d_in[18];
  const float* blk_ln2_w  = (const float*)d_in[19];
  const float* blk_ln2_b  = (const float*)d_in[20];
  const float* blk_mlp_w1 = (const float*)d_in[21];
  const float* blk_mlp_b1 = (const float*)d_in[22];
  const float* blk_mlp_w2 = (const float*)d_in[23];
  const float* blk_mlp_b2 = (const float*)d_in[24];
  const float* down1_w    = (const float*)d_in[25];
  const float* down1_b    = (const float*)d_in[26];
  const float* down2_w    = (const float*)d_in[27];
  const float* down2_b    = (const float*)d_in[28];
  const float* bott_w     = (const float*)d_in[29];
  const float* bott_b     = (const float*)d_in[30];
  const float* up1_w      = (const float*)d_in[31];
  const float* up1_b      = (const float*)d_in[32];
  const float* up2_w      = (const float*)d_in[33];
  const float* up2_b      = (const float*)d_in[34];
  const float* final_w    = (const float*)d_in[35];
  const float* final_b    = (const float*)d_in[36];

  // workspace layout (float offsets, F = 1Mi floats):
  //  EMB 0-8F | XN1 8-12F | XN2 12-16F | MH/U2C 16-24F | Zu 24-28F
  //  W3+CWT 28-29.2F | Ubuf 32-33F | HST 33-34F      (no overlaps!)
  float* ws = (float*)d_ws;
  constexpr size_t F = 1u << 20;
  float* EMB = ws;                            // fp32 residual [M,128]
  ushort* XN1 = (ushort*)(ws + 8 * F);        // ln1-out bf16 [M,128]
  ushort* XN2 = XN1 + 8 * F;                  // sln-out / y bf16 [M,128]
  ushort* MH  = (ushort*)(ws + 16 * F);       // mlp hidden bf16 [M,256]
  ushort* Zu  = (ushort*)(ws + 24 * F);       // z bf16 [M,128]
  ushort* W3  = (ushort*)(ws + 28 * F);       // preprocessed weights
  float* Ubuf = ws + 32 * F;                  // xc scratch, then U_T fp32
  float* HST  = ws + 33 * F;                  // hs^T fp32

  // W3 offsets (ushorts)
  ushort* Wi  = W3;                 // 2*256*128
  ushort* Wo  = W3 + 65536;         // 2*128*128
  ushort* Wm1 = W3 + 98304;         // 2*256*128
  ushort* Wm2 = W3 + 163840;        // 2*128*256
  ushort* Wx  = W3 + 229376;        // 2*16*128
  ushort* Wd1 = W3 + 233472;        // 9*128*128
  ushort* Wd2 = W3 + 380928;        // 9*256*128
  ushort* Wb9 = W3 + 675840;        // 9*256*256
  ushort* Wu1 = W3 + 1265664;       // 16*128*256
  ushort* Wu2 = W3 + 1789952;       // 16*128*256
  float*  CWT = (float*)(W3 + 2314240); // 2*4*128 fp32

  k_prep<<<9044, 256, 0, stream>>>(blk_in_w, blk_out_w, blk_mlp_w1, blk_mlp_w2, blk_x_w,
                                   blk_conv_w, down1_w, down2_w, bott_w, up1_w, up2_w, W3, CWT);
  k_combine<<<256, 256, 0, stream>>>(x, Ubuf);
  k_embedln<<<8192, 256, 0, stream>>>(Ubuf, emb_w, emb_b, pos_embed, time_embed,
                                      blk_ln1_w, blk_ln1_b, EMB, XN1);

  ushort* U2C = MH; // [B,64,64,256] channels-last (written by mlp2 MODE4 + up2)
  for (int i = 0; i < 2; i++) {
    k_fuse1<<<4096, 256, 0, stream>>>(XN1, EMB, XN2, CWT + i * 512, blk_conv_b + i * Dn,
                                      blk_sln_w + i * Dn, blk_sln_b + i * Dn);
    k_gemm_xz<<<dim3(512, 2), 256, 0, stream>>>(XN2, Wi + i * 32768, blk_in_b + i * 256,
                                                Zu, Wx + i * 2048, blk_x_b + i * DSn, Ubuf);
    k_scan<<<256, 64, 0, stream>>>(Ubuf, HST, blk_A_log + i * DSn);
    k_yb<<<32768, 256, 0, stream>>>(HST, blk_D + i * DSn * Dn, Zu, XN2);
    k_gemm_om<<<dim3(512, 1), 256, 0, stream>>>(XN2, Wo + i * 16384, blk_out_b + i * Dn,
                                                EMB, blk_ln2_w + i * Dn, blk_ln2_b + i * Dn,
                                                Wm1 + i * 32768, blk_mlp_b1 + i * 256, MH);
    if (i == 0)
      k_mgemm<5, 256><<<dim3(512, 1), 256, 0, stream>>>(MH, Wm2 + i * 32768, blk_mlp_b2 + i * Dn,
                                                        XN1, EMB, blk_ln1_w + Dn, blk_ln1_b + Dn);
    else
      k_mgemm<4, 256><<<dim3(512, 1), 256, 0, stream>>>(MH, Wm2 + i * 32768, blk_mlp_b2 + i * Dn,
                                                        U2C, EMB, nullptr, nullptr);
  }

  // ---- UNet head, channels-last bf16 ----
  ushort* U1C = XN1;              // [B,32,32,256] (dead XN1 region)
  ushort* X2b = XN1 + 8388608;    // [B,16,16,256] (dead XN2 region)
  ushort* X3b = X2b + 1048576;    // [B,16,16,256]

  k_cv<1, 8, 8, 128, 4><<<dim3(2 * 16, 1, 16), 256, 0, stream>>>(
      U2C, U1C, Wd1, down1_b, 64, 64, 256, 128, 256, 128, 128,
      16, 4, 64L * 64 * 256, 32L * 32 * 256);
  k_cv<1, 8, 8, 128, 2><<<dim3(8 * 4, 1, 16), 128, 0, stream>>>(
      U1C, X2b, Wd2, down2_b, 32, 32, 256, 128, 256, 0, 256,
      4, 2, 32L * 32 * 256, 16L * 16 * 256);
  k_cv<0, 8, 8, 256, 2><<<dim3(8 * 4, 1, 16), 128, 0, stream>>>(
      X2b, X3b, Wb9, bott_b, 16, 16, 256, 0, 256, 0, 256,
      4, 2, 16L * 16 * 256, 16L * 16 * 256);
  k_cv<2, 8, 16, 256, 2><<<dim3(4 * 2, 4, 16), 128, 0, stream>>>(
      X3b, U1C, Wu1, up1_b, 16, 16, 256, 0, 256, 0, 128,
      2, 1, 16L * 16 * 256, 32L * 32 * 256);
  k_cv<2, 16, 16, 256, 4><<<dim3(2 * 4, 4, 16), 256, 0, stream>>>(
      U1C, U2C, Wu2, up2_b, 32, 32, 256, 0, 256, 0, 128,
      4, 2, 32L * 32 * 256, 64L * 64 * 256);

  k_final2<<<256, 256, 0, stream>>>(U2C, final_w, final_b, (float*)d_out);
}